// Round 1
// baseline (2414.415 us; speedup 1.0000x reference)
//
#include <hip/hip_runtime.h>

#define NN 50000
#define NE 400000
#define FIN 64
#define EIN 16
#define H 128
#define NL 4
#define NG 256
#define NOUT 12
#define EPSV 1e-5f

#define SB 256
#define NBLK ((NN + SB - 1) / SB)   // 196
#define GB ((NN + 63) / 64)          // 782 (64-row GEMM tiles)

struct Ptr3 { const float* p0; const float* p1; const float* p2; };

__device__ __forceinline__ const float* ptr3_get(const Ptr3& b, int i) {
    return i == 0 ? b.p0 : (i == 1 ? b.p1 : b.p2);
}

__device__ __forceinline__ void fma4(float4& c, float a, float4 b) {
    c.x = fmaf(a, b.x, c.x); c.y = fmaf(a, b.y, c.y);
    c.z = fmaf(a, b.z, c.z); c.w = fmaf(a, b.w, c.w);
}

// ---------------- setup kernels ----------------
__global__ void k_hist(const int* __restrict__ dst, int* __restrict__ deg) {
    int e = blockIdx.x * 256 + threadIdx.x;
    if (e < NE) atomicAdd(&deg[dst[e]], 1);
}

__global__ void k_scan1(const int* __restrict__ deg, int* __restrict__ partial) {
    __shared__ int sm[256];
    int i = blockIdx.x * 256 + threadIdx.x;
    sm[threadIdx.x] = (i < NN) ? deg[i] : 0;
    __syncthreads();
    for (int s = 128; s > 0; s >>= 1) {
        if (threadIdx.x < s) sm[threadIdx.x] += sm[threadIdx.x + s];
        __syncthreads();
    }
    if (threadIdx.x == 0) partial[blockIdx.x] = sm[0];
}

__global__ void k_scan2(int* __restrict__ partial, int* __restrict__ row_ptr, int nblk) {
    __shared__ int sm[256];
    int t = threadIdx.x;
    sm[t] = (t < nblk) ? partial[t] : 0;
    __syncthreads();
    for (int off = 1; off < 256; off <<= 1) {
        int v = (t >= off) ? sm[t - off] : 0;
        __syncthreads();
        sm[t] += v;
        __syncthreads();
    }
    int excl = (t == 0) ? 0 : sm[t - 1];
    if (t < nblk) partial[t] = excl;
    if (t == 0) row_ptr[0] = 0;
}

__global__ void k_scan3(const int* __restrict__ deg, const int* __restrict__ partial,
                        int* __restrict__ row_ptr) {
    __shared__ int sm[256];
    int t = threadIdx.x;
    int i = blockIdx.x * 256 + t;
    sm[t] = (i < NN) ? deg[i] : 0;
    __syncthreads();
    for (int off = 1; off < 256; off <<= 1) {
        int v = (t >= off) ? sm[t - off] : 0;
        __syncthreads();
        sm[t] += v;
        __syncthreads();
    }
    if (i < NN) row_ptr[i + 1] = partial[blockIdx.x] + sm[t];
}

__global__ void k_fill(const int* __restrict__ src, const int* __restrict__ dst,
                       const int* __restrict__ row_ptr, int* __restrict__ cursor,
                       int* __restrict__ csr_src, int* __restrict__ csr_eid) {
    int e = blockIdx.x * 256 + threadIdx.x;
    if (e >= NE) return;
    int d = dst[e];
    int pos = atomicAdd(&cursor[d], 1);
    int slot = row_ptr[d] + pos;
    csr_src[slot] = src[e];
    csr_eid[slot] = e;
}

__global__ void k_sumlog(const int* __restrict__ deg, float* __restrict__ sum) {
    int i = blockIdx.x * 256 + threadIdx.x;
    float v = (i < NN) ? log1pf((float)deg[i]) : 0.f;
    #pragma unroll
    for (int off = 32; off > 0; off >>= 1) v += __shfl_down(v, off, 64);
    if ((threadIdx.x & 63) == 0) atomicAdd(sum, v);
}

__global__ void k_scalers(const int* __restrict__ deg, const float* __restrict__ sumlog,
                          float* __restrict__ amp, float* __restrict__ att) {
    int i = blockIdx.x * 256 + threadIdx.x;
    if (i >= NN) return;
    float avg = sumlog[0] / (float)NN;
    float degc = fmaxf((float)deg[i], 1.0f);
    float la = logf(degc + 1.0f);
    amp[i] = la / avg;
    att[i] = avg / la;
}

// Per-layer fold: K_l = embW @ encW_l @ preW_l[2H:]  (16x128)
//                 c_l = ((emb_b @ encW_l) + enc_b_l) @ preW_l[2H:] + pre_b_l (128)
__global__ void k_wprep(const float* __restrict__ embW, const float* __restrict__ emb_b,
                        const float* __restrict__ encW, const float* __restrict__ enc_b,
                        const float* __restrict__ preW, const float* __restrict__ pre_b,
                        float* __restrict__ Kc, float* __restrict__ cc) {
    int l = blockIdx.x;
    const float* encWl = encW + (size_t)l * H * H;
    const float* preW2 = preW + (size_t)l * 3 * H * H + 2 * H * H;
    __shared__ float T1[16 * H];
    __shared__ float b1[H];
    int t = threadIdx.x;
    for (int idx = t; idx < 16 * H; idx += 256) {
        int r = idx / H, j = idx % H;
        float s = 0.f;
        for (int k = 0; k < H; k++) s = fmaf(embW[r * H + k], encWl[k * H + j], s);
        T1[idx] = s;
    }
    if (t < H) {
        float s = enc_b[l * H + t];
        for (int k = 0; k < H; k++) s = fmaf(emb_b[k], encWl[k * H + t], s);
        b1[t] = s;
    }
    __syncthreads();
    for (int idx = t; idx < 16 * H; idx += 256) {
        int r = idx / H, j = idx % H;
        float s = 0.f;
        for (int k = 0; k < H; k++) s = fmaf(T1[r * H + k], preW2[k * H + j], s);
        Kc[l * 16 * H + idx] = s;
    }
    if (t < H) {
        float s = pre_b[l * H + t];
        for (int k = 0; k < H; k++) s = fmaf(b1[k], preW2[k * H + t], s);
        cc[l * H + t] = s;
    }
}

// ---------------- generic GEMM: C[plane] = A[M,K] @ B_plane[K,128] (+bias, relu) ----------------
// block: 256 thr, tile 64 rows x 128 cols; planes via blockIdx.y
__global__ __launch_bounds__(256) void k_gemm(const float* __restrict__ A, int lda, int K,
                                              Ptr3 B, float* __restrict__ C,
                                              const float* __restrict__ bias, int relu) {
    __shared__ float As[32][68];   // [kk][row], pad 68 keeps rows 16B-aligned
    __shared__ float Bs[32][128];
    const float* Bp = ptr3_get(B, blockIdx.y);
    float* Cp = C + (size_t)blockIdx.y * NN * H;
    int m0 = blockIdx.x * 64;
    int tid = threadIdx.x;
    int tx = tid & 31, ty = tid >> 5;
    float4 acc[8];
    #pragma unroll
    for (int r = 0; r < 8; r++) acc[r] = make_float4(0, 0, 0, 0);

    int f = tid & 7, r0 = tid >> 3;
    int cf = tid & 31, kr0 = tid >> 5;

    for (int k0 = 0; k0 < K; k0 += 32) {
        #pragma unroll
        for (int hh = 0; hh < 2; hh++) {
            int r = r0 + hh * 32;
            int row = m0 + r;
            float4 v = make_float4(0, 0, 0, 0);
            if (row < NN) v = *(const float4*)(A + (size_t)row * lda + k0 + f * 4);
            As[f * 4 + 0][r] = v.x; As[f * 4 + 1][r] = v.y;
            As[f * 4 + 2][r] = v.z; As[f * 4 + 3][r] = v.w;
        }
        #pragma unroll
        for (int hh = 0; hh < 4; hh++) {
            int kr = kr0 + hh * 8;
            *(float4*)&Bs[kr][cf * 4] = *(const float4*)(Bp + (size_t)(k0 + kr) * H + cf * 4);
        }
        __syncthreads();
        #pragma unroll
        for (int kk = 0; kk < 32; kk++) {
            float4 b = *(float4*)&Bs[kk][tx * 4];
            float4 a0 = *(float4*)&As[kk][ty * 8];
            float4 a1 = *(float4*)&As[kk][ty * 8 + 4];
            fma4(acc[0], a0.x, b); fma4(acc[1], a0.y, b);
            fma4(acc[2], a0.z, b); fma4(acc[3], a0.w, b);
            fma4(acc[4], a1.x, b); fma4(acc[5], a1.y, b);
            fma4(acc[6], a1.z, b); fma4(acc[7], a1.w, b);
        }
        __syncthreads();
    }
    float4 bi = make_float4(0, 0, 0, 0);
    if (bias) bi = *(const float4*)(bias + tx * 4);
    #pragma unroll
    for (int r = 0; r < 8; r++) {
        int row = m0 + ty * 8 + r;
        if (row < NN) {
            float4 o;
            o.x = acc[r].x + bi.x; o.y = acc[r].y + bi.y;
            o.z = acc[r].z + bi.z; o.w = acc[r].w + bi.w;
            if (relu) {
                o.x = fmaxf(o.x, 0.f); o.y = fmaxf(o.y, 0.f);
                o.z = fmaxf(o.z, 0.f); o.w = fmaxf(o.w, 0.f);
            }
            *(float4*)(Cp + (size_t)row * H + tx * 4) = o;
        }
    }
}

// ---------------- fused post GEMM: out = hA + agg@B1 + amp*(agg@B2) + att*(agg@B3) + post_b ----
// tile 32 rows x 128 cols x 3 planes, K=512
__global__ __launch_bounds__(256) void k_gemm2(const float* __restrict__ A,
                                               const float* __restrict__ postWl,
                                               const float* __restrict__ tmpA,
                                               const float* __restrict__ amp,
                                               const float* __restrict__ att,
                                               const float* __restrict__ pb,
                                               float* __restrict__ outp) {
    __shared__ float As[32][36];
    __shared__ float Bs[3][32][128];
    int m0 = blockIdx.x * 32;
    int tid = threadIdx.x;
    int tx = tid & 31, ty = tid >> 5;
    float4 acc[3][4];
    #pragma unroll
    for (int g = 0; g < 3; g++)
        #pragma unroll
        for (int r = 0; r < 4; r++) acc[g][r] = make_float4(0, 0, 0, 0);

    int f = tid & 7, ar = tid >> 3;

    for (int k0 = 0; k0 < 4 * H; k0 += 32) {
        {
            float4 v = make_float4(0, 0, 0, 0);
            int row = m0 + ar;
            if (row < NN) v = *(const float4*)(A + (size_t)row * 4 * H + k0 + f * 4);
            As[f * 4 + 0][ar] = v.x; As[f * 4 + 1][ar] = v.y;
            As[f * 4 + 2][ar] = v.z; As[f * 4 + 3][ar] = v.w;
        }
        #pragma unroll
        for (int g = 0; g < 3; g++) {
            const float* bp = postWl + (size_t)(H + 4 * H * g + k0) * H;
            #pragma unroll
            for (int hh = 0; hh < 4; hh++) {
                int kr = ty + hh * 8;
                *(float4*)&Bs[g][kr][tx * 4] = *(const float4*)(bp + (size_t)kr * H + tx * 4);
            }
        }
        __syncthreads();
        #pragma unroll
        for (int kk = 0; kk < 32; kk++) {
            float4 a = *(float4*)&As[kk][ty * 4];
            float4 b0 = *(float4*)&Bs[0][kk][tx * 4];
            float4 b1 = *(float4*)&Bs[1][kk][tx * 4];
            float4 b2 = *(float4*)&Bs[2][kk][tx * 4];
            fma4(acc[0][0], a.x, b0); fma4(acc[0][1], a.y, b0);
            fma4(acc[0][2], a.z, b0); fma4(acc[0][3], a.w, b0);
            fma4(acc[1][0], a.x, b1); fma4(acc[1][1], a.y, b1);
            fma4(acc[1][2], a.z, b1); fma4(acc[1][3], a.w, b1);
            fma4(acc[2][0], a.x, b2); fma4(acc[2][1], a.y, b2);
            fma4(acc[2][2], a.z, b2); fma4(acc[2][3], a.w, b2);
        }
        __syncthreads();
    }
    float4 pbv = *(const float4*)(pb + tx * 4);
    #pragma unroll
    for (int r = 0; r < 4; r++) {
        int row = m0 + ty * 4 + r;
        if (row < NN) {
            float av = amp[row], tv = att[row];
            float4 ha = *(const float4*)(tmpA + (size_t)row * H + tx * 4);
            float4 o;
            o.x = ha.x + acc[0][r].x + av * acc[1][r].x + tv * acc[2][r].x + pbv.x;
            o.y = ha.y + acc[0][r].y + av * acc[1][r].y + tv * acc[2][r].y + pbv.y;
            o.z = ha.z + acc[0][r].z + av * acc[1][r].z + tv * acc[2][r].z + pbv.z;
            o.w = ha.w + acc[0][r].w + av * acc[1][r].w + tv * acc[2][r].w + pbv.w;
            *(float4*)(outp + (size_t)row * H + tx * 4) = o;
        }
    }
}

// ---------------- aggregation: one wave per node, CSR over incoming edges ----------------
__global__ __launch_bounds__(256) void k_agg(const float* __restrict__ hWd,
                                             const float* __restrict__ hWs,
                                             const float* __restrict__ eattr,
                                             const int* __restrict__ row_ptr,
                                             const int* __restrict__ csr_src,
                                             const int* __restrict__ csr_eid,
                                             const float* __restrict__ Kl,
                                             const float* __restrict__ cl,
                                             float* __restrict__ agg) {
    int w = threadIdx.x >> 6;
    int lane = threadIdx.x & 63;
    int i = blockIdx.x * 4 + w;
    if (i >= NN) return;
    int d0 = lane * 2;
    float2 kr[16];
    #pragma unroll
    for (int k = 0; k < 16; k++) kr[k] = *(const float2*)(Kl + k * H + d0);
    float2 c2 = *(const float2*)(cl + d0);
    float2 base = *(const float2*)(hWd + (size_t)i * H + d0);
    base.x += c2.x; base.y += c2.y;
    int rs = row_ptr[i], re = row_ptr[i + 1];
    float2 s = make_float2(0, 0), q = make_float2(0, 0);
    float2 mn = make_float2(3.0e38f, 3.0e38f), mx = make_float2(-3.0e38f, -3.0e38f);
    for (int slot = rs; slot < re; slot++) {
        int sn = csr_src[slot];
        int eid = csr_eid[slot];
        const float* ep = eattr + (size_t)eid * EIN;
        float4 e0 = *(const float4*)(ep);
        float4 e1 = *(const float4*)(ep + 4);
        float4 e2 = *(const float4*)(ep + 8);
        float4 e3 = *(const float4*)(ep + 12);
        float2 hs = *(const float2*)(hWs + (size_t)sn * H + d0);
        float ax = base.x + hs.x;
        float ay = base.y + hs.y;
        ax = fmaf(e0.x, kr[0].x, ax);  ay = fmaf(e0.x, kr[0].y, ay);
        ax = fmaf(e0.y, kr[1].x, ax);  ay = fmaf(e0.y, kr[1].y, ay);
        ax = fmaf(e0.z, kr[2].x, ax);  ay = fmaf(e0.z, kr[2].y, ay);
        ax = fmaf(e0.w, kr[3].x, ax);  ay = fmaf(e0.w, kr[3].y, ay);
        ax = fmaf(e1.x, kr[4].x, ax);  ay = fmaf(e1.x, kr[4].y, ay);
        ax = fmaf(e1.y, kr[5].x, ax);  ay = fmaf(e1.y, kr[5].y, ay);
        ax = fmaf(e1.z, kr[6].x, ax);  ay = fmaf(e1.z, kr[6].y, ay);
        ax = fmaf(e1.w, kr[7].x, ax);  ay = fmaf(e1.w, kr[7].y, ay);
        ax = fmaf(e2.x, kr[8].x, ax);  ay = fmaf(e2.x, kr[8].y, ay);
        ax = fmaf(e2.y, kr[9].x, ax);  ay = fmaf(e2.y, kr[9].y, ay);
        ax = fmaf(e2.z, kr[10].x, ax); ay = fmaf(e2.z, kr[10].y, ay);
        ax = fmaf(e2.w, kr[11].x, ax); ay = fmaf(e2.w, kr[11].y, ay);
        ax = fmaf(e3.x, kr[12].x, ax); ay = fmaf(e3.x, kr[12].y, ay);
        ax = fmaf(e3.y, kr[13].x, ax); ay = fmaf(e3.y, kr[13].y, ay);
        ax = fmaf(e3.z, kr[14].x, ax); ay = fmaf(e3.z, kr[14].y, ay);
        ax = fmaf(e3.w, kr[15].x, ax); ay = fmaf(e3.w, kr[15].y, ay);
        s.x += ax; s.y += ay;
        q.x = fmaf(ax, ax, q.x); q.y = fmaf(ay, ay, q.y);
        mn.x = fminf(mn.x, ax); mn.y = fminf(mn.y, ay);
        mx.x = fmaxf(mx.x, ax); mx.y = fmaxf(mx.y, ay);
    }
    int dg = re - rs;
    float dinv = 1.0f / fmaxf((float)dg, 1.0f);
    float2 mean = make_float2(s.x * dinv, s.y * dinv);
    float2 m2v = make_float2(q.x * dinv, q.y * dinv);
    float2 sd;
    sd.x = sqrtf(fmaxf(m2v.x - mean.x * mean.x, 0.f) + EPSV);
    sd.y = sqrtf(fmaxf(m2v.y - mean.y * mean.y, 0.f) + EPSV);
    if (dg == 0) { mn = make_float2(0, 0); mx = make_float2(0, 0); }
    float* ap = agg + (size_t)i * (4 * H) + d0;
    *(float2*)(ap)         = mean;
    *(float2*)(ap + H)     = mn;
    *(float2*)(ap + 2 * H) = mx;
    *(float2*)(ap + 3 * H) = sd;
}

// ---------------- pooling + head ----------------
__device__ __forceinline__ int lbound(const int* a, int n, int v) {
    int lo = 0, hi = n;
    while (lo < hi) { int m = (lo + hi) >> 1; if (a[m] < v) lo = m + 1; else hi = m; }
    return lo;
}

__global__ __launch_bounds__(256) void k_pool(const float* __restrict__ h,
                                              const int* __restrict__ batch,
                                              const float* __restrict__ headW,
                                              const float* __restrict__ headb,
                                              float* __restrict__ out) {
    __shared__ float sm[256];
    int g = blockIdx.x;
    int t = threadIdx.x;
    int col = t & 127;
    int half = t >> 7;
    int lo = lbound(batch, NN, g);
    int hi = lbound(batch, NN, g + 1);
    int mid = lo + ((hi - lo) >> 1);
    int b0 = half ? mid : lo;
    int b1 = half ? hi : mid;
    float acc = 0.f;
    for (int i = b0; i < b1; i++) acc += h[(size_t)i * H + col];
    sm[t] = acc;
    __syncthreads();
    if (t < 128) sm[t] += sm[t + 128];
    __syncthreads();
    if (t < NOUT) {
        float r = headb[t];
        for (int j = 0; j < H; j++) r = fmaf(sm[j], headW[j * NOUT + t], r);
        out[g * NOUT + t] = r;
    }
}

// ---------------- launch ----------------
extern "C" void kernel_launch(void* const* d_in, const int* in_sizes, int n_in,
                              void* d_out, int out_size, void* d_ws, size_t ws_size,
                              hipStream_t stream) {
    const float* x          = (const float*)d_in[0];
    const float* edge_attr  = (const float*)d_in[1];
    const int*   src        = (const int*)d_in[2];
    const int*   dst        = (const int*)d_in[3];
    const int*   batch      = (const int*)d_in[4];
    const float* node_emb_W = (const float*)d_in[5];
    const float* node_emb_b = (const float*)d_in[6];
    const float* edge_emb_W = (const float*)d_in[7];
    const float* edge_emb_b = (const float*)d_in[8];
    const float* edge_enc_W = (const float*)d_in[9];
    const float* edge_enc_b = (const float*)d_in[10];
    const float* pre_W      = (const float*)d_in[11];
    const float* pre_b      = (const float*)d_in[12];
    const float* post_W     = (const float*)d_in[13];
    const float* post_b     = (const float*)d_in[14];
    const float* lin_W      = (const float*)d_in[15];
    const float* lin_b      = (const float*)d_in[16];
    const float* head_W     = (const float*)d_in[17];
    const float* head_b     = (const float*)d_in[18];
    float* out = (float*)d_out;

    char* wp = (char*)d_ws;
    auto carve = [&](size_t bytes) -> char* {
        char* r = wp;
        wp += (bytes + 255) & ~(size_t)255;
        return r;
    };
    int*   deg     = (int*)carve((size_t)NN * 4);
    int*   cursor  = (int*)carve((size_t)NN * 4);
    float* sumlog  = (float*)carve(4);
    int*   partial = (int*)carve(256 * 4);
    int*   row_ptr = (int*)carve((size_t)(NN + 1) * 4);
    int*   csr_src = (int*)carve((size_t)NE * 4);
    int*   csr_eid = (int*)carve((size_t)NE * 4);
    float* amp     = (float*)carve((size_t)NN * 4);
    float* att     = (float*)carve((size_t)NN * 4);
    float* Kc      = (float*)carve((size_t)NL * 16 * H * 4);
    float* cc      = (float*)carve((size_t)NL * H * 4);
    float* h0      = (float*)carve((size_t)NN * H * 4);
    float* h1      = (float*)carve((size_t)NN * H * 4);
    float* planes  = (float*)carve((size_t)3 * NN * H * 4);
    float* aggb    = (float*)carve((size_t)NN * 4 * H * 4);

    const size_t NP = (size_t)NN * H;

    hipMemsetAsync(deg, 0, (size_t)NN * 4, stream);
    hipMemsetAsync(cursor, 0, (size_t)NN * 4, stream);
    hipMemsetAsync(sumlog, 0, 4, stream);

    k_hist<<<(NE + 255) / 256, 256, 0, stream>>>(dst, deg);
    k_scan1<<<NBLK, 256, 0, stream>>>(deg, partial);
    k_scan2<<<1, 256, 0, stream>>>(partial, row_ptr, NBLK);
    k_scan3<<<NBLK, 256, 0, stream>>>(deg, partial, row_ptr);
    k_fill<<<(NE + 255) / 256, 256, 0, stream>>>(src, dst, row_ptr, cursor, csr_src, csr_eid);
    k_sumlog<<<NBLK, 256, 0, stream>>>(deg, sumlog);
    k_scalers<<<NBLK, 256, 0, stream>>>(deg, sumlog, amp, att);
    k_wprep<<<NL, 256, 0, stream>>>(edge_emb_W, edge_emb_b, edge_enc_W, edge_enc_b,
                                    pre_W, pre_b, Kc, cc);

    // h0 = x @ node_emb_W + b
    k_gemm<<<dim3(GB, 1), 256, 0, stream>>>(x, FIN, FIN, Ptr3{node_emb_W, nullptr, nullptr},
                                            h0, node_emb_b, 0);

    float* hc = h0;
    float* hn = h1;
    for (int l = 0; l < NL; l++) {
        const float* preWl  = pre_W + (size_t)l * 3 * H * H;
        const float* postWl = post_W + (size_t)l * 13 * H * H;
        // planes: [hW_dst | hW_src | hA]
        k_gemm<<<dim3(GB, 3), 256, 0, stream>>>(hc, H, H,
                                                Ptr3{preWl, preWl + H * H, postWl},
                                                planes, nullptr, 0);
        k_agg<<<(NN + 3) / 4, 256, 0, stream>>>(planes, planes + NP, edge_attr,
                                                row_ptr, csr_src, csr_eid,
                                                Kc + (size_t)l * 16 * H, cc + (size_t)l * H,
                                                aggb);
        // out_pre (reuses plane0) = hA + agg@B1 + amp*agg@B2 + att*agg@B3 + post_b
        k_gemm2<<<(NN + 31) / 32, 256, 0, stream>>>(aggb, postWl, planes + 2 * NP,
                                                    amp, att, post_b + (size_t)l * H, planes);
        // h_next = relu(out_pre @ lin_W + lin_b)
        k_gemm<<<dim3(GB, 1), 256, 0, stream>>>(planes, H, H,
                                                Ptr3{lin_W + (size_t)l * H * H, nullptr, nullptr},
                                                hn, lin_b + (size_t)l * H, 1);
        float* tswap = hc; hc = hn; hn = tswap;
    }

    k_pool<<<NG, 256, 0, stream>>>(hc, batch, head_W, head_b, out);
}

// Round 2
// 1467.565 us; speedup vs baseline: 1.6452x; 1.6452x over previous
//
#include <hip/hip_runtime.h>

#define NN 50000
#define NE 400000
#define FIN 64
#define EIN 16
#define H 128
#define NL 4
#define NG 256
#define NOUT 12
#define EPSV 1e-5f

#define SB 256
#define NBLK ((NN + SB - 1) / SB)    // 196
#define GB2 ((NN + 127) / 128)       // 391 (128-row MFMA tiles)

typedef short bf16x8 __attribute__((ext_vector_type(8)));
typedef float f32x4 __attribute__((ext_vector_type(4)));

__device__ __forceinline__ unsigned short f2bf(float f) {
    unsigned u = __float_as_uint(f);
    u += 0x7fffu + ((u >> 16) & 1u);
    return (unsigned short)(u >> 16);
}

__device__ __forceinline__ unsigned scale_pk(unsigned u, float s) {
    float lo = __uint_as_float(u << 16);
    float hi = __uint_as_float(u & 0xffff0000u);
    lo *= s; hi *= s;
    return (unsigned)f2bf(lo) | ((unsigned)f2bf(hi) << 16);
}

// ---------------- setup kernels ----------------
__global__ void k_hist(const int* __restrict__ dst, int* __restrict__ deg) {
    int e = blockIdx.x * 256 + threadIdx.x;
    if (e < NE) atomicAdd(&deg[dst[e]], 1);
}

__global__ void k_scan1(const int* __restrict__ deg, int* __restrict__ partial) {
    __shared__ int sm[256];
    int i = blockIdx.x * 256 + threadIdx.x;
    sm[threadIdx.x] = (i < NN) ? deg[i] : 0;
    __syncthreads();
    for (int s = 128; s > 0; s >>= 1) {
        if (threadIdx.x < s) sm[threadIdx.x] += sm[threadIdx.x + s];
        __syncthreads();
    }
    if (threadIdx.x == 0) partial[blockIdx.x] = sm[0];
}

__global__ void k_scan2(int* __restrict__ partial, int* __restrict__ row_ptr, int nblk) {
    __shared__ int sm[256];
    int t = threadIdx.x;
    sm[t] = (t < nblk) ? partial[t] : 0;
    __syncthreads();
    for (int off = 1; off < 256; off <<= 1) {
        int v = (t >= off) ? sm[t - off] : 0;
        __syncthreads();
        sm[t] += v;
        __syncthreads();
    }
    int excl = (t == 0) ? 0 : sm[t - 1];
    if (t < nblk) partial[t] = excl;
    if (t == 0) row_ptr[0] = 0;
}

__global__ void k_scan3(const int* __restrict__ deg, const int* __restrict__ partial,
                        int* __restrict__ row_ptr) {
    __shared__ int sm[256];
    int t = threadIdx.x;
    int i = blockIdx.x * 256 + t;
    sm[t] = (i < NN) ? deg[i] : 0;
    __syncthreads();
    for (int off = 1; off < 256; off <<= 1) {
        int v = (t >= off) ? sm[t - off] : 0;
        __syncthreads();
        sm[t] += v;
        __syncthreads();
    }
    if (i < NN) row_ptr[i + 1] = partial[blockIdx.x] + sm[t];
}

__global__ void k_fill(const int* __restrict__ src, const int* __restrict__ dst,
                       const int* __restrict__ row_ptr, int* __restrict__ cursor,
                       int* __restrict__ csr_src, int* __restrict__ csr_eid) {
    int e = blockIdx.x * 256 + threadIdx.x;
    if (e >= NE) return;
    int d = dst[e];
    int pos = atomicAdd(&cursor[d], 1);
    int slot = row_ptr[d] + pos;
    csr_src[slot] = src[e];
    csr_eid[slot] = e;
}

__global__ void k_sumlog(const int* __restrict__ deg, float* __restrict__ sum) {
    int i = blockIdx.x * 256 + threadIdx.x;
    float v = (i < NN) ? log1pf((float)deg[i]) : 0.f;
    #pragma unroll
    for (int off = 32; off > 0; off >>= 1) v += __shfl_down(v, off, 64);
    if ((threadIdx.x & 63) == 0) atomicAdd(sum, v);
}

__global__ void k_scalers(const int* __restrict__ deg, const float* __restrict__ sumlog,
                          float* __restrict__ amp, float* __restrict__ att) {
    int i = blockIdx.x * 256 + threadIdx.x;
    if (i >= NN) return;
    float avg = sumlog[0] / (float)NN;
    float degc = fmaxf((float)deg[i], 1.0f);
    float la = logf(degc + 1.0f);
    amp[i] = la / avg;
    att[i] = avg / la;
}

// Per-layer fold: K_l = embW @ encW_l @ preW_l[2H:]  (16x128)
__global__ void k_wprep(const float* __restrict__ embW, const float* __restrict__ emb_b,
                        const float* __restrict__ encW, const float* __restrict__ enc_b,
                        const float* __restrict__ preW, const float* __restrict__ pre_b,
                        float* __restrict__ Kc, float* __restrict__ cc) {
    int l = blockIdx.x;
    const float* encWl = encW + (size_t)l * H * H;
    const float* preW2 = preW + (size_t)l * 3 * H * H + 2 * H * H;
    __shared__ float T1[16 * H];
    __shared__ float b1[H];
    int t = threadIdx.x;
    for (int idx = t; idx < 16 * H; idx += 256) {
        int r = idx / H, j = idx % H;
        float s = 0.f;
        for (int k = 0; k < H; k++) s = fmaf(embW[r * H + k], encWl[k * H + j], s);
        T1[idx] = s;
    }
    if (t < H) {
        float s = enc_b[l * H + t];
        for (int k = 0; k < H; k++) s = fmaf(emb_b[k], encWl[k * H + t], s);
        b1[t] = s;
    }
    __syncthreads();
    for (int idx = t; idx < 16 * H; idx += 256) {
        int r = idx / H, j = idx % H;
        float s = 0.f;
        for (int k = 0; k < H; k++) s = fmaf(T1[r * H + k], preW2[k * H + j], s);
        Kc[l * 16 * H + idx] = s;
    }
    if (t < H) {
        float s = pre_b[l * H + t];
        for (int k = 0; k < H; k++) s = fmaf(b1[k], preW2[k * H + t], s);
        cc[l * H + t] = s;
    }
}

// ---------------- weight transpose+cast: D[n][k] = bf16(S[k][n]), S has 128 cols ----------------
struct TD { const float* S; unsigned short* D; int K; };
struct TDs { TD t[21]; };

__global__ void k_prepw(TDs p) {
    TD d = p.t[blockIdx.y];
    int idx = blockIdx.x * 256 + threadIdx.x;
    int total = d.K << 7;
    if (idx < total) {
        int k = idx >> 7, n = idx & 127;
        d.D[(size_t)n * d.K + k] = f2bf(d.S[(size_t)k * 128 + n]);
    }
}

__global__ void k_cast(const float* __restrict__ S, unsigned short* __restrict__ D, int n) {
    int i = blockIdx.x * 256 + threadIdx.x;
    if (i < n) D[i] = f2bf(S[i]);
}

// ---------------- bf16 MFMA GEMM ----------------
// C[M,128] = A[M,K'] @ B[K',128] via Bt[128][K'] (bf16, pre-transposed).
// Block: 256 thr = 2x2 waves, tile 128 rows x 128 cols, each wave 64x64 (4x4 frags 16x16x32).
// scaleMode: virtual K'=1536 from lda=512 agg with per-region row scaler (1, amp, att).
// Epilogue: +bias, +addC (fp32), relu, dual store fp32/bf16.
__global__ __launch_bounds__(256, 3) void k_mgemm(
    const unsigned short* __restrict__ A, int lda, int K, int nch,
    const unsigned short* __restrict__ Bt,
    const float* __restrict__ bias, const float* __restrict__ addC,
    float* __restrict__ outF, unsigned short* __restrict__ outB,
    int relu, int scaleMode,
    const float* __restrict__ amp, const float* __restrict__ att)
{
    __shared__ unsigned short As[128][72];   // +8 pad: 2-way bank aliasing only (free)
    __shared__ unsigned short Bs[128][72];
    const unsigned short* Btp = Bt + (size_t)blockIdx.y * 128 * K;
    int m0 = blockIdx.x * 128;
    int tid = threadIdx.x;
    int wave = tid >> 6, lane = tid & 63;
    int wr = wave >> 1, wc = wave & 1;
    int ln = lane & 15, q = lane >> 4;

    f32x4 acc[4][4];
    #pragma unroll
    for (int a = 0; a < 4; a++)
        #pragma unroll
        for (int b = 0; b < 4; b++) acc[a][b] = (f32x4){0.f, 0.f, 0.f, 0.f};

    for (int c = 0; c < nch; c++) {
        int g = scaleMode ? (c >> 3) : 0;
        int acol = scaleMode ? ((c & 7) * 64) : c * 64;
        int bcol = c * 64;
        #pragma unroll
        for (int i0 = 0; i0 < 4; i0++) {
            int i = tid + i0 * 256;
            int row = i >> 3, seg = i & 7;
            uint4 bv = *(const uint4*)(Btp + (size_t)row * K + bcol + seg * 8);
            *(uint4*)(&Bs[row][seg * 8]) = bv;
            int rowg = m0 + row;
            uint4 av = make_uint4(0, 0, 0, 0);
            if (rowg < NN) {
                av = *(const uint4*)(A + (size_t)rowg * lda + acol + seg * 8);
                if (g) {
                    float s = (g == 1) ? amp[rowg] : att[rowg];
                    av.x = scale_pk(av.x, s); av.y = scale_pk(av.y, s);
                    av.z = scale_pk(av.z, s); av.w = scale_pk(av.w, s);
                }
            }
            *(uint4*)(&As[row][seg * 8]) = av;
        }
        __syncthreads();
        #pragma unroll
        for (int kq = 0; kq < 2; kq++) {
            bf16x8 af[4], bfr[4];
            #pragma unroll
            for (int f = 0; f < 4; f++) {
                af[f]  = *(const bf16x8*)(&As[wr * 64 + f * 16 + ln][kq * 32 + q * 8]);
                bfr[f] = *(const bf16x8*)(&Bs[wc * 64 + f * 16 + ln][kq * 32 + q * 8]);
            }
            #pragma unroll
            for (int fr = 0; fr < 4; fr++)
                #pragma unroll
                for (int fc = 0; fc < 4; fc++)
                    acc[fr][fc] = __builtin_amdgcn_mfma_f32_16x16x32_bf16(
                        af[fr], bfr[fc], acc[fr][fc], 0, 0, 0);
        }
        __syncthreads();
    }

    float* outFp = outF ? outF + (size_t)blockIdx.y * NN * H : nullptr;
    #pragma unroll
    for (int fc = 0; fc < 4; fc++) {
        int col = wc * 64 + fc * 16 + ln;
        float bv = bias ? bias[col] : 0.f;
        #pragma unroll
        for (int fr = 0; fr < 4; fr++) {
            int rowb = m0 + wr * 64 + fr * 16 + q * 4;
            #pragma unroll
            for (int r = 0; r < 4; r++) {
                int rowg = rowb + r;
                if (rowg < NN) {
                    float v = acc[fr][fc][r] + bv;
                    if (addC) v += addC[(size_t)rowg * H + col];
                    if (relu) v = fmaxf(v, 0.f);
                    if (outFp) outFp[(size_t)rowg * H + col] = v;
                    if (outB) outB[(size_t)rowg * H + col] = f2bf(v);
                }
            }
        }
    }
}

// ---------------- aggregation: one wave per node, CSR over incoming edges ----------------
__global__ __launch_bounds__(256) void k_agg(const float* __restrict__ hWd,
                                             const float* __restrict__ hWs,
                                             const float* __restrict__ eattr,
                                             const int* __restrict__ row_ptr,
                                             const int* __restrict__ csr_src,
                                             const int* __restrict__ csr_eid,
                                             const float* __restrict__ Kl,
                                             const float* __restrict__ cl,
                                             unsigned short* __restrict__ agg) {
    int w = threadIdx.x >> 6;
    int lane = threadIdx.x & 63;
    int i = blockIdx.x * 4 + w;
    if (i >= NN) return;
    int d0 = lane * 2;
    float2 kr[16];
    #pragma unroll
    for (int k = 0; k < 16; k++) kr[k] = *(const float2*)(Kl + k * H + d0);
    float2 c2 = *(const float2*)(cl + d0);
    float2 base = *(const float2*)(hWd + (size_t)i * H + d0);
    base.x += c2.x; base.y += c2.y;
    int rs = row_ptr[i], re = row_ptr[i + 1];
    float2 s = make_float2(0, 0), qq = make_float2(0, 0);
    float2 mn = make_float2(3.0e38f, 3.0e38f), mx = make_float2(-3.0e38f, -3.0e38f);
    for (int slot = rs; slot < re; slot++) {
        int sn = csr_src[slot];
        int eid = csr_eid[slot];
        const float* ep = eattr + (size_t)eid * EIN;
        float4 e0 = *(const float4*)(ep);
        float4 e1 = *(const float4*)(ep + 4);
        float4 e2 = *(const float4*)(ep + 8);
        float4 e3 = *(const float4*)(ep + 12);
        float2 hs = *(const float2*)(hWs + (size_t)sn * H + d0);
        float ax = base.x + hs.x;
        float ay = base.y + hs.y;
        ax = fmaf(e0.x, kr[0].x, ax);  ay = fmaf(e0.x, kr[0].y, ay);
        ax = fmaf(e0.y, kr[1].x, ax);  ay = fmaf(e0.y, kr[1].y, ay);
        ax = fmaf(e0.z, kr[2].x, ax);  ay = fmaf(e0.z, kr[2].y, ay);
        ax = fmaf(e0.w, kr[3].x, ax);  ay = fmaf(e0.w, kr[3].y, ay);
        ax = fmaf(e1.x, kr[4].x, ax);  ay = fmaf(e1.x, kr[4].y, ay);
        ax = fmaf(e1.y, kr[5].x, ax);  ay = fmaf(e1.y, kr[5].y, ay);
        ax = fmaf(e1.z, kr[6].x, ax);  ay = fmaf(e1.z, kr[6].y, ay);
        ax = fmaf(e1.w, kr[7].x, ax);  ay = fmaf(e1.w, kr[7].y, ay);
        ax = fmaf(e2.x, kr[8].x, ax);  ay = fmaf(e2.x, kr[8].y, ay);
        ax = fmaf(e2.y, kr[9].x, ax);  ay = fmaf(e2.y, kr[9].y, ay);
        ax = fmaf(e2.z, kr[10].x, ax); ay = fmaf(e2.z, kr[10].y, ay);
        ax = fmaf(e2.w, kr[11].x, ax); ay = fmaf(e2.w, kr[11].y, ay);
        ax = fmaf(e3.x, kr[12].x, ax); ay = fmaf(e3.x, kr[12].y, ay);
        ax = fmaf(e3.y, kr[13].x, ax); ay = fmaf(e3.y, kr[13].y, ay);
        ax = fmaf(e3.z, kr[14].x, ax); ay = fmaf(e3.z, kr[14].y, ay);
        ax = fmaf(e3.w, kr[15].x, ax); ay = fmaf(e3.w, kr[15].y, ay);
        s.x += ax; s.y += ay;
        qq.x = fmaf(ax, ax, qq.x); qq.y = fmaf(ay, ay, qq.y);
        mn.x = fminf(mn.x, ax); mn.y = fminf(mn.y, ay);
        mx.x = fmaxf(mx.x, ax); mx.y = fmaxf(mx.y, ay);
    }
    int dg = re - rs;
    float dinv = 1.0f / fmaxf((float)dg, 1.0f);
    float2 mean = make_float2(s.x * dinv, s.y * dinv);
    float2 m2v = make_float2(qq.x * dinv, qq.y * dinv);
    float2 sd;
    sd.x = sqrtf(fmaxf(m2v.x - mean.x * mean.x, 0.f) + EPSV);
    sd.y = sqrtf(fmaxf(m2v.y - mean.y * mean.y, 0.f) + EPSV);
    if (dg == 0) { mn = make_float2(0, 0); mx = make_float2(0, 0); }
    unsigned short* ap = agg + (size_t)i * 512 + d0;
    *(unsigned*)(ap)       = (unsigned)f2bf(mean.x) | ((unsigned)f2bf(mean.y) << 16);
    *(unsigned*)(ap + 128) = (unsigned)f2bf(mn.x)   | ((unsigned)f2bf(mn.y)   << 16);
    *(unsigned*)(ap + 256) = (unsigned)f2bf(mx.x)   | ((unsigned)f2bf(mx.y)   << 16);
    *(unsigned*)(ap + 384) = (unsigned)f2bf(sd.x)   | ((unsigned)f2bf(sd.y)   << 16);
}

// ---------------- pooling + head ----------------
__device__ __forceinline__ int lbound(const int* a, int n, int v) {
    int lo = 0, hi = n;
    while (lo < hi) { int m = (lo + hi) >> 1; if (a[m] < v) lo = m + 1; else hi = m; }
    return lo;
}

__global__ __launch_bounds__(256) void k_pool(const float* __restrict__ h,
                                              const int* __restrict__ batch,
                                              const float* __restrict__ headW,
                                              const float* __restrict__ headb,
                                              float* __restrict__ out) {
    __shared__ float sm[256];
    int g = blockIdx.x;
    int t = threadIdx.x;
    int col = t & 127;
    int half = t >> 7;
    int lo = lbound(batch, NN, g);
    int hi = lbound(batch, NN, g + 1);
    int mid = lo + ((hi - lo) >> 1);
    int b0 = half ? mid : lo;
    int b1 = half ? hi : mid;
    float acc = 0.f;
    for (int i = b0; i < b1; i++) acc += h[(size_t)i * H + col];
    sm[t] = acc;
    __syncthreads();
    if (t < 128) sm[t] += sm[t + 128];
    __syncthreads();
    if (t < NOUT) {
        float r = headb[t];
        for (int j = 0; j < H; j++) r = fmaf(sm[j], headW[j * NOUT + t], r);
        out[g * NOUT + t] = r;
    }
}

// ---------------- launch ----------------
extern "C" void kernel_launch(void* const* d_in, const int* in_sizes, int n_in,
                              void* d_out, int out_size, void* d_ws, size_t ws_size,
                              hipStream_t stream) {
    const float* x          = (const float*)d_in[0];
    const float* edge_attr  = (const float*)d_in[1];
    const int*   src        = (const int*)d_in[2];
    const int*   dst        = (const int*)d_in[3];
    const int*   batch      = (const int*)d_in[4];
    const float* node_emb_W = (const float*)d_in[5];
    const float* node_emb_b = (const float*)d_in[6];
    const float* edge_emb_W = (const float*)d_in[7];
    const float* edge_emb_b = (const float*)d_in[8];
    const float* edge_enc_W = (const float*)d_in[9];
    const float* edge_enc_b = (const float*)d_in[10];
    const float* pre_W      = (const float*)d_in[11];
    const float* pre_b      = (const float*)d_in[12];
    const float* post_W     = (const float*)d_in[13];
    const float* post_b     = (const float*)d_in[14];
    const float* lin_W      = (const float*)d_in[15];
    const float* lin_b      = (const float*)d_in[16];
    const float* head_W     = (const float*)d_in[17];
    const float* head_b     = (const float*)d_in[18];
    float* out = (float*)d_out;

    char* wp = (char*)d_ws;
    auto carve = [&](size_t bytes) -> char* {
        char* r = wp;
        wp += (bytes + 255) & ~(size_t)255;
        return r;
    };
    int*   deg     = (int*)carve((size_t)NN * 4);
    int*   cursor  = (int*)carve((size_t)NN * 4);
    float* sumlog  = (float*)carve(4);
    int*   partial = (int*)carve(256 * 4);
    int*   row_ptr = (int*)carve((size_t)(NN + 1) * 4);
    int*   csr_src = (int*)carve((size_t)NE * 4);
    int*   csr_eid = (int*)carve((size_t)NE * 4);
    float* amp     = (float*)carve((size_t)NN * 4);
    float* att     = (float*)carve((size_t)NN * 4);
    float* Kc      = (float*)carve((size_t)NL * 16 * H * 4);
    float* cc      = (float*)carve((size_t)NL * H * 4);
    unsigned short* xb     = (unsigned short*)carve((size_t)NN * FIN * 2);
    unsigned short* embWt  = (unsigned short*)carve((size_t)H * FIN * 2);
    unsigned short* Wt3    = (unsigned short*)carve((size_t)NL * 3 * H * H * 2);
    unsigned short* postWt = (unsigned short*)carve((size_t)NL * H * 12 * H * 2);
    unsigned short* linWt  = (unsigned short*)carve((size_t)NL * H * H * 2);
    float* hf      = (float*)carve((size_t)NN * H * 4);
    unsigned short* hb = (unsigned short*)carve((size_t)NN * H * 2);
    unsigned short* ob = (unsigned short*)carve((size_t)NN * H * 2);
    float* planes  = (float*)carve((size_t)3 * NN * H * 4);
    unsigned short* aggb = (unsigned short*)carve((size_t)NN * 4 * H * 2);

    const size_t NP = (size_t)NN * H;

    hipMemsetAsync(deg, 0, (size_t)NN * 4, stream);
    hipMemsetAsync(cursor, 0, (size_t)NN * 4, stream);
    hipMemsetAsync(sumlog, 0, 4, stream);

    k_hist<<<(NE + 255) / 256, 256, 0, stream>>>(dst, deg);
    k_scan1<<<NBLK, 256, 0, stream>>>(deg, partial);
    k_scan2<<<1, 256, 0, stream>>>(partial, row_ptr, NBLK);
    k_scan3<<<NBLK, 256, 0, stream>>>(deg, partial, row_ptr);
    k_fill<<<(NE + 255) / 256, 256, 0, stream>>>(src, dst, row_ptr, cursor, csr_src, csr_eid);
    k_sumlog<<<NBLK, 256, 0, stream>>>(deg, sumlog);
    k_scalers<<<NBLK, 256, 0, stream>>>(deg, sumlog, amp, att);
    k_wprep<<<NL, 256, 0, stream>>>(edge_emb_W, edge_emb_b, edge_enc_W, edge_enc_b,
                                    pre_W, pre_b, Kc, cc);

    // weight transpose+cast descriptor table
    TDs tds;
    int nd = 0;
    tds.t[nd++] = TD{node_emb_W, embWt, FIN};
    for (int l = 0; l < NL; l++) {
        tds.t[nd++] = TD{pre_W + (size_t)l * 3 * H * H,           Wt3 + (size_t)(l * 3 + 0) * H * H, H};
        tds.t[nd++] = TD{pre_W + (size_t)l * 3 * H * H + H * H,   Wt3 + (size_t)(l * 3 + 1) * H * H, H};
        tds.t[nd++] = TD{post_W + (size_t)l * 13 * H * H,         Wt3 + (size_t)(l * 3 + 2) * H * H, H};
        tds.t[nd++] = TD{post_W + (size_t)l * 13 * H * H + H * H, postWt + (size_t)l * H * 12 * H,   12 * H};
        tds.t[nd++] = TD{lin_W + (size_t)l * H * H,               linWt + (size_t)l * H * H,         H};
    }
    k_prepw<<<dim3(768, 21), 256, 0, stream>>>(tds);
    k_cast<<<(NN * FIN + 255) / 256, 256, 0, stream>>>(x, xb, NN * FIN);

    // h = x @ node_emb_W + b  (bf16 out only)
    k_mgemm<<<dim3(GB2, 1), 256, 0, stream>>>(xb, FIN, FIN, 1, embWt, node_emb_b,
                                              nullptr, nullptr, hb, 0, 0, nullptr, nullptr);

    for (int l = 0; l < NL; l++) {
        // planes fp32: [hW_dst | hW_src | hA]
        k_mgemm<<<dim3(GB2, 3), 256, 0, stream>>>(hb, H, H, 2,
                                                  Wt3 + (size_t)l * 3 * H * H,
                                                  nullptr, nullptr, planes, nullptr,
                                                  0, 0, nullptr, nullptr);
        k_agg<<<(NN + 3) / 4, 256, 0, stream>>>(planes, planes + NP, edge_attr,
                                                row_ptr, csr_src, csr_eid,
                                                Kc + (size_t)l * 16 * H, cc + (size_t)l * H,
                                                aggb);
        // out_pre = [agg|amp*agg|att*agg] @ postW[H:] + hA + post_b  (virtual K=1536)
        k_mgemm<<<dim3(GB2, 1), 256, 0, stream>>>(aggb, 4 * H, 12 * H, 24,
                                                  postWt + (size_t)l * H * 12 * H,
                                                  post_b + (size_t)l * H, planes + 2 * NP,
                                                  nullptr, ob, 0, 1, amp, att);
        // h = relu(out_pre @ lin_W + lin_b)  (dual fp32+bf16)
        k_mgemm<<<dim3(GB2, 1), 256, 0, stream>>>(ob, H, H, 2,
                                                  linWt + (size_t)l * H * H,
                                                  lin_b + (size_t)l * H, nullptr,
                                                  hf, hb, 1, 0, nullptr, nullptr);
    }

    k_pool<<<NG, 256, 0, stream>>>(hf, batch, head_W, head_b, out);
}

// Round 4
// 1294.732 us; speedup vs baseline: 1.8648x; 1.1335x over previous
//
#include <hip/hip_runtime.h>

#define NN 50000
#define NE 400000
#define FIN 64
#define EIN 16
#define H 128
#define NL 4
#define NG 256
#define NOUT 12
#define EPSV 1e-5f

#define SB 256
#define NBLK ((NN + SB - 1) / SB)    // 196
#define GB2 ((NN + 127) / 128)       // 391 (128-row MFMA tiles)

typedef short bf16x8 __attribute__((ext_vector_type(8)));
typedef float f32x4 __attribute__((ext_vector_type(4)));

__device__ __forceinline__ unsigned short f2bf(float f) {
    unsigned u = __float_as_uint(f);
    u += 0x7fffu + ((u >> 16) & 1u);
    return (unsigned short)(u >> 16);
}

__device__ __forceinline__ float bflo(unsigned u) { return __uint_as_float(u << 16); }
__device__ __forceinline__ float bfhi(unsigned u) { return __uint_as_float(u & 0xffff0000u); }

__device__ __forceinline__ unsigned scale_pk(unsigned u, float s) {
    float lo = bflo(u) * s;
    float hi = bfhi(u) * s;
    return (unsigned)f2bf(lo) | ((unsigned)f2bf(hi) << 16);
}

// ---------------- setup kernels ----------------
__global__ void k_hist(const int* __restrict__ dst, int* __restrict__ deg) {
    int e = blockIdx.x * 256 + threadIdx.x;
    if (e < NE) atomicAdd(&deg[dst[e]], 1);
}

__global__ void k_scan1(const int* __restrict__ deg, int* __restrict__ partial) {
    __shared__ int sm[256];
    int i = blockIdx.x * 256 + threadIdx.x;
    sm[threadIdx.x] = (i < NN) ? deg[i] : 0;
    __syncthreads();
    for (int s = 128; s > 0; s >>= 1) {
        if (threadIdx.x < s) sm[threadIdx.x] += sm[threadIdx.x + s];
        __syncthreads();
    }
    if (threadIdx.x == 0) partial[blockIdx.x] = sm[0];
}

__global__ void k_scan2(int* __restrict__ partial, int* __restrict__ row_ptr, int nblk) {
    __shared__ int sm[256];
    int t = threadIdx.x;
    sm[t] = (t < nblk) ? partial[t] : 0;
    __syncthreads();
    for (int off = 1; off < 256; off <<= 1) {
        int v = (t >= off) ? sm[t - off] : 0;
        __syncthreads();
        sm[t] += v;
        __syncthreads();
    }
    int excl = (t == 0) ? 0 : sm[t - 1];
    if (t < nblk) partial[t] = excl;
    if (t == 0) row_ptr[0] = 0;
}

__global__ void k_scan3(const int* __restrict__ deg, const int* __restrict__ partial,
                        int* __restrict__ row_ptr) {
    __shared__ int sm[256];
    int t = threadIdx.x;
    int i = blockIdx.x * 256 + t;
    sm[t] = (i < NN) ? deg[i] : 0;
    __syncthreads();
    for (int off = 1; off < 256; off <<= 1) {
        int v = (t >= off) ? sm[t - off] : 0;
        __syncthreads();
        sm[t] += v;
        __syncthreads();
    }
    if (i < NN) row_ptr[i + 1] = partial[blockIdx.x] + sm[t];
}

__global__ void k_fill(const int* __restrict__ src, const int* __restrict__ dst,
                       const int* __restrict__ row_ptr, int* __restrict__ cursor,
                       int2* __restrict__ csr_sd, int* __restrict__ csr_eid) {
    int e = blockIdx.x * 256 + threadIdx.x;
    if (e >= NE) return;
    int d = dst[e];
    int pos = atomicAdd(&cursor[d], 1);
    int slot = row_ptr[d] + pos;
    csr_sd[slot] = make_int2(src[e], d);
    csr_eid[slot] = e;
}

// eattr permuted into CSR slot order, cast to bf16 (one-time; reused by all 4 layers)
__global__ void k_eperm(const float* __restrict__ eattr, const int* __restrict__ csr_eid,
                        unsigned short* __restrict__ eattrP) {
    int idx = blockIdx.x * 256 + threadIdx.x;
    if (idx >= NE * EIN) return;
    int slot = idx >> 4, j = idx & 15;
    eattrP[idx] = f2bf(eattr[(size_t)csr_eid[slot] * EIN + j]);
}

__global__ void k_sumlog(const int* __restrict__ deg, float* __restrict__ sum) {
    int i = blockIdx.x * 256 + threadIdx.x;
    float v = (i < NN) ? log1pf((float)deg[i]) : 0.f;
    #pragma unroll
    for (int off = 32; off > 0; off >>= 1) v += __shfl_down(v, off, 64);
    if ((threadIdx.x & 63) == 0) atomicAdd(sum, v);
}

__global__ void k_scalers(const int* __restrict__ deg, const float* __restrict__ sumlog,
                          float* __restrict__ amp, float* __restrict__ att) {
    int i = blockIdx.x * 256 + threadIdx.x;
    if (i >= NN) return;
    float avg = sumlog[0] / (float)NN;
    float degc = fmaxf((float)deg[i], 1.0f);
    float la = logf(degc + 1.0f);
    amp[i] = la / avg;
    att[i] = avg / la;
}

// Per-layer fold: K_l = embW @ encW_l @ preW_l[2H:]  (16x128)
__global__ void k_wprep(const float* __restrict__ embW, const float* __restrict__ emb_b,
                        const float* __restrict__ encW, const float* __restrict__ enc_b,
                        const float* __restrict__ preW, const float* __restrict__ pre_b,
                        float* __restrict__ Kc, float* __restrict__ cc) {
    int l = blockIdx.x;
    const float* encWl = encW + (size_t)l * H * H;
    const float* preW2 = preW + (size_t)l * 3 * H * H + 2 * H * H;
    __shared__ float T1[16 * H];
    __shared__ float b1[H];
    int t = threadIdx.x;
    for (int idx = t; idx < 16 * H; idx += 256) {
        int r = idx / H, j = idx % H;
        float s = 0.f;
        for (int k = 0; k < H; k++) s = fmaf(embW[r * H + k], encWl[k * H + j], s);
        T1[idx] = s;
    }
    if (t < H) {
        float s = enc_b[l * H + t];
        for (int k = 0; k < H; k++) s = fmaf(emb_b[k], encWl[k * H + t], s);
        b1[t] = s;
    }
    __syncthreads();
    for (int idx = t; idx < 16 * H; idx += 256) {
        int r = idx / H, j = idx % H;
        float s = 0.f;
        for (int k = 0; k < H; k++) s = fmaf(T1[r * H + k], preW2[k * H + j], s);
        Kc[l * 16 * H + idx] = s;
    }
    if (t < H) {
        float s = pre_b[l * H + t];
        for (int k = 0; k < H; k++) s = fmaf(b1[k], preW2[k * H + t], s);
        cc[l * H + t] = s;
    }
}

// ---------------- weight transpose+cast: D[n][k] = bf16(S[k][n]), S has 128 cols ----------------
struct TD { const float* S; unsigned short* D; int K; };
struct TDs { TD t[21]; };

__global__ void k_prepw(TDs p) {
    TD d = p.t[blockIdx.y];
    int idx = blockIdx.x * 256 + threadIdx.x;
    int total = d.K << 7;
    if (idx < total) {
        int k = idx >> 7, n = idx & 127;
        d.D[(size_t)n * d.K + k] = f2bf(d.S[(size_t)k * 128 + n]);
    }
}

__global__ void k_cast(const float* __restrict__ S, unsigned short* __restrict__ D, int n) {
    int i = blockIdx.x * 256 + threadIdx.x;
    if (i < n) D[i] = f2bf(S[i]);
}

// ---------------- bf16 MFMA GEMM ----------------
__global__ __launch_bounds__(256, 3) void k_mgemm(
    const unsigned short* __restrict__ A, int lda, int K, int nch,
    const unsigned short* __restrict__ Bt,
    const float* __restrict__ bias, const unsigned short* __restrict__ addCb,
    float* __restrict__ outF, unsigned short* __restrict__ outB,
    int relu, int scaleMode,
    const float* __restrict__ amp, const float* __restrict__ att)
{
    __shared__ unsigned short As[128][72];   // +8 pad: 2-way bank aliasing only (free)
    __shared__ unsigned short Bs[128][72];
    const unsigned short* Btp = Bt + (size_t)blockIdx.y * 128 * K;
    int m0 = blockIdx.x * 128;
    int tid = threadIdx.x;
    int wave = tid >> 6, lane = tid & 63;
    int wr = wave >> 1, wc = wave & 1;
    int ln = lane & 15, q = lane >> 4;

    f32x4 acc[4][4];
    #pragma unroll
    for (int a = 0; a < 4; a++)
        #pragma unroll
        for (int b = 0; b < 4; b++) acc[a][b] = (f32x4){0.f, 0.f, 0.f, 0.f};

    for (int c = 0; c < nch; c++) {
        int g = scaleMode ? (c >> 3) : 0;
        int acol = scaleMode ? ((c & 7) * 64) : c * 64;
        int bcol = c * 64;
        #pragma unroll
        for (int i0 = 0; i0 < 4; i0++) {
            int i = tid + i0 * 256;
            int row = i >> 3, seg = i & 7;
            uint4 bv = *(const uint4*)(Btp + (size_t)row * K + bcol + seg * 8);
            *(uint4*)(&Bs[row][seg * 8]) = bv;
            int rowg = m0 + row;
            uint4 av = make_uint4(0, 0, 0, 0);
            if (rowg < NN) {
                av = *(const uint4*)(A + (size_t)rowg * lda + acol + seg * 8);
                if (g) {
                    float s = (g == 1) ? amp[rowg] : att[rowg];
                    av.x = scale_pk(av.x, s); av.y = scale_pk(av.y, s);
                    av.z = scale_pk(av.z, s); av.w = scale_pk(av.w, s);
                }
            }
            *(uint4*)(&As[row][seg * 8]) = av;
        }
        __syncthreads();
        #pragma unroll
        for (int kq = 0; kq < 2; kq++) {
            bf16x8 af[4], bfr[4];
            #pragma unroll
            for (int f = 0; f < 4; f++) {
                af[f]  = *(const bf16x8*)(&As[wr * 64 + f * 16 + ln][kq * 32 + q * 8]);
                bfr[f] = *(const bf16x8*)(&Bs[wc * 64 + f * 16 + ln][kq * 32 + q * 8]);
            }
            #pragma unroll
            for (int fr = 0; fr < 4; fr++)
                #pragma unroll
                for (int fc = 0; fc < 4; fc++)
                    acc[fr][fc] = __builtin_amdgcn_mfma_f32_16x16x32_bf16(
                        af[fr], bfr[fc], acc[fr][fc], 0, 0, 0);
        }
        __syncthreads();
    }

    float* outFp = outF ? outF + (size_t)blockIdx.y * NN * H : nullptr;
    unsigned short* outBp = outB ? outB + (size_t)blockIdx.y * NN * H : nullptr;
    #pragma unroll
    for (int fc = 0; fc < 4; fc++) {
        int col = wc * 64 + fc * 16 + ln;
        float bv = bias ? bias[col] : 0.f;
        #pragma unroll
        for (int fr = 0; fr < 4; fr++) {
            int rowb = m0 + wr * 64 + fr * 16 + q * 4;
            #pragma unroll
            for (int r = 0; r < 4; r++) {
                int rowg = rowb + r;
                if (rowg < NN) {
                    float v = acc[fr][fc][r] + bv;
                    if (addCb) v += bflo((unsigned)addCb[(size_t)rowg * H + col]);
                    if (relu) v = fmaxf(v, 0.f);
                    if (outFp) outFp[(size_t)rowg * H + col] = v;
                    if (outBp) outBp[(size_t)rowg * H + col] = f2bf(v);
                }
            }
        }
    }
}

// ---------------- phase A: per-slot message compute (slot-parallel, full MLP) ----------------
// m[slot] = hWd[dst] + hWs[src] + eattrP[slot]*K + c   -> mbuf (bf16 packed, slot-ordered)
#define SLOTW 8
__global__ __launch_bounds__(256) void k_edgem(
    const unsigned short* __restrict__ pd, const unsigned short* __restrict__ ps,
    const unsigned* __restrict__ eattrP, const int2* __restrict__ csr_sd,
    const float* __restrict__ Kl, const float* __restrict__ cl,
    unsigned* __restrict__ mbuf)
{
    int wv = threadIdx.x >> 6, lane = threadIdx.x & 63;
    int s0 = (blockIdx.x * 4 + wv) * SLOTW;
    int d0 = lane * 2;
    float2 kr[16];
    #pragma unroll
    for (int k = 0; k < 16; k++) kr[k] = *(const float2*)(Kl + k * H + d0);
    float2 c2 = *(const float2*)(cl + d0);
    #pragma unroll
    for (int u = 0; u < SLOTW; u++) {
        int slot = s0 + u;
        int2 sd = csr_sd[slot];
        const unsigned* ep = eattrP + (size_t)slot * 8;   // 16 bf16 = 8 dwords
        unsigned eu[8];
        *(uint4*)(eu)     = *(const uint4*)(ep);
        *(uint4*)(eu + 4) = *(const uint4*)(ep + 4);
        unsigned hd = *(const unsigned*)(pd + (size_t)sd.y * H + d0);
        unsigned hs = *(const unsigned*)(ps + (size_t)sd.x * H + d0);
        float ax = c2.x + bflo(hd) + bflo(hs);
        float ay = c2.y + bfhi(hd) + bfhi(hs);
        #pragma unroll
        for (int j = 0; j < 8; j++) {
            float elo = bflo(eu[j]), ehi = bfhi(eu[j]);
            ax = fmaf(elo, kr[2 * j].x, ax);     ay = fmaf(elo, kr[2 * j].y, ay);
            ax = fmaf(ehi, kr[2 * j + 1].x, ax); ay = fmaf(ehi, kr[2 * j + 1].y, ay);
        }
        mbuf[(size_t)slot * 64 + lane] = (unsigned)f2bf(ax) | ((unsigned)f2bf(ay) << 16);
    }
}

// ---------------- phase B: streaming segmented reduce over mbuf ----------------
__global__ __launch_bounds__(256) void k_reduce(const unsigned* __restrict__ mbuf,
                                                const int* __restrict__ row_ptr,
                                                unsigned short* __restrict__ agg) {
    int wv = threadIdx.x >> 6, lane = threadIdx.x & 63;
    int i = blockIdx.x * 4 + wv;
    int rs = row_ptr[i], re = row_ptr[i + 1];
    float2 s = make_float2(0, 0), qq = make_float2(0, 0);
    float2 mn = make_float2(3.0e38f, 3.0e38f), mx = make_float2(-3.0e38f, -3.0e38f);
    int slot = rs;
    for (; slot + 1 < re; slot += 2) {
        unsigned u0 = mbuf[(size_t)slot * 64 + lane];
        unsigned u1 = mbuf[(size_t)(slot + 1) * 64 + lane];
        float ax0 = bflo(u0), ay0 = bfhi(u0);
        float ax1 = bflo(u1), ay1 = bfhi(u1);
        s.x += ax0 + ax1; s.y += ay0 + ay1;
        qq.x = fmaf(ax0, ax0, fmaf(ax1, ax1, qq.x));
        qq.y = fmaf(ay0, ay0, fmaf(ay1, ay1, qq.y));
        mn.x = fminf(mn.x, fminf(ax0, ax1)); mn.y = fminf(mn.y, fminf(ay0, ay1));
        mx.x = fmaxf(mx.x, fmaxf(ax0, ax1)); mx.y = fmaxf(mx.y, fmaxf(ay0, ay1));
    }
    if (slot < re) {
        unsigned u0 = mbuf[(size_t)slot * 64 + lane];
        float ax0 = bflo(u0), ay0 = bfhi(u0);
        s.x += ax0; s.y += ay0;
        qq.x = fmaf(ax0, ax0, qq.x); qq.y = fmaf(ay0, ay0, qq.y);
        mn.x = fminf(mn.x, ax0); mn.y = fminf(mn.y, ay0);
        mx.x = fmaxf(mx.x, ax0); mx.y = fmaxf(mx.y, ay0);
    }
    int dg = re - rs;
    float dinv = 1.0f / fmaxf((float)dg, 1.0f);
    float2 mean = make_float2(s.x * dinv, s.y * dinv);
    float2 m2v = make_float2(qq.x * dinv, qq.y * dinv);
    float2 sd;
    sd.x = sqrtf(fmaxf(m2v.x - mean.x * mean.x, 0.f) + EPSV);
    sd.y = sqrtf(fmaxf(m2v.y - mean.y * mean.y, 0.f) + EPSV);
    if (dg == 0) { mn = make_float2(0, 0); mx = make_float2(0, 0); }
    unsigned short* ap = agg + (size_t)i * 512 + lane * 2;
    *(unsigned*)(ap)       = (unsigned)f2bf(mean.x) | ((unsigned)f2bf(mean.y) << 16);
    *(unsigned*)(ap + 128) = (unsigned)f2bf(mn.x)   | ((unsigned)f2bf(mn.y)   << 16);
    *(unsigned*)(ap + 256) = (unsigned)f2bf(mx.x)   | ((unsigned)f2bf(mx.y)   << 16);
    *(unsigned*)(ap + 384) = (unsigned)f2bf(sd.x)   | ((unsigned)f2bf(sd.y)   << 16);
}

// ---------------- pooling + head ----------------
__device__ __forceinline__ int lbound(const int* a, int n, int v) {
    int lo = 0, hi = n;
    while (lo < hi) { int m = (lo + hi) >> 1; if (a[m] < v) lo = m + 1; else hi = m; }
    return lo;
}

__global__ __launch_bounds__(256) void k_pool(const float* __restrict__ h,
                                              const int* __restrict__ batch,
                                              const float* __restrict__ headW,
                                              const float* __restrict__ headb,
                                              float* __restrict__ out) {
    __shared__ float sm[256];
    int g = blockIdx.x;
    int t = threadIdx.x;
    int col = t & 127;
    int half = t >> 7;
    int lo = lbound(batch, NN, g);
    int hi = lbound(batch, NN, g + 1);
    int mid = lo + ((hi - lo) >> 1);
    int b0 = half ? mid : lo;
    int b1 = half ? hi : mid;
    float acc = 0.f;
    for (int i = b0; i < b1; i++) acc += h[(size_t)i * H + col];
    sm[t] = acc;
    __syncthreads();
    if (t < 128) sm[t] += sm[t + 128];
    __syncthreads();
    if (t < NOUT) {
        float r = headb[t];
        for (int j = 0; j < H; j++) r = fmaf(sm[j], headW[j * NOUT + t], r);
        out[g * NOUT + t] = r;
    }
}

// ---------------- launch ----------------
extern "C" void kernel_launch(void* const* d_in, const int* in_sizes, int n_in,
                              void* d_out, int out_size, void* d_ws, size_t ws_size,
                              hipStream_t stream) {
    const float* x          = (const float*)d_in[0];
    const float* edge_attr  = (const float*)d_in[1];
    const int*   src        = (const int*)d_in[2];
    const int*   dst        = (const int*)d_in[3];
    const int*   batch      = (const int*)d_in[4];
    const float* node_emb_W = (const float*)d_in[5];
    const float* node_emb_b = (const float*)d_in[6];
    const float* edge_emb_W = (const float*)d_in[7];
    const float* edge_emb_b = (const float*)d_in[8];
    const float* edge_enc_W = (const float*)d_in[9];
    const float* edge_enc_b = (const float*)d_in[10];
    const float* pre_W      = (const float*)d_in[11];
    const float* pre_b      = (const float*)d_in[12];
    const float* post_W     = (const float*)d_in[13];
    const float* post_b     = (const float*)d_in[14];
    const float* lin_W      = (const float*)d_in[15];
    const float* lin_b      = (const float*)d_in[16];
    const float* head_W     = (const float*)d_in[17];
    const float* head_b     = (const float*)d_in[18];
    float* out = (float*)d_out;

    char* wp = (char*)d_ws;
    auto carve = [&](size_t bytes) -> char* {
        char* r = wp;
        wp += (bytes + 255) & ~(size_t)255;
        return r;
    };
    // ---- persistent region (~121 MB) ----
    int*   deg     = (int*)carve((size_t)NN * 4);
    int*   cursor  = (int*)carve((size_t)NN * 4);
    float* sumlog  = (float*)carve(4);
    int*   partial = (int*)carve(256 * 4);
    int*   row_ptr = (int*)carve((size_t)(NN + 1) * 4);
    int2*  csr_sd  = (int2*)carve((size_t)NE * 8);
    float* amp     = (float*)carve((size_t)NN * 4);
    float* att     = (float*)carve((size_t)NN * 4);
    float* Kc      = (float*)carve((size_t)NL * 16 * H * 4);
    float* cc      = (float*)carve((size_t)NL * H * 4);
    unsigned short* eattrP = (unsigned short*)carve((size_t)NE * EIN * 2);   // bf16
    unsigned short* embWt  = (unsigned short*)carve((size_t)H * FIN * 2);
    unsigned short* Wt3    = (unsigned short*)carve((size_t)NL * 3 * H * H * 2);
    unsigned short* postWt = (unsigned short*)carve((size_t)NL * H * 12 * H * 2);
    unsigned short* linWt  = (unsigned short*)carve((size_t)NL * H * H * 2);
    unsigned short* hb     = (unsigned short*)carve((size_t)NN * H * 2);
    unsigned short* planesB= (unsigned short*)carve((size_t)3 * NN * H * 2);
    unsigned short* aggb   = (unsigned short*)carve((size_t)NN * 4 * H * 2);
    // ---- mbuf region (102.4 MB) with lifetime-based aliases ----
    unsigned* mbuf = (unsigned*)carve((size_t)NE * 64 * 4);
    // setup-time aliases (dead before first k_edgem):
    unsigned short* xb = (unsigned short*)mbuf;                         // 6.4 MB
    int* csr_eid = (int*)((char*)mbuf + (size_t)NN * FIN * 2);          // 1.6 MB @ +6.4 MB
    // post-reduce aliases (mbuf dead after k_reduce within a layer):
    unsigned short* ob = (unsigned short*)mbuf;                         // 12.8 MB @ +0
    float* hf = (float*)((char*)mbuf + (size_t)NN * H * 2);             // 25.6 MB @ +12.8 MB

    const size_t NP = (size_t)NN * H;

    hipMemsetAsync(deg, 0, (size_t)NN * 4, stream);
    hipMemsetAsync(cursor, 0, (size_t)NN * 4, stream);
    hipMemsetAsync(sumlog, 0, 4, stream);

    k_hist<<<(NE + 255) / 256, 256, 0, stream>>>(dst, deg);
    k_scan1<<<NBLK, 256, 0, stream>>>(deg, partial);
    k_scan2<<<1, 256, 0, stream>>>(partial, row_ptr, NBLK);
    k_scan3<<<NBLK, 256, 0, stream>>>(deg, partial, row_ptr);
    k_fill<<<(NE + 255) / 256, 256, 0, stream>>>(src, dst, row_ptr, cursor, csr_sd, csr_eid);
    k_eperm<<<(NE * EIN + 255) / 256, 256, 0, stream>>>(edge_attr, csr_eid, eattrP);
    k_sumlog<<<NBLK, 256, 0, stream>>>(deg, sumlog);
    k_scalers<<<NBLK, 256, 0, stream>>>(deg, sumlog, amp, att);
    k_wprep<<<NL, 256, 0, stream>>>(edge_emb_W, edge_emb_b, edge_enc_W, edge_enc_b,
                                    pre_W, pre_b, Kc, cc);

    // weight transpose+cast descriptor table
    TDs tds;
    int nd = 0;
    tds.t[nd++] = TD{node_emb_W, embWt, FIN};
    for (int l = 0; l < NL; l++) {
        tds.t[nd++] = TD{pre_W + (size_t)l * 3 * H * H,           Wt3 + (size_t)(l * 3 + 0) * H * H, H};
        tds.t[nd++] = TD{pre_W + (size_t)l * 3 * H * H + H * H,   Wt3 + (size_t)(l * 3 + 1) * H * H, H};
        tds.t[nd++] = TD{post_W + (size_t)l * 13 * H * H,         Wt3 + (size_t)(l * 3 + 2) * H * H, H};
        tds.t[nd++] = TD{post_W + (size_t)l * 13 * H * H + H * H, postWt + (size_t)l * H * 12 * H,   12 * H};
        tds.t[nd++] = TD{lin_W + (size_t)l * H * H,               linWt + (size_t)l * H * H,         H};
    }
    k_prepw<<<dim3(768, 21), 256, 0, stream>>>(tds);
    k_cast<<<(NN * FIN + 255) / 256, 256, 0, stream>>>(x, xb, NN * FIN);

    // h = x @ node_emb_W + b  (bf16 out only)
    k_mgemm<<<dim3(GB2, 1), 256, 0, stream>>>(xb, FIN, FIN, 1, embWt, node_emb_b,
                                              nullptr, nullptr, hb, 0, 0, nullptr, nullptr);

    for (int l = 0; l < NL; l++) {
        int last = (l == NL - 1);
        // planesB bf16: [hW_dst | hW_src | hA]
        k_mgemm<<<dim3(GB2, 3), 256, 0, stream>>>(hb, H, H, 2,
                                                  Wt3 + (size_t)l * 3 * H * H,
                                                  nullptr, nullptr, nullptr, planesB,
                                                  0, 0, nullptr, nullptr);
        // phase A: per-slot messages (slot-parallel)
        k_edgem<<<NE / (4 * SLOTW), 256, 0, stream>>>(planesB, planesB + NP,
                                                      (const unsigned*)eattrP, csr_sd,
                                                      Kc + (size_t)l * 16 * H,
                                                      cc + (size_t)l * H, mbuf);
        // phase B: streaming segmented reduce (mbuf dead afterwards)
        k_reduce<<<NN / 4, 256, 0, stream>>>(mbuf, row_ptr, aggb);
        // out_pre = [agg|amp*agg|att*agg] @ postW[H:] + hA + post_b  (virtual K=1536)
        k_mgemm<<<dim3(GB2, 1), 256, 0, stream>>>(aggb, 4 * H, 12 * H, 24,
                                                  postWt + (size_t)l * H * 12 * H,
                                                  post_b + (size_t)l * H, planesB + 2 * NP,
                                                  nullptr, ob, 0, 1, amp, att);
        // h = relu(out_pre @ lin_W + lin_b); fp32 copy only needed for the final pool
        k_mgemm<<<dim3(GB2, 1), 256, 0, stream>>>(ob, H, H, 2,
                                                  linWt + (size_t)l * H * H,
                                                  lin_b + (size_t)l * H, nullptr,
                                                  last ? hf : nullptr, hb, 1, 0,
                                                  nullptr, nullptr);
    }

    k_pool<<<NG, 256, 0, stream>>>(hf, batch, head_W, head_b, out);
}

// Round 5
// 1140.693 us; speedup vs baseline: 2.1166x; 1.1350x over previous
//
#include <hip/hip_runtime.h>

#define NN 50000
#define NE 400000
#define FIN 64
#define EIN 16
#define H 128
#define NL 4
#define NG 256
#define NOUT 12
#define EPSV 1e-5f

#define SB 256
#define NBLK ((NN + SB - 1) / SB)    // 196
#define GB2 ((NN + 127) / 128)       // 391 (128-row MFMA tiles)
#define NP64 (NN * 64)               // dwords per [NN,H] bf16 plane

typedef short bf16x8 __attribute__((ext_vector_type(8)));
typedef float f32x4 __attribute__((ext_vector_type(4)));

__device__ __forceinline__ unsigned short f2bf(float f) {
    unsigned u = __float_as_uint(f);
    u += 0x7fffu + ((u >> 16) & 1u);
    return (unsigned short)(u >> 16);
}

__device__ __forceinline__ float bflo(unsigned u) { return __uint_as_float(u << 16); }
__device__ __forceinline__ float bfhi(unsigned u) { return __uint_as_float(u & 0xffff0000u); }

// ---------------- setup kernels ----------------
__global__ void k_hist(const int* __restrict__ dst, int* __restrict__ deg) {
    int e = blockIdx.x * 256 + threadIdx.x;
    if (e < NE) atomicAdd(&deg[dst[e]], 1);
}

__global__ void k_scan1(const int* __restrict__ deg, int* __restrict__ partial) {
    __shared__ int sm[256];
    int i = blockIdx.x * 256 + threadIdx.x;
    sm[threadIdx.x] = (i < NN) ? deg[i] : 0;
    __syncthreads();
    for (int s = 128; s > 0; s >>= 1) {
        if (threadIdx.x < s) sm[threadIdx.x] += sm[threadIdx.x + s];
        __syncthreads();
    }
    if (threadIdx.x == 0) partial[blockIdx.x] = sm[0];
}

__global__ void k_scan2(int* __restrict__ partial, int* __restrict__ row_ptr, int nblk) {
    __shared__ int sm[256];
    int t = threadIdx.x;
    sm[t] = (t < nblk) ? partial[t] : 0;
    __syncthreads();
    for (int off = 1; off < 256; off <<= 1) {
        int v = (t >= off) ? sm[t - off] : 0;
        __syncthreads();
        sm[t] += v;
        __syncthreads();
    }
    int excl = (t == 0) ? 0 : sm[t - 1];
    if (t < nblk) partial[t] = excl;
    if (t == 0) row_ptr[0] = 0;
}

__global__ void k_scan3(const int* __restrict__ deg, const int* __restrict__ partial,
                        int* __restrict__ row_ptr) {
    __shared__ int sm[256];
    int t = threadIdx.x;
    int i = blockIdx.x * 256 + t;
    sm[t] = (i < NN) ? deg[i] : 0;
    __syncthreads();
    for (int off = 1; off < 256; off <<= 1) {
        int v = (t >= off) ? sm[t - off] : 0;
        __syncthreads();
        sm[t] += v;
        __syncthreads();
    }
    if (i < NN) row_ptr[i + 1] = partial[blockIdx.x] + sm[t];
}

__global__ void k_fill(const int* __restrict__ src, const int* __restrict__ dst,
                       const int* __restrict__ row_ptr, int* __restrict__ cursor,
                       int2* __restrict__ csr_sd, int* __restrict__ csr_eid) {
    int e = blockIdx.x * 256 + threadIdx.x;
    if (e >= NE) return;
    int d = dst[e];
    int pos = atomicAdd(&cursor[d], 1);
    int slot = row_ptr[d] + pos;
    csr_sd[slot] = make_int2(src[e], d);
    csr_eid[slot] = e;
}

// eattr permuted into CSR slot order, cast to bf16 (one-time; reused by all 4 layers)
__global__ void k_eperm(const float* __restrict__ eattr, const int* __restrict__ csr_eid,
                        unsigned short* __restrict__ eattrP) {
    int idx = blockIdx.x * 256 + threadIdx.x;
    if (idx >= NE * EIN) return;
    int slot = idx >> 4, j = idx & 15;
    eattrP[idx] = f2bf(eattr[(size_t)csr_eid[slot] * EIN + j]);
}

__global__ void k_sumlog(const int* __restrict__ deg, float* __restrict__ sum) {
    int i = blockIdx.x * 256 + threadIdx.x;
    float v = (i < NN) ? log1pf((float)deg[i]) : 0.f;
    #pragma unroll
    for (int off = 32; off > 0; off >>= 1) v += __shfl_down(v, off, 64);
    if ((threadIdx.x & 63) == 0) atomicAdd(sum, v);
}

__global__ void k_scalers(const int* __restrict__ deg, const float* __restrict__ sumlog,
                          float* __restrict__ amp, float* __restrict__ att) {
    int i = blockIdx.x * 256 + threadIdx.x;
    if (i >= NN) return;
    float avg = sumlog[0] / (float)NN;
    float degc = fmaxf((float)deg[i], 1.0f);
    float la = logf(degc + 1.0f);
    amp[i] = la / avg;
    att[i] = avg / la;
}

// Per-layer fold: K_l = embW @ encW_l @ preW_l[2H:]  (16x128)
__global__ void k_wprep(const float* __restrict__ embW, const float* __restrict__ emb_b,
                        const float* __restrict__ encW, const float* __restrict__ enc_b,
                        const float* __restrict__ preW, const float* __restrict__ pre_b,
                        float* __restrict__ Kc, float* __restrict__ cc) {
    int l = blockIdx.x;
    const float* encWl = encW + (size_t)l * H * H;
    const float* preW2 = preW + (size_t)l * 3 * H * H + 2 * H * H;
    __shared__ float T1[16 * H];
    __shared__ float b1[H];
    int t = threadIdx.x;
    for (int idx = t; idx < 16 * H; idx += 256) {
        int r = idx / H, j = idx % H;
        float s = 0.f;
        for (int k = 0; k < H; k++) s = fmaf(embW[r * H + k], encWl[k * H + j], s);
        T1[idx] = s;
    }
    if (t < H) {
        float s = enc_b[l * H + t];
        for (int k = 0; k < H; k++) s = fmaf(emb_b[k], encWl[k * H + t], s);
        b1[t] = s;
    }
    __syncthreads();
    for (int idx = t; idx < 16 * H; idx += 256) {
        int r = idx / H, j = idx % H;
        float s = 0.f;
        for (int k = 0; k < H; k++) s = fmaf(T1[r * H + k], preW2[k * H + j], s);
        Kc[l * 16 * H + idx] = s;
    }
    if (t < H) {
        float s = pre_b[l * H + t];
        for (int k = 0; k < H; k++) s = fmaf(b1[k], preW2[k * H + t], s);
        cc[l * H + t] = s;
    }
}

// ---------------- weight transpose+cast: D[n][k] = bf16(S[k][n]), S has 128 cols ----------------
struct TD { const float* S; unsigned short* D; int K; };
struct TDs { TD t[9]; };

__global__ void k_prepw(TDs p) {
    TD d = p.t[blockIdx.y];
    int idx = blockIdx.x * 256 + threadIdx.x;
    int total = d.K << 7;
    if (idx < total) {
        int k = idx >> 7, n = idx & 127;
        d.D[(size_t)n * d.K + k] = f2bf(d.S[(size_t)k * 128 + n]);
    }
}

__global__ void k_cast(const float* __restrict__ S, unsigned short* __restrict__ D, int n) {
    int i = blockIdx.x * 256 + threadIdx.x;
    if (i < n) D[i] = f2bf(S[i]);
}

// ---------------- weight fold: fold_l = postW_l @ linW_l  (fp32 acc, bf16-T out) --------------
// rows 0..127  (Wh@linW)   -> Wt3 plane (l*3+2), layout [n][k] stride 128
// rows 128..1663 (B@linW)  -> foldT_l, layout [n][k] stride 1664 (k absolute)
__global__ __launch_bounds__(256) void k_wfold(const float* __restrict__ postW,
                                               const float* __restrict__ linW,
                                               unsigned short* __restrict__ Wt3,
                                               unsigned short* __restrict__ foldT) {
    __shared__ float As[32][68];
    __shared__ float Bs[32][128];
    int l = blockIdx.y;
    const float* A = postW + (size_t)l * 13 * H * H;   // [1664][128]
    const float* Bp = linW + (size_t)l * H * H;        // [128][128]
    int m0 = blockIdx.x * 64;
    int tid = threadIdx.x;
    int tx = tid & 31, ty = tid >> 5;
    float4 acc[8];
    #pragma unroll
    for (int r = 0; r < 8; r++) acc[r] = make_float4(0, 0, 0, 0);
    int f = tid & 7, r0 = tid >> 3;
    int cf = tid & 31, kr0 = tid >> 5;
    for (int k0 = 0; k0 < H; k0 += 32) {
        #pragma unroll
        for (int hh = 0; hh < 2; hh++) {
            int r = r0 + hh * 32;
            float4 v = *(const float4*)(A + (size_t)(m0 + r) * H + k0 + f * 4);
            As[f * 4 + 0][r] = v.x; As[f * 4 + 1][r] = v.y;
            As[f * 4 + 2][r] = v.z; As[f * 4 + 3][r] = v.w;
        }
        #pragma unroll
        for (int hh = 0; hh < 4; hh++) {
            int kr = kr0 + hh * 8;
            *(float4*)&Bs[kr][cf * 4] = *(const float4*)(Bp + (size_t)(k0 + kr) * H + cf * 4);
        }
        __syncthreads();
        #pragma unroll
        for (int kk = 0; kk < 32; kk++) {
            float4 b = *(float4*)&Bs[kk][tx * 4];
            float4 a0 = *(float4*)&As[kk][ty * 8];
            float4 a1 = *(float4*)&As[kk][ty * 8 + 4];
            acc[0].x = fmaf(a0.x, b.x, acc[0].x); acc[0].y = fmaf(a0.x, b.y, acc[0].y);
            acc[0].z = fmaf(a0.x, b.z, acc[0].z); acc[0].w = fmaf(a0.x, b.w, acc[0].w);
            acc[1].x = fmaf(a0.y, b.x, acc[1].x); acc[1].y = fmaf(a0.y, b.y, acc[1].y);
            acc[1].z = fmaf(a0.y, b.z, acc[1].z); acc[1].w = fmaf(a0.y, b.w, acc[1].w);
            acc[2].x = fmaf(a0.z, b.x, acc[2].x); acc[2].y = fmaf(a0.z, b.y, acc[2].y);
            acc[2].z = fmaf(a0.z, b.z, acc[2].z); acc[2].w = fmaf(a0.z, b.w, acc[2].w);
            acc[3].x = fmaf(a0.w, b.x, acc[3].x); acc[3].y = fmaf(a0.w, b.y, acc[3].y);
            acc[3].z = fmaf(a0.w, b.z, acc[3].z); acc[3].w = fmaf(a0.w, b.w, acc[3].w);
            acc[4].x = fmaf(a1.x, b.x, acc[4].x); acc[4].y = fmaf(a1.x, b.y, acc[4].y);
            acc[4].z = fmaf(a1.x, b.z, acc[4].z); acc[4].w = fmaf(a1.x, b.w, acc[4].w);
            acc[5].x = fmaf(a1.y, b.x, acc[5].x); acc[5].y = fmaf(a1.y, b.y, acc[5].y);
            acc[5].z = fmaf(a1.y, b.z, acc[5].z); acc[5].w = fmaf(a1.y, b.w, acc[5].w);
            acc[6].x = fmaf(a1.z, b.x, acc[6].x); acc[6].y = fmaf(a1.z, b.y, acc[6].y);
            acc[6].z = fmaf(a1.z, b.z, acc[6].z); acc[6].w = fmaf(a1.z, b.w, acc[6].w);
            acc[7].x = fmaf(a1.w, b.x, acc[7].x); acc[7].y = fmaf(a1.w, b.y, acc[7].y);
            acc[7].z = fmaf(a1.w, b.z, acc[7].z); acc[7].w = fmaf(a1.w, b.w, acc[7].w);
        }
        __syncthreads();
    }
    unsigned short* w2 = Wt3 + (size_t)(l * 3 + 2) * H * H;
    unsigned short* ft = foldT + (size_t)l * 128 * 1664;
    int r = m0 + ty * 8;   // 8 consecutive output rows (k index), all in one region
    #pragma unroll
    for (int c = 0; c < 4; c++) {
        int n = tx * 4 + c;
        unsigned short tmp[8] __attribute__((aligned(16)));
        #pragma unroll
        for (int rr = 0; rr < 8; rr++) tmp[rr] = f2bf(((const float*)&acc[rr])[c]);
        unsigned short* dstp = (r < 128) ? (w2 + (size_t)n * 128 + r)
                                         : (ft + (size_t)n * 1664 + r);
        *(uint4*)dstp = *(const uint4*)tmp;
    }
}

// bias' = pb @ linW + lb  (per layer)
__global__ void k_bfold(const float* __restrict__ pb, const float* __restrict__ lb,
                        const float* __restrict__ linW, float* __restrict__ cf) {
    int l = blockIdx.x, n = threadIdx.x;
    const float* B = linW + (size_t)l * H * H;
    float s = lb[l * H + n];
    for (int j = 0; j < H; j++) s = fmaf(pb[l * H + j], B[j * H + n], s);
    cf[l * H + n] = s;
}

// ---------------- bf16 MFMA GEMM ----------------
// C[M,128](plane y) = A[M,K] @ Bt_y[128][K]; Btp = Bt + y*bstride_y, row stride ldb.
__global__ __launch_bounds__(256, 3) void k_mgemm(
    const unsigned short* __restrict__ A, int lda, int K, int nch,
    const unsigned short* __restrict__ Bt, int ldb, int bstride_y,
    const float* __restrict__ bias,
    float* __restrict__ outF, unsigned short* __restrict__ outB, int relu)
{
    __shared__ unsigned short As[128][72];   // +8 pad: 2-way bank aliasing only (free)
    __shared__ unsigned short Bs[128][72];
    const unsigned short* Btp = Bt + (size_t)blockIdx.y * bstride_y;
    int m0 = blockIdx.x * 128;
    int tid = threadIdx.x;
    int wave = tid >> 6, lane = tid & 63;
    int wr = wave >> 1, wc = wave & 1;
    int ln = lane & 15, q = lane >> 4;

    f32x4 acc[4][4];
    #pragma unroll
    for (int a = 0; a < 4; a++)
        #pragma unroll
        for (int b = 0; b < 4; b++) acc[a][b] = (f32x4){0.f, 0.f, 0.f, 0.f};

    for (int c = 0; c < nch; c++) {
        int col = c * 64;
        #pragma unroll
        for (int i0 = 0; i0 < 4; i0++) {
            int i = tid + i0 * 256;
            int row = i >> 3, seg = i & 7;
            uint4 bv = *(const uint4*)(Btp + (size_t)row * ldb + col + seg * 8);
            *(uint4*)(&Bs[row][seg * 8]) = bv;
            int rowg = m0 + row;
            uint4 av = make_uint4(0, 0, 0, 0);
            if (rowg < NN) av = *(const uint4*)(A + (size_t)rowg * lda + col + seg * 8);
            *(uint4*)(&As[row][seg * 8]) = av;
        }
        __syncthreads();
        #pragma unroll
        for (int kq = 0; kq < 2; kq++) {
            bf16x8 af[4], bfr[4];
            #pragma unroll
            for (int f = 0; f < 4; f++) {
                af[f]  = *(const bf16x8*)(&As[wr * 64 + f * 16 + ln][kq * 32 + q * 8]);
                bfr[f] = *(const bf16x8*)(&Bs[wc * 64 + f * 16 + ln][kq * 32 + q * 8]);
            }
            #pragma unroll
            for (int fr = 0; fr < 4; fr++)
                #pragma unroll
                for (int fc = 0; fc < 4; fc++)
                    acc[fr][fc] = __builtin_amdgcn_mfma_f32_16x16x32_bf16(
                        af[fr], bfr[fc], acc[fr][fc], 0, 0, 0);
        }
        __syncthreads();
    }

    float* outFp = outF ? outF + (size_t)blockIdx.y * NN * H : nullptr;
    unsigned short* outBp = outB ? outB + (size_t)blockIdx.y * NN * H : nullptr;
    #pragma unroll
    for (int fc = 0; fc < 4; fc++) {
        int col = wc * 64 + fc * 16 + ln;
        float bv = bias ? bias[col] : 0.f;
        #pragma unroll
        for (int fr = 0; fr < 4; fr++) {
            int rowb = m0 + wr * 64 + fr * 16 + q * 4;
            #pragma unroll
            for (int r = 0; r < 4; r++) {
                int rowg = rowb + r;
                if (rowg < NN) {
                    float v = acc[fr][fc][r] + bv;
                    if (relu) v = fmaxf(v, 0.f);
                    if (outFp) outFp[(size_t)rowg * H + col] = v;
                    if (outBp) outBp[(size_t)rowg * H + col] = f2bf(v);
                }
            }
        }
    }
}

// ---------------- phase A: per-slot message compute (slot-parallel, full MLP) ----------------
#define SLOTW 8
__global__ __launch_bounds__(256) void k_edgem(
    const unsigned short* __restrict__ pd, const unsigned short* __restrict__ ps,
    const unsigned* __restrict__ eattrP, const int2* __restrict__ csr_sd,
    const float* __restrict__ Kl, const float* __restrict__ cl,
    unsigned* __restrict__ mbuf)
{
    int wv = threadIdx.x >> 6, lane = threadIdx.x & 63;
    int s0 = (blockIdx.x * 4 + wv) * SLOTW;
    int d0 = lane * 2;
    float2 kr[16];
    #pragma unroll
    for (int k = 0; k < 16; k++) kr[k] = *(const float2*)(Kl + k * H + d0);
    float2 c2 = *(const float2*)(cl + d0);
    #pragma unroll
    for (int u = 0; u < SLOTW; u++) {
        int slot = s0 + u;
        int2 sd = csr_sd[slot];
        const unsigned* ep = eattrP + (size_t)slot * 8;   // 16 bf16 = 8 dwords
        unsigned eu[8];
        *(uint4*)(eu)     = *(const uint4*)(ep);
        *(uint4*)(eu + 4) = *(const uint4*)(ep + 4);
        unsigned hd = *(const unsigned*)(pd + (size_t)sd.y * H + d0);
        unsigned hs = *(const unsigned*)(ps + (size_t)sd.x * H + d0);
        float ax = c2.x + bflo(hd) + bflo(hs);
        float ay = c2.y + bfhi(hd) + bfhi(hs);
        #pragma unroll
        for (int j = 0; j < 8; j++) {
            float elo = bflo(eu[j]), ehi = bfhi(eu[j]);
            ax = fmaf(elo, kr[2 * j].x, ax);     ay = fmaf(elo, kr[2 * j].y, ay);
            ax = fmaf(ehi, kr[2 * j + 1].x, ax); ay = fmaf(ehi, kr[2 * j + 1].y, ay);
        }
        mbuf[(size_t)slot * 64 + lane] = (unsigned)f2bf(ax) | ((unsigned)f2bf(ay) << 16);
    }
}

// ---------------- phase B: streaming segmented reduce over mbuf ----------------
__global__ __launch_bounds__(256) void k_reduce(const unsigned* __restrict__ mbuf,
                                                const int* __restrict__ row_ptr,
                                                unsigned short* __restrict__ agg) {
    int wv = threadIdx.x >> 6, lane = threadIdx.x & 63;
    int i = blockIdx.x * 4 + wv;
    int rs = row_ptr[i], re = row_ptr[i + 1];
    float2 s = make_float2(0, 0), qq = make_float2(0, 0);
    float2 mn = make_float2(3.0e38f, 3.0e38f), mx = make_float2(-3.0e38f, -3.0e38f);
    int slot = rs;
    for (; slot + 1 < re; slot += 2) {
        unsigned u0 = mbuf[(size_t)slot * 64 + lane];
        unsigned u1 = mbuf[(size_t)(slot + 1) * 64 + lane];
        float ax0 = bflo(u0), ay0 = bfhi(u0);
        float ax1 = bflo(u1), ay1 = bfhi(u1);
        s.x += ax0 + ax1; s.y += ay0 + ay1;
        qq.x = fmaf(ax0, ax0, fmaf(ax1, ax1, qq.x));
        qq.y = fmaf(ay0, ay0, fmaf(ay1, ay1, qq.y));
        mn.x = fminf(mn.x, fminf(ax0, ax1)); mn.y = fminf(mn.y, fminf(ay0, ay1));
        mx.x = fmaxf(mx.x, fmaxf(ax0, ax1)); mx.y = fmaxf(mx.y, fmaxf(ay0, ay1));
    }
    if (slot < re) {
        unsigned u0 = mbuf[(size_t)slot * 64 + lane];
        float ax0 = bflo(u0), ay0 = bfhi(u0);
        s.x += ax0; s.y += ay0;
        qq.x = fmaf(ax0, ax0, qq.x); qq.y = fmaf(ay0, ay0, qq.y);
        mn.x = fminf(mn.x, ax0); mn.y = fminf(mn.y, ay0);
        mx.x = fmaxf(mx.x, ax0); mx.y = fmaxf(mx.y, ay0);
    }
    int dg = re - rs;
    float dinv = 1.0f / fmaxf((float)dg, 1.0f);
    float2 mean = make_float2(s.x * dinv, s.y * dinv);
    float2 m2v = make_float2(qq.x * dinv, qq.y * dinv);
    float2 sd;
    sd.x = sqrtf(fmaxf(m2v.x - mean.x * mean.x, 0.f) + EPSV);
    sd.y = sqrtf(fmaxf(m2v.y - mean.y * mean.y, 0.f) + EPSV);
    if (dg == 0) { mn = make_float2(0, 0); mx = make_float2(0, 0); }
    unsigned short* ap = agg + (size_t)i * 512 + lane * 2;
    *(unsigned*)(ap)       = (unsigned)f2bf(mean.x) | ((unsigned)f2bf(mean.y) << 16);
    *(unsigned*)(ap + 128) = (unsigned)f2bf(mn.x)   | ((unsigned)f2bf(mn.y)   << 16);
    *(unsigned*)(ap + 256) = (unsigned)f2bf(mx.x)   | ((unsigned)f2bf(mx.y)   << 16);
    *(unsigned*)(ap + 384) = (unsigned)f2bf(sd.x)   | ((unsigned)f2bf(sd.y)   << 16);
}

// ---------------- combine: h = relu(hA' + p0 + amp*p1 + att*p2 + bias') ----------------
__global__ __launch_bounds__(256) void k_comb(const unsigned* __restrict__ ha,
                                              const unsigned* __restrict__ part,
                                              const float* __restrict__ amp,
                                              const float* __restrict__ att,
                                              const float* __restrict__ biasf,
                                              unsigned* __restrict__ hbo,
                                              float* __restrict__ hfo) {
    int dv = blockIdx.x * 256 + threadIdx.x;   // NN*64 total dwords
    int i = dv >> 6;
    int cp = dv & 63;
    float a = amp[i], t = att[i];
    unsigned uh = ha[dv];
    unsigned p0 = part[dv];
    unsigned p1 = part[dv + NP64];
    unsigned p2 = part[dv + 2 * NP64];
    float lo = bflo(uh) + bflo(p0) + a * bflo(p1) + t * bflo(p2) + biasf[cp * 2];
    float hi = bfhi(uh) + bfhi(p0) + a * bfhi(p1) + t * bfhi(p2) + biasf[cp * 2 + 1];
    lo = fmaxf(lo, 0.f); hi = fmaxf(hi, 0.f);
    hbo[dv] = (unsigned)f2bf(lo) | ((unsigned)f2bf(hi) << 16);
    if (hfo) { hfo[dv * 2] = lo; hfo[dv * 2 + 1] = hi; }
}

// ---------------- pooling + head ----------------
__device__ __forceinline__ int lbound(const int* a, int n, int v) {
    int lo = 0, hi = n;
    while (lo < hi) { int m = (lo + hi) >> 1; if (a[m] < v) lo = m + 1; else hi = m; }
    return lo;
}

__global__ __launch_bounds__(256) void k_pool(const float* __restrict__ h,
                                              const int* __restrict__ batch,
                                              const float* __restrict__ headW,
                                              const float* __restrict__ headb,
                                              float* __restrict__ out) {
    __shared__ float sm[256];
    int g = blockIdx.x;
    int t = threadIdx.x;
    int col = t & 127;
    int half = t >> 7;
    int lo = lbound(batch, NN, g);
    int hi = lbound(batch, NN, g + 1);
    int mid = lo + ((hi - lo) >> 1);
    int b0 = half ? mid : lo;
    int b1 = half ? hi : mid;
    float acc = 0.f;
    for (int i = b0; i < b1; i++) acc += h[(size_t)i * H + col];
    sm[t] = acc;
    __syncthreads();
    if (t < 128) sm[t] += sm[t + 128];
    __syncthreads();
    if (t < NOUT) {
        float r = headb[t];
        for (int j = 0; j < H; j++) r = fmaf(sm[j], headW[j * NOUT + t], r);
        out[g * NOUT + t] = r;
    }
}

// ---------------- launch ----------------
extern "C" void kernel_launch(void* const* d_in, const int* in_sizes, int n_in,
                              void* d_out, int out_size, void* d_ws, size_t ws_size,
                              hipStream_t stream) {
    const float* x          = (const float*)d_in[0];
    const float* edge_attr  = (const float*)d_in[1];
    const int*   src        = (const int*)d_in[2];
    const int*   dst        = (const int*)d_in[3];
    const int*   batch      = (const int*)d_in[4];
    const float* node_emb_W = (const float*)d_in[5];
    const float* node_emb_b = (const float*)d_in[6];
    const float* edge_emb_W = (const float*)d_in[7];
    const float* edge_emb_b = (const float*)d_in[8];
    const float* edge_enc_W = (const float*)d_in[9];
    const float* edge_enc_b = (const float*)d_in[10];
    const float* pre_W      = (const float*)d_in[11];
    const float* pre_b      = (const float*)d_in[12];
    const float* post_W     = (const float*)d_in[13];
    const float* post_b     = (const float*)d_in[14];
    const float* lin_W      = (const float*)d_in[15];
    const float* lin_b      = (const float*)d_in[16];
    const float* head_W     = (const float*)d_in[17];
    const float* head_b     = (const float*)d_in[18];
    float* out = (float*)d_out;

    char* wp = (char*)d_ws;
    auto carve = [&](size_t bytes) -> char* {
        char* r = wp;
        wp += (bytes + 255) & ~(size_t)255;
        return r;
    };
    // ---- persistent region ----
    int*   deg     = (int*)carve((size_t)NN * 4);
    int*   cursor  = (int*)carve((size_t)NN * 4);
    float* sumlog  = (float*)carve(4);
    int*   partial = (int*)carve(256 * 4);
    int*   row_ptr = (int*)carve((size_t)(NN + 1) * 4);
    int2*  csr_sd  = (int2*)carve((size_t)NE * 8);
    float* amp     = (float*)carve((size_t)NN * 4);
    float* att     = (float*)carve((size_t)NN * 4);
    float* Kc      = (float*)carve((size_t)NL * 16 * H * 4);
    float* cc      = (float*)carve((size_t)NL * H * 4);
    float* cfold   = (float*)carve((size_t)NL * H * 4);
    unsigned short* eattrP = (unsigned short*)carve((size_t)NE * EIN * 2);   // bf16
    unsigned short* embWt  = (unsigned short*)carve((size_t)H * FIN * 2);
    unsigned short* Wt3    = (unsigned short*)carve((size_t)NL * 3 * H * H * 2);
    unsigned short* foldT  = (unsigned short*)carve((size_t)NL * 128 * 1664 * 2);
    unsigned short* hb     = (unsigned short*)carve((size_t)NN * H * 2);
    unsigned short* planesB= (unsigned short*)carve((size_t)3 * NN * H * 2);
    unsigned short* aggb   = (unsigned short*)carve((size_t)NN * 4 * H * 2);
    // ---- mbuf region (102.4 MB) with lifetime-based aliases ----
    unsigned* mbuf = (unsigned*)carve((size_t)NE * 64 * 4);
    // setup-time aliases (dead before first k_edgem):
    unsigned short* xb = (unsigned short*)mbuf;                         // 6.4 MB
    int* csr_eid = (int*)((char*)mbuf + (size_t)NN * FIN * 2);          // 1.6 MB @ +6.4 MB
    // post-reduce aliases (mbuf dead after k_reduce within a layer):
    unsigned short* partsB = (unsigned short*)mbuf;                     // 38.4 MB @ +0
    float* hf = (float*)((char*)mbuf + (size_t)3 * NN * H * 2);         // 25.6 MB @ +38.4 MB

    const size_t NP = (size_t)NN * H;

    hipMemsetAsync(deg, 0, (size_t)NN * 4, stream);
    hipMemsetAsync(cursor, 0, (size_t)NN * 4, stream);
    hipMemsetAsync(sumlog, 0, 4, stream);

    k_hist<<<(NE + 255) / 256, 256, 0, stream>>>(dst, deg);
    k_scan1<<<NBLK, 256, 0, stream>>>(deg, partial);
    k_scan2<<<1, 256, 0, stream>>>(partial, row_ptr, NBLK);
    k_scan3<<<NBLK, 256, 0, stream>>>(deg, partial, row_ptr);
    k_fill<<<(NE + 255) / 256, 256, 0, stream>>>(src, dst, row_ptr, cursor, csr_sd, csr_eid);
    k_eperm<<<(NE * EIN + 255) / 256, 256, 0, stream>>>(edge_attr, csr_eid, eattrP);
    k_sumlog<<<NBLK, 256, 0, stream>>>(deg, sumlog);
    k_scalers<<<NBLK, 256, 0, stream>>>(deg, sumlog, amp, att);
    k_wprep<<<NL, 256, 0, stream>>>(edge_emb_W, edge_emb_b, edge_enc_W, edge_enc_b,
                                    pre_W, pre_b, Kc, cc);
    k_wfold<<<dim3(26, NL), 256, 0, stream>>>(post_W, lin_W, Wt3, foldT);
    k_bfold<<<NL, H, 0, stream>>>(post_b, lin_b, lin_W, cfold);

    // weight transpose+cast descriptor table (emb + 2 pre planes per layer)
    TDs tds;
    int nd = 0;
    tds.t[nd++] = TD{node_emb_W, embWt, FIN};
    for (int l = 0; l < NL; l++) {
        tds.t[nd++] = TD{pre_W + (size_t)l * 3 * H * H,         Wt3 + (size_t)(l * 3 + 0) * H * H, H};
        tds.t[nd++] = TD{pre_W + (size_t)l * 3 * H * H + H * H, Wt3 + (size_t)(l * 3 + 1) * H * H, H};
    }
    k_prepw<<<dim3(64, 9), 256, 0, stream>>>(tds);
    k_cast<<<(NN * FIN + 255) / 256, 256, 0, stream>>>(x, xb, NN * FIN);

    // h = x @ node_emb_W + b  (bf16 out only)
    k_mgemm<<<dim3(GB2, 1), 256, 0, stream>>>(xb, FIN, FIN, 1, embWt, FIN, 0,
                                              node_emb_b, nullptr, hb, 0);

    for (int l = 0; l < NL; l++) {
        int last = (l == NL - 1);
        // planesB bf16: [hW_dst | hW_src | hA'(=h@Wh@linW)]
        k_mgemm<<<dim3(GB2, 3), 256, 0, stream>>>(hb, H, H, 2,
                                                  Wt3 + (size_t)l * 3 * H * H, H, H * H,
                                                  nullptr, nullptr, planesB, 0);
        // phase A: per-slot messages (slot-parallel)
        k_edgem<<<NE / (4 * SLOTW), 256, 0, stream>>>(planesB, planesB + NP,
                                                      (const unsigned*)eattrP, csr_sd,
                                                      Kc + (size_t)l * 16 * H,
                                                      cc + (size_t)l * H, mbuf);
        // phase B: streaming segmented reduce (mbuf free afterwards)
        k_reduce<<<NN / 4, 256, 0, stream>>>(mbuf, row_ptr, aggb);
        // partials: p_g = agg @ (B_g@linW), g=0..2  (split-K by scale group)
        k_mgemm<<<dim3(GB2, 3), 256, 0, stream>>>(aggb, 4 * H, 4 * H, 8,
                                                  foldT + (size_t)l * 128 * 1664 + 128,
                                                  1664, 512,
                                                  nullptr, nullptr, partsB, 0);
        // combine: h = relu(hA' + p0 + amp*p1 + att*p2 + bias')
        k_comb<<<NP64 / 256, 256, 0, stream>>>((const unsigned*)(planesB + 2 * NP),
                                               (const unsigned*)partsB, amp, att,
                                               cfold + (size_t)l * H,
                                               (unsigned*)hb, last ? hf : nullptr);
    }

    k_pool<<<NG, 256, 0, stream>>>(hf, batch, head_W, head_b, out);
}

// Round 6
// 996.116 us; speedup vs baseline: 2.4238x; 1.1451x over previous
//
#include <hip/hip_runtime.h>

#define NN 50000
#define NE 400000
#define FIN 64
#define EIN 16
#define H 128
#define NL 4
#define NG 256
#define NOUT 12
#define EPSV 1e-5f

#define SB 256
#define NBLK ((NN + SB - 1) / SB)    // 196
#define GB2 ((NN + 127) / 128)       // 391 (128-row MFMA tiles)
#define NP64 (NN * 64)               // dwords per [NN,H] bf16 plane

typedef short bf16x8 __attribute__((ext_vector_type(8)));
typedef float f32x4 __attribute__((ext_vector_type(4)));

__device__ __forceinline__ unsigned short f2bf(float f) {
    unsigned u = __float_as_uint(f);
    u += 0x7fffu + ((u >> 16) & 1u);
    return (unsigned short)(u >> 16);
}

__device__ __forceinline__ float bflo(unsigned u) { return __uint_as_float(u << 16); }
__device__ __forceinline__ float bfhi(unsigned u) { return __uint_as_float(u & 0xffff0000u); }

// ---------------- setup kernels ----------------
__global__ void k_hist(const int* __restrict__ dst, int* __restrict__ deg) {
    int e = blockIdx.x * 256 + threadIdx.x;
    if (e < NE) atomicAdd(&deg[dst[e]], 1);
}

__global__ void k_scan1(const int* __restrict__ deg, int* __restrict__ partial) {
    __shared__ int sm[256];
    int i = blockIdx.x * 256 + threadIdx.x;
    sm[threadIdx.x] = (i < NN) ? deg[i] : 0;
    __syncthreads();
    for (int s = 128; s > 0; s >>= 1) {
        if (threadIdx.x < s) sm[threadIdx.x] += sm[threadIdx.x + s];
        __syncthreads();
    }
    if (threadIdx.x == 0) partial[blockIdx.x] = sm[0];
}

__global__ void k_scan2(int* __restrict__ partial, int* __restrict__ row_ptr, int nblk) {
    __shared__ int sm[256];
    int t = threadIdx.x;
    sm[t] = (t < nblk) ? partial[t] : 0;
    __syncthreads();
    for (int off = 1; off < 256; off <<= 1) {
        int v = (t >= off) ? sm[t - off] : 0;
        __syncthreads();
        sm[t] += v;
        __syncthreads();
    }
    int excl = (t == 0) ? 0 : sm[t - 1];
    if (t < nblk) partial[t] = excl;
    if (t == 0) row_ptr[0] = 0;
}

__global__ void k_scan3(const int* __restrict__ deg, const int* __restrict__ partial,
                        int* __restrict__ row_ptr) {
    __shared__ int sm[256];
    int t = threadIdx.x;
    int i = blockIdx.x * 256 + t;
    sm[t] = (i < NN) ? deg[i] : 0;
    __syncthreads();
    for (int off = 1; off < 256; off <<= 1) {
        int v = (t >= off) ? sm[t - off] : 0;
        __syncthreads();
        sm[t] += v;
        __syncthreads();
    }
    if (i < NN) row_ptr[i + 1] = partial[blockIdx.x] + sm[t];
}

__global__ void k_fill(const int* __restrict__ src, const int* __restrict__ dst,
                       const int* __restrict__ row_ptr, int* __restrict__ cursor,
                       int* __restrict__ csr_src, int* __restrict__ csr_eid) {
    int e = blockIdx.x * 256 + threadIdx.x;
    if (e >= NE) return;
    int d = dst[e];
    int pos = atomicAdd(&cursor[d], 1);
    int slot = row_ptr[d] + pos;
    csr_src[slot] = src[e];
    csr_eid[slot] = e;
}

// eattr permuted into CSR slot order, cast to bf16 (one-time; reused by all 4 layers)
__global__ void k_eperm(const float* __restrict__ eattr, const int* __restrict__ csr_eid,
                        unsigned short* __restrict__ eattrP) {
    int idx = blockIdx.x * 256 + threadIdx.x;
    if (idx >= NE * EIN) return;
    int slot = idx >> 4, j = idx & 15;
    eattrP[idx] = f2bf(eattr[(size_t)csr_eid[slot] * EIN + j]);
}

__global__ void k_sumlog(const int* __restrict__ deg, float* __restrict__ sum) {
    int i = blockIdx.x * 256 + threadIdx.x;
    float v = (i < NN) ? log1pf((float)deg[i]) : 0.f;
    #pragma unroll
    for (int off = 32; off > 0; off >>= 1) v += __shfl_down(v, off, 64);
    if ((threadIdx.x & 63) == 0) atomicAdd(sum, v);
}

__global__ void k_scalers(const int* __restrict__ deg, const float* __restrict__ sumlog,
                          float* __restrict__ amp, float* __restrict__ att) {
    int i = blockIdx.x * 256 + threadIdx.x;
    if (i >= NN) return;
    float avg = sumlog[0] / (float)NN;
    float degc = fmaxf((float)deg[i], 1.0f);
    float la = logf(degc + 1.0f);
    amp[i] = la / avg;
    att[i] = avg / la;
}

// Per-layer fold: K_l = embW @ encW_l @ preW_l[2H:]  (16x128)
__global__ void k_wprep(const float* __restrict__ embW, const float* __restrict__ emb_b,
                        const float* __restrict__ encW, const float* __restrict__ enc_b,
                        const float* __restrict__ preW, const float* __restrict__ pre_b,
                        float* __restrict__ Kc, float* __restrict__ cc) {
    int l = blockIdx.x;
    const float* encWl = encW + (size_t)l * H * H;
    const float* preW2 = preW + (size_t)l * 3 * H * H + 2 * H * H;
    __shared__ float T1[16 * H];
    __shared__ float b1[H];
    int t = threadIdx.x;
    for (int idx = t; idx < 16 * H; idx += 256) {
        int r = idx / H, j = idx % H;
        float s = 0.f;
        for (int k = 0; k < H; k++) s = fmaf(embW[r * H + k], encWl[k * H + j], s);
        T1[idx] = s;
    }
    if (t < H) {
        float s = enc_b[l * H + t];
        for (int k = 0; k < H; k++) s = fmaf(emb_b[k], encWl[k * H + t], s);
        b1[t] = s;
    }
    __syncthreads();
    for (int idx = t; idx < 16 * H; idx += 256) {
        int r = idx / H, j = idx % H;
        float s = 0.f;
        for (int k = 0; k < H; k++) s = fmaf(T1[r * H + k], preW2[k * H + j], s);
        Kc[l * 16 * H + idx] = s;
    }
    if (t < H) {
        float s = pre_b[l * H + t];
        for (int k = 0; k < H; k++) s = fmaf(b1[k], preW2[k * H + t], s);
        cc[l * H + t] = s;
    }
}

// ---------------- weight transpose+cast: D[n][k] = bf16(S[k][n]), S has 128 cols ----------------
struct TD { const float* S; unsigned short* D; int K; };
struct TDs { TD t[9]; };

__global__ void k_prepw(TDs p) {
    TD d = p.t[blockIdx.y];
    int idx = blockIdx.x * 256 + threadIdx.x;
    int total = d.K << 7;
    if (idx < total) {
        int k = idx >> 7, n = idx & 127;
        d.D[(size_t)n * d.K + k] = f2bf(d.S[(size_t)k * 128 + n]);
    }
}

__global__ void k_cast(const float* __restrict__ S, unsigned short* __restrict__ D, int n) {
    int i = blockIdx.x * 256 + threadIdx.x;
    if (i < n) D[i] = f2bf(S[i]);
}

// ---------------- weight fold: fold_l = postW_l @ linW_l  (fp32 acc, bf16-T out) --------------
__global__ __launch_bounds__(256) void k_wfold(const float* __restrict__ postW,
                                               const float* __restrict__ linW,
                                               unsigned short* __restrict__ Wt3,
                                               unsigned short* __restrict__ foldT) {
    __shared__ float As[32][68];
    __shared__ float Bs[32][128];
    int l = blockIdx.y;
    const float* A = postW + (size_t)l * 13 * H * H;   // [1664][128]
    const float* Bp = linW + (size_t)l * H * H;        // [128][128]
    int m0 = blockIdx.x * 64;
    int tid = threadIdx.x;
    int tx = tid & 31, ty = tid >> 5;
    float4 acc[8];
    #pragma unroll
    for (int r = 0; r < 8; r++) acc[r] = make_float4(0, 0, 0, 0);
    int f = tid & 7, r0 = tid >> 3;
    int cf = tid & 31, kr0 = tid >> 5;
    for (int k0 = 0; k0 < H; k0 += 32) {
        #pragma unroll
        for (int hh = 0; hh < 2; hh++) {
            int r = r0 + hh * 32;
            float4 v = *(const float4*)(A + (size_t)(m0 + r) * H + k0 + f * 4);
            As[f * 4 + 0][r] = v.x; As[f * 4 + 1][r] = v.y;
            As[f * 4 + 2][r] = v.z; As[f * 4 + 3][r] = v.w;
        }
        #pragma unroll
        for (int hh = 0; hh < 4; hh++) {
            int kr = kr0 + hh * 8;
            *(float4*)&Bs[kr][cf * 4] = *(const float4*)(Bp + (size_t)(k0 + kr) * H + cf * 4);
        }
        __syncthreads();
        #pragma unroll
        for (int kk = 0; kk < 32; kk++) {
            float4 b = *(float4*)&Bs[kk][tx * 4];
            float4 a0 = *(float4*)&As[kk][ty * 8];
            float4 a1 = *(float4*)&As[kk][ty * 8 + 4];
            acc[0].x = fmaf(a0.x, b.x, acc[0].x); acc[0].y = fmaf(a0.x, b.y, acc[0].y);
            acc[0].z = fmaf(a0.x, b.z, acc[0].z); acc[0].w = fmaf(a0.x, b.w, acc[0].w);
            acc[1].x = fmaf(a0.y, b.x, acc[1].x); acc[1].y = fmaf(a0.y, b.y, acc[1].y);
            acc[1].z = fmaf(a0.y, b.z, acc[1].z); acc[1].w = fmaf(a0.y, b.w, acc[1].w);
            acc[2].x = fmaf(a0.z, b.x, acc[2].x); acc[2].y = fmaf(a0.z, b.y, acc[2].y);
            acc[2].z = fmaf(a0.z, b.z, acc[2].z); acc[2].w = fmaf(a0.z, b.w, acc[2].w);
            acc[3].x = fmaf(a0.w, b.x, acc[3].x); acc[3].y = fmaf(a0.w, b.y, acc[3].y);
            acc[3].z = fmaf(a0.w, b.z, acc[3].z); acc[3].w = fmaf(a0.w, b.w, acc[3].w);
            acc[4].x = fmaf(a1.x, b.x, acc[4].x); acc[4].y = fmaf(a1.x, b.y, acc[4].y);
            acc[4].z = fmaf(a1.x, b.z, acc[4].z); acc[4].w = fmaf(a1.x, b.w, acc[4].w);
            acc[5].x = fmaf(a1.y, b.x, acc[5].x); acc[5].y = fmaf(a1.y, b.y, acc[5].y);
            acc[5].z = fmaf(a1.y, b.z, acc[5].z); acc[5].w = fmaf(a1.y, b.w, acc[5].w);
            acc[6].x = fmaf(a1.z, b.x, acc[6].x); acc[6].y = fmaf(a1.z, b.y, acc[6].y);
            acc[6].z = fmaf(a1.z, b.z, acc[6].z); acc[6].w = fmaf(a1.z, b.w, acc[6].w);
            acc[7].x = fmaf(a1.w, b.x, acc[7].x); acc[7].y = fmaf(a1.w, b.y, acc[7].y);
            acc[7].z = fmaf(a1.w, b.z, acc[7].z); acc[7].w = fmaf(a1.w, b.w, acc[7].w);
        }
        __syncthreads();
    }
    unsigned short* w2 = Wt3 + (size_t)(l * 3 + 2) * H * H;
    unsigned short* ft = foldT + (size_t)l * 128 * 1664;
    int r = m0 + ty * 8;
    #pragma unroll
    for (int c = 0; c < 4; c++) {
        int n = tx * 4 + c;
        unsigned short tmp[8] __attribute__((aligned(16)));
        #pragma unroll
        for (int rr = 0; rr < 8; rr++) tmp[rr] = f2bf(((const float*)&acc[rr])[c]);
        unsigned short* dstp = (r < 128) ? (w2 + (size_t)n * 128 + r)
                                         : (ft + (size_t)n * 1664 + r);
        *(uint4*)dstp = *(const uint4*)tmp;
    }
}

// bias' = pb @ linW + lb  (per layer)
__global__ void k_bfold(const float* __restrict__ pb, const float* __restrict__ lb,
                        const float* __restrict__ linW, float* __restrict__ cf) {
    int l = blockIdx.x, n = threadIdx.x;
    const float* B = linW + (size_t)l * H * H;
    float s = lb[l * H + n];
    for (int j = 0; j < H; j++) s = fmaf(pb[l * H + j], B[j * H + n], s);
    cf[l * H + n] = s;
}

// ---------------- bf16 MFMA GEMM ----------------
__global__ __launch_bounds__(256, 3) void k_mgemm(
    const unsigned short* __restrict__ A, int lda, int K, int nch,
    const unsigned short* __restrict__ Bt, int ldb, int bstride_y,
    const float* __restrict__ bias,
    float* __restrict__ outF, unsigned short* __restrict__ outB, int relu)
{
    __shared__ unsigned short As[128][72];
    __shared__ unsigned short Bs[128][72];
    const unsigned short* Btp = Bt + (size_t)blockIdx.y * bstride_y;
    int m0 = blockIdx.x * 128;
    int tid = threadIdx.x;
    int wave = tid >> 6, lane = tid & 63;
    int wr = wave >> 1, wc = wave & 1;
    int ln = lane & 15, q = lane >> 4;

    f32x4 acc[4][4];
    #pragma unroll
    for (int a = 0; a < 4; a++)
        #pragma unroll
        for (int b = 0; b < 4; b++) acc[a][b] = (f32x4){0.f, 0.f, 0.f, 0.f};

    for (int c = 0; c < nch; c++) {
        int col = c * 64;
        #pragma unroll
        for (int i0 = 0; i0 < 4; i0++) {
            int i = tid + i0 * 256;
            int row = i >> 3, seg = i & 7;
            uint4 bv = *(const uint4*)(Btp + (size_t)row * ldb + col + seg * 8);
            *(uint4*)(&Bs[row][seg * 8]) = bv;
            int rowg = m0 + row;
            uint4 av = make_uint4(0, 0, 0, 0);
            if (rowg < NN) av = *(const uint4*)(A + (size_t)rowg * lda + col + seg * 8);
            *(uint4*)(&As[row][seg * 8]) = av;
        }
        __syncthreads();
        #pragma unroll
        for (int kq = 0; kq < 2; kq++) {
            bf16x8 af[4], bfr[4];
            #pragma unroll
            for (int f = 0; f < 4; f++) {
                af[f]  = *(const bf16x8*)(&As[wr * 64 + f * 16 + ln][kq * 32 + q * 8]);
                bfr[f] = *(const bf16x8*)(&Bs[wc * 64 + f * 16 + ln][kq * 32 + q * 8]);
            }
            #pragma unroll
            for (int fr = 0; fr < 4; fr++)
                #pragma unroll
                for (int fc = 0; fc < 4; fc++)
                    acc[fr][fc] = __builtin_amdgcn_mfma_f32_16x16x32_bf16(
                        af[fr], bfr[fc], acc[fr][fc], 0, 0, 0);
        }
        __syncthreads();
    }

    float* outFp = outF ? outF + (size_t)blockIdx.y * NN * H : nullptr;
    unsigned short* outBp = outB ? outB + (size_t)blockIdx.y * NN * H : nullptr;
    #pragma unroll
    for (int fc = 0; fc < 4; fc++) {
        int col = wc * 64 + fc * 16 + ln;
        float bv = bias ? bias[col] : 0.f;
        #pragma unroll
        for (int fr = 0; fr < 4; fr++) {
            int rowb = m0 + wr * 64 + fr * 16 + q * 4;
            #pragma unroll
            for (int r = 0; r < 4; r++) {
                int rowg = rowb + r;
                if (rowg < NN) {
                    float v = acc[fr][fc][r] + bv;
                    if (relu) v = fmaxf(v, 0.f);
                    if (outFp) outFp[(size_t)rowg * H + col] = v;
                    if (outBp) outBp[(size_t)rowg * H + col] = f2bf(v);
                }
            }
        }
    }
}

// ---------------- fused aggregation: one wave per node ----------------
// All per-slot loads are wave-uniform (scalarized via readfirstlane loop bounds:
// csr_src + eattr rows become s_loads) except the coalesced 4B/lane hWs row read.
// m = hWd[i] + hWs[src] + E@K + c computed in fp32 regs; sum/sumsq/min/max in regs.
__global__ __launch_bounds__(256) void k_agg2(
    const unsigned short* __restrict__ pd, const unsigned short* __restrict__ ps,
    const uint4* __restrict__ eattrP,     // [E][2] uint4 (16 bf16, slot-ordered)
    const int* __restrict__ csr_src, const int* __restrict__ row_ptr,
    const float* __restrict__ Kl, const float* __restrict__ cl,
    unsigned short* __restrict__ agg)
{
    int wv = threadIdx.x >> 6, lane = threadIdx.x & 63;
    int i = blockIdx.x * 4 + wv;
    int d0 = lane * 2;
    float2 kr[16];
    #pragma unroll
    for (int k = 0; k < 16; k++) kr[k] = *(const float2*)(Kl + k * H + d0);
    float2 c2 = *(const float2*)(cl + d0);
    unsigned hd = *(const unsigned*)(pd + (size_t)i * H + d0);
    float bx = c2.x + bflo(hd);
    float by = c2.y + bfhi(hd);
    int rs = __builtin_amdgcn_readfirstlane(row_ptr[i]);
    int re = __builtin_amdgcn_readfirstlane(row_ptr[i + 1]);
    float sx = 0.f, sy = 0.f, qx = 0.f, qy = 0.f;
    float mnx = 3.0e38f, mny = 3.0e38f, mxx = -3.0e38f, mxy = -3.0e38f;

    // depth-2 software pipeline on the uniform (scalar) loads
    int src = (rs < re) ? csr_src[rs] : 0;
    uint4 e0 = (rs < re) ? eattrP[(size_t)rs * 2]     : make_uint4(0, 0, 0, 0);
    uint4 e1 = (rs < re) ? eattrP[(size_t)rs * 2 + 1] : make_uint4(0, 0, 0, 0);

    for (int slot = rs; slot < re; slot++) {
        // coalesced per-lane load for the current slot (issued immediately)
        unsigned hs = *(const unsigned*)(ps + (size_t)src * H + d0);
        // prefetch next slot's scalars
        int nx = slot + 1;
        int src_n = (nx < re) ? csr_src[nx] : 0;
        uint4 e0n = (nx < re) ? eattrP[(size_t)nx * 2]     : make_uint4(0, 0, 0, 0);
        uint4 e1n = (nx < re) ? eattrP[(size_t)nx * 2 + 1] : make_uint4(0, 0, 0, 0);
        // E@K on scalar eattr operands (no dependence on hs)
        unsigned eu[8] = {e0.x, e0.y, e0.z, e0.w, e1.x, e1.y, e1.z, e1.w};
        float ex = 0.f, ey = 0.f;
        #pragma unroll
        for (int j = 0; j < 8; j++) {
            float elo = __uint_as_float(eu[j] << 16);
            float ehi = __uint_as_float(eu[j] & 0xffff0000u);
            ex = fmaf(elo, kr[2 * j].x, ex);     ey = fmaf(elo, kr[2 * j].y, ey);
            ex = fmaf(ehi, kr[2 * j + 1].x, ex); ey = fmaf(ehi, kr[2 * j + 1].y, ey);
        }
        float ax = bx + bflo(hs) + ex;
        float ay = by + bfhi(hs) + ey;
        sx += ax; sy += ay;
        qx = fmaf(ax, ax, qx); qy = fmaf(ay, ay, qy);
        mnx = fminf(mnx, ax); mny = fminf(mny, ay);
        mxx = fmaxf(mxx, ax); mxy = fmaxf(mxy, ay);
        src = src_n; e0 = e0n; e1 = e1n;
    }

    int dg = re - rs;
    float dinv = 1.0f / fmaxf((float)dg, 1.0f);
    float mex = sx * dinv, mey = sy * dinv;
    float sdx = sqrtf(fmaxf(qx * dinv - mex * mex, 0.f) + EPSV);
    float sdy = sqrtf(fmaxf(qy * dinv - mey * mey, 0.f) + EPSV);
    if (dg == 0) { mnx = 0.f; mny = 0.f; mxx = 0.f; mxy = 0.f; }
    unsigned short* ap = agg + (size_t)i * 512 + d0;
    *(unsigned*)(ap)       = (unsigned)f2bf(mex) | ((unsigned)f2bf(mey) << 16);
    *(unsigned*)(ap + 128) = (unsigned)f2bf(mnx) | ((unsigned)f2bf(mny) << 16);
    *(unsigned*)(ap + 256) = (unsigned)f2bf(mxx) | ((unsigned)f2bf(mxy) << 16);
    *(unsigned*)(ap + 384) = (unsigned)f2bf(sdx) | ((unsigned)f2bf(sdy) << 16);
}

// ---------------- combine: h = relu(hA' + p0 + amp*p1 + att*p2 + bias') ----------------
__global__ __launch_bounds__(256) void k_comb(const unsigned* __restrict__ ha,
                                              const unsigned* __restrict__ part,
                                              const float* __restrict__ amp,
                                              const float* __restrict__ att,
                                              const float* __restrict__ biasf,
                                              unsigned* __restrict__ hbo,
                                              float* __restrict__ hfo) {
    int dv = blockIdx.x * 256 + threadIdx.x;
    int i = dv >> 6;
    int cp = dv & 63;
    float a = amp[i], t = att[i];
    unsigned uh = ha[dv];
    unsigned p0 = part[dv];
    unsigned p1 = part[dv + NP64];
    unsigned p2 = part[dv + 2 * NP64];
    float lo = bflo(uh) + bflo(p0) + a * bflo(p1) + t * bflo(p2) + biasf[cp * 2];
    float hi = bfhi(uh) + bfhi(p0) + a * bfhi(p1) + t * bfhi(p2) + biasf[cp * 2 + 1];
    lo = fmaxf(lo, 0.f); hi = fmaxf(hi, 0.f);
    hbo[dv] = (unsigned)f2bf(lo) | ((unsigned)f2bf(hi) << 16);
    if (hfo) { hfo[dv * 2] = lo; hfo[dv * 2 + 1] = hi; }
}

// ---------------- pooling + head ----------------
__device__ __forceinline__ int lbound(const int* a, int n, int v) {
    int lo = 0, hi = n;
    while (lo < hi) { int m = (lo + hi) >> 1; if (a[m] < v) lo = m + 1; else hi = m; }
    return lo;
}

__global__ __launch_bounds__(256) void k_pool(const float* __restrict__ h,
                                              const int* __restrict__ batch,
                                              const float* __restrict__ headW,
                                              const float* __restrict__ headb,
                                              float* __restrict__ out) {
    __shared__ float sm[256];
    int g = blockIdx.x;
    int t = threadIdx.x;
    int col = t & 127;
    int half = t >> 7;
    int lo = lbound(batch, NN, g);
    int hi = lbound(batch, NN, g + 1);
    int mid = lo + ((hi - lo) >> 1);
    int b0 = half ? mid : lo;
    int b1 = half ? hi : mid;
    float acc = 0.f;
    for (int i = b0; i < b1; i++) acc += h[(size_t)i * H + col];
    sm[t] = acc;
    __syncthreads();
    if (t < 128) sm[t] += sm[t + 128];
    __syncthreads();
    if (t < NOUT) {
        float r = headb[t];
        for (int j = 0; j < H; j++) r = fmaf(sm[j], headW[j * NOUT + t], r);
        out[g * NOUT + t] = r;
    }
}

// ---------------- launch ----------------
extern "C" void kernel_launch(void* const* d_in, const int* in_sizes, int n_in,
                              void* d_out, int out_size, void* d_ws, size_t ws_size,
                              hipStream_t stream) {
    const float* x          = (const float*)d_in[0];
    const float* edge_attr  = (const float*)d_in[1];
    const int*   src        = (const int*)d_in[2];
    const int*   dst        = (const int*)d_in[3];
    const int*   batch      = (const int*)d_in[4];
    const float* node_emb_W = (const float*)d_in[5];
    const float* node_emb_b = (const float*)d_in[6];
    const float* edge_emb_W = (const float*)d_in[7];
    const float* edge_emb_b = (const float*)d_in[8];
    const float* edge_enc_W = (const float*)d_in[9];
    const float* edge_enc_b = (const float*)d_in[10];
    const float* pre_W      = (const float*)d_in[11];
    const float* pre_b      = (const float*)d_in[12];
    const float* post_W     = (const float*)d_in[13];
    const float* post_b     = (const float*)d_in[14];
    const float* lin_W      = (const float*)d_in[15];
    const float* lin_b      = (const float*)d_in[16];
    const float* head_W     = (const float*)d_in[17];
    const float* head_b     = (const float*)d_in[18];
    float* out = (float*)d_out;

    char* wp = (char*)d_ws;
    auto carve = [&](size_t bytes) -> char* {
        char* r = wp;
        wp += (bytes + 255) & ~(size_t)255;
        return r;
    };
    int*   deg     = (int*)carve((size_t)NN * 4);
    int*   cursor  = (int*)carve((size_t)NN * 4);
    float* sumlog  = (float*)carve(4);
    int*   partial = (int*)carve(256 * 4);
    int*   row_ptr = (int*)carve((size_t)(NN + 1) * 4);
    int*   csr_src = (int*)carve((size_t)NE * 4);
    int*   csr_eid = (int*)carve((size_t)NE * 4);
    float* amp     = (float*)carve((size_t)NN * 4);
    float* att     = (float*)carve((size_t)NN * 4);
    float* Kc      = (float*)carve((size_t)NL * 16 * H * 4);
    float* cc      = (float*)carve((size_t)NL * H * 4);
    float* cfold   = (float*)carve((size_t)NL * H * 4);
    unsigned short* eattrP = (unsigned short*)carve((size_t)NE * EIN * 2);
    unsigned short* embWt  = (unsigned short*)carve((size_t)H * FIN * 2);
    unsigned short* Wt3    = (unsigned short*)carve((size_t)NL * 3 * H * H * 2);
    unsigned short* foldT  = (unsigned short*)carve((size_t)NL * 128 * 1664 * 2);
    unsigned short* xb     = (unsigned short*)carve((size_t)NN * FIN * 2);
    unsigned short* hb     = (unsigned short*)carve((size_t)NN * H * 2);
    unsigned short* planesB= (unsigned short*)carve((size_t)3 * NN * H * 2);
    unsigned short* aggb   = (unsigned short*)carve((size_t)NN * 4 * H * 2);
    unsigned short* partsB = (unsigned short*)carve((size_t)3 * NN * H * 2);
    float* hf      = (float*)carve((size_t)NN * H * 4);

    const size_t NP = (size_t)NN * H;

    hipMemsetAsync(deg, 0, (size_t)NN * 4, stream);
    hipMemsetAsync(cursor, 0, (size_t)NN * 4, stream);
    hipMemsetAsync(sumlog, 0, 4, stream);

    k_hist<<<(NE + 255) / 256, 256, 0, stream>>>(dst, deg);
    k_scan1<<<NBLK, 256, 0, stream>>>(deg, partial);
    k_scan2<<<1, 256, 0, stream>>>(partial, row_ptr, NBLK);
    k_scan3<<<NBLK, 256, 0, stream>>>(deg, partial, row_ptr);
    k_fill<<<(NE + 255) / 256, 256, 0, stream>>>(src, dst, row_ptr, cursor, csr_src, csr_eid);
    k_eperm<<<(NE * EIN + 255) / 256, 256, 0, stream>>>(edge_attr, csr_eid, eattrP);
    k_sumlog<<<NBLK, 256, 0, stream>>>(deg, sumlog);
    k_scalers<<<NBLK, 256, 0, stream>>>(deg, sumlog, amp, att);
    k_wprep<<<NL, 256, 0, stream>>>(edge_emb_W, edge_emb_b, edge_enc_W, edge_enc_b,
                                    pre_W, pre_b, Kc, cc);
    k_wfold<<<dim3(26, NL), 256, 0, stream>>>(post_W, lin_W, Wt3, foldT);
    k_bfold<<<NL, H, 0, stream>>>(post_b, lin_b, lin_W, cfold);

    TDs tds;
    int nd = 0;
    tds.t[nd++] = TD{node_emb_W, embWt, FIN};
    for (int l = 0; l < NL; l++) {
        tds.t[nd++] = TD{pre_W + (size_t)l * 3 * H * H,         Wt3 + (size_t)(l * 3 + 0) * H * H, H};
        tds.t[nd++] = TD{pre_W + (size_t)l * 3 * H * H + H * H, Wt3 + (size_t)(l * 3 + 1) * H * H, H};
    }
    k_prepw<<<dim3(64, 9), 256, 0, stream>>>(tds);
    k_cast<<<(NN * FIN + 255) / 256, 256, 0, stream>>>(x, xb, NN * FIN);

    // h = x @ node_emb_W + b  (bf16 out only)
    k_mgemm<<<dim3(GB2, 1), 256, 0, stream>>>(xb, FIN, FIN, 1, embWt, FIN, 0,
                                              node_emb_b, nullptr, hb, 0);

    for (int l = 0; l < NL; l++) {
        int last = (l == NL - 1);
        // planesB bf16: [hW_dst | hW_src | hA'(=h@Wh@linW)]
        k_mgemm<<<dim3(GB2, 3), 256, 0, stream>>>(hb, H, H, 2,
                                                  Wt3 + (size_t)l * 3 * H * H, H, H * H,
                                                  nullptr, nullptr, planesB, 0);
        // fused aggregation (replaces edgem+reduce; no mbuf)
        k_agg2<<<NN / 4, 256, 0, stream>>>(planesB, planesB + NP,
                                           (const uint4*)eattrP, csr_src, row_ptr,
                                           Kc + (size_t)l * 16 * H, cc + (size_t)l * H,
                                           aggb);
        // partials: p_g = agg @ (B_g@linW), g=0..2  (split-K by scale group)
        k_mgemm<<<dim3(GB2, 3), 256, 0, stream>>>(aggb, 4 * H, 4 * H, 8,
                                                  foldT + (size_t)l * 128 * 1664 + 128,
                                                  1664, 512,
                                                  nullptr, nullptr, partsB, 0);
        // combine: h = relu(hA' + p0 + amp*p1 + att*p2 + bias')
        k_comb<<<NP64 / 256, 256, 0, stream>>>((const unsigned*)(planesB + 2 * NP),
                                               (const unsigned*)partsB, amp, att,
                                               cfold + (size_t)l * H,
                                               (unsigned*)hb, last ? hf : nullptr);
    }

    k_pool<<<NG, 256, 0, stream>>>(hf, batch, head_W, head_b, out);
}

// Round 7
// 864.281 us; speedup vs baseline: 2.7936x; 1.1525x over previous
//
#include <hip/hip_runtime.h>

#define NN 50000
#define NE 400000
#define FIN 64
#define EIN 16
#define H 128
#define NL 4
#define NG 256
#define NOUT 12
#define EPSV 1e-5f

#define SB 256
#define NBLK ((NN + SB - 1) / SB)    // 196
#define GB2 ((NN + 127) / 128)       // 391 (128-row MFMA tiles)
#define NP64 (NN * 64)               // dwords per [NN,H] bf16 plane

typedef short bf16x8 __attribute__((ext_vector_type(8)));
typedef float f32x4 __attribute__((ext_vector_type(4)));

__device__ __forceinline__ unsigned short f2bf(float f) {
    unsigned u = __float_as_uint(f);
    u += 0x7fffu + ((u >> 16) & 1u);
    return (unsigned short)(u >> 16);
}

__device__ __forceinline__ float bflo(unsigned u) { return __uint_as_float(u << 16); }
__device__ __forceinline__ float bfhi(unsigned u) { return __uint_as_float(u & 0xffff0000u); }

// ---------------- setup kernels ----------------
__global__ void k_hist(const int* __restrict__ dst, int* __restrict__ deg) {
    int e = blockIdx.x * 256 + threadIdx.x;
    if (e < NE) atomicAdd(&deg[dst[e]], 1);
}

__global__ void k_scan1(const int* __restrict__ deg, int* __restrict__ partial) {
    __shared__ int sm[256];
    int i = blockIdx.x * 256 + threadIdx.x;
    sm[threadIdx.x] = (i < NN) ? deg[i] : 0;
    __syncthreads();
    for (int s = 128; s > 0; s >>= 1) {
        if (threadIdx.x < s) sm[threadIdx.x] += sm[threadIdx.x + s];
        __syncthreads();
    }
    if (threadIdx.x == 0) partial[blockIdx.x] = sm[0];
}

__global__ void k_scan2(int* __restrict__ partial, int* __restrict__ row_ptr, int nblk) {
    __shared__ int sm[256];
    int t = threadIdx.x;
    sm[t] = (t < nblk) ? partial[t] : 0;
    __syncthreads();
    for (int off = 1; off < 256; off <<= 1) {
        int v = (t >= off) ? sm[t - off] : 0;
        __syncthreads();
        sm[t] += v;
        __syncthreads();
    }
    int excl = (t == 0) ? 0 : sm[t - 1];
    if (t < nblk) partial[t] = excl;
    if (t == 0) row_ptr[0] = 0;
}

__global__ void k_scan3(const int* __restrict__ deg, const int* __restrict__ partial,
                        int* __restrict__ row_ptr) {
    __shared__ int sm[256];
    int t = threadIdx.x;
    int i = blockIdx.x * 256 + t;
    sm[t] = (i < NN) ? deg[i] : 0;
    __syncthreads();
    for (int off = 1; off < 256; off <<= 1) {
        int v = (t >= off) ? sm[t - off] : 0;
        __syncthreads();
        sm[t] += v;
        __syncthreads();
    }
    if (i < NN) row_ptr[i + 1] = partial[blockIdx.x] + sm[t];
}

__global__ void k_fill(const int* __restrict__ src, const int* __restrict__ dst,
                       const int* __restrict__ row_ptr, int* __restrict__ cursor,
                       int* __restrict__ csr_src, int* __restrict__ csr_eid) {
    int e = blockIdx.x * 256 + threadIdx.x;
    if (e >= NE) return;
    int d = dst[e];
    int pos = atomicAdd(&cursor[d], 1);
    int slot = row_ptr[d] + pos;
    csr_src[slot] = src[e];
    csr_eid[slot] = e;
}

// eattr permuted into CSR slot order, cast to bf16 (one-time; reused by all 4 layers)
__global__ void k_eperm(const float* __restrict__ eattr, const int* __restrict__ csr_eid,
                        unsigned short* __restrict__ eattrP) {
    int idx = blockIdx.x * 256 + threadIdx.x;
    if (idx >= NE * EIN) return;
    int slot = idx >> 4, j = idx & 15;
    eattrP[idx] = f2bf(eattr[(size_t)csr_eid[slot] * EIN + j]);
}

__global__ void k_sumlog(const int* __restrict__ deg, float* __restrict__ sum) {
    int i = blockIdx.x * 256 + threadIdx.x;
    float v = (i < NN) ? log1pf((float)deg[i]) : 0.f;
    #pragma unroll
    for (int off = 32; off > 0; off >>= 1) v += __shfl_down(v, off, 64);
    if ((threadIdx.x & 63) == 0) atomicAdd(sum, v);
}

__global__ void k_scalers(const int* __restrict__ deg, const float* __restrict__ sumlog,
                          float* __restrict__ amp, float* __restrict__ att) {
    int i = blockIdx.x * 256 + threadIdx.x;
    if (i >= NN) return;
    float avg = sumlog[0] / (float)NN;
    float degc = fmaxf((float)deg[i], 1.0f);
    float la = logf(degc + 1.0f);
    amp[i] = la / avg;
    att[i] = avg / la;
}

// Per-layer fold: K_l = embW @ encW_l @ preW_l[2H:]  (16x128)
__global__ void k_wprep(const float* __restrict__ embW, const float* __restrict__ emb_b,
                        const float* __restrict__ encW, const float* __restrict__ enc_b,
                        const float* __restrict__ preW, const float* __restrict__ pre_b,
                        float* __restrict__ Kc, float* __restrict__ cc) {
    int l = blockIdx.x;
    const float* encWl = encW + (size_t)l * H * H;
    const float* preW2 = preW + (size_t)l * 3 * H * H + 2 * H * H;
    __shared__ float T1[16 * H];
    __shared__ float b1[H];
    int t = threadIdx.x;
    for (int idx = t; idx < 16 * H; idx += 256) {
        int r = idx / H, j = idx % H;
        float s = 0.f;
        for (int k = 0; k < H; k++) s = fmaf(embW[r * H + k], encWl[k * H + j], s);
        T1[idx] = s;
    }
    if (t < H) {
        float s = enc_b[l * H + t];
        for (int k = 0; k < H; k++) s = fmaf(emb_b[k], encWl[k * H + t], s);
        b1[t] = s;
    }
    __syncthreads();
    for (int idx = t; idx < 16 * H; idx += 256) {
        int r = idx / H, j = idx % H;
        float s = 0.f;
        for (int k = 0; k < H; k++) s = fmaf(T1[r * H + k], preW2[k * H + j], s);
        Kc[l * 16 * H + idx] = s;
    }
    if (t < H) {
        float s = pre_b[l * H + t];
        for (int k = 0; k < H; k++) s = fmaf(b1[k], preW2[k * H + t], s);
        cc[l * H + t] = s;
    }
}

// ---------------- weight transpose+cast: D[n][k] = bf16(S[k][n]), S has 128 cols ----------------
struct TD { const float* S; unsigned short* D; int K; };
struct TDs { TD t[9]; };

__global__ void k_prepw(TDs p) {
    TD d = p.t[blockIdx.y];
    int idx = blockIdx.x * 256 + threadIdx.x;
    int total = d.K << 7;
    if (idx < total) {
        int k = idx >> 7, n = idx & 127;
        d.D[(size_t)n * d.K + k] = f2bf(d.S[(size_t)k * 128 + n]);
    }
}

__global__ void k_cast(const float* __restrict__ S, unsigned short* __restrict__ D, int n) {
    int i = blockIdx.x * 256 + threadIdx.x;
    if (i < n) D[i] = f2bf(S[i]);
}

// ---------------- weight fold: fold_l = postW_l @ linW_l  (fp32 acc, bf16-T out) --------------
__global__ __launch_bounds__(256) void k_wfold(const float* __restrict__ postW,
                                               const float* __restrict__ linW,
                                               unsigned short* __restrict__ Wt3,
                                               unsigned short* __restrict__ foldT) {
    __shared__ float As[32][68];
    __shared__ float Bs[32][128];
    int l = blockIdx.y;
    const float* A = postW + (size_t)l * 13 * H * H;   // [1664][128]
    const float* Bp = linW + (size_t)l * H * H;        // [128][128]
    int m0 = blockIdx.x * 64;
    int tid = threadIdx.x;
    int tx = tid & 31, ty = tid >> 5;
    float4 acc[8];
    #pragma unroll
    for (int r = 0; r < 8; r++) acc[r] = make_float4(0, 0, 0, 0);
    int f = tid & 7, r0 = tid >> 3;
    int cf = tid & 31, kr0 = tid >> 5;
    for (int k0 = 0; k0 < H; k0 += 32) {
        #pragma unroll
        for (int hh = 0; hh < 2; hh++) {
            int r = r0 + hh * 32;
            float4 v = *(const float4*)(A + (size_t)(m0 + r) * H + k0 + f * 4);
            As[f * 4 + 0][r] = v.x; As[f * 4 + 1][r] = v.y;
            As[f * 4 + 2][r] = v.z; As[f * 4 + 3][r] = v.w;
        }
        #pragma unroll
        for (int hh = 0; hh < 4; hh++) {
            int kr = kr0 + hh * 8;
            *(float4*)&Bs[kr][cf * 4] = *(const float4*)(Bp + (size_t)(k0 + kr) * H + cf * 4);
        }
        __syncthreads();
        #pragma unroll
        for (int kk = 0; kk < 32; kk++) {
            float4 b = *(float4*)&Bs[kk][tx * 4];
            float4 a0 = *(float4*)&As[kk][ty * 8];
            float4 a1 = *(float4*)&As[kk][ty * 8 + 4];
            acc[0].x = fmaf(a0.x, b.x, acc[0].x); acc[0].y = fmaf(a0.x, b.y, acc[0].y);
            acc[0].z = fmaf(a0.x, b.z, acc[0].z); acc[0].w = fmaf(a0.x, b.w, acc[0].w);
            acc[1].x = fmaf(a0.y, b.x, acc[1].x); acc[1].y = fmaf(a0.y, b.y, acc[1].y);
            acc[1].z = fmaf(a0.y, b.z, acc[1].z); acc[1].w = fmaf(a0.y, b.w, acc[1].w);
            acc[2].x = fmaf(a0.z, b.x, acc[2].x); acc[2].y = fmaf(a0.z, b.y, acc[2].y);
            acc[2].z = fmaf(a0.z, b.z, acc[2].z); acc[2].w = fmaf(a0.z, b.w, acc[2].w);
            acc[3].x = fmaf(a0.w, b.x, acc[3].x); acc[3].y = fmaf(a0.w, b.y, acc[3].y);
            acc[3].z = fmaf(a0.w, b.z, acc[3].z); acc[3].w = fmaf(a0.w, b.w, acc[3].w);
            acc[4].x = fmaf(a1.x, b.x, acc[4].x); acc[4].y = fmaf(a1.x, b.y, acc[4].y);
            acc[4].z = fmaf(a1.x, b.z, acc[4].z); acc[4].w = fmaf(a1.x, b.w, acc[4].w);
            acc[5].x = fmaf(a1.y, b.x, acc[5].x); acc[5].y = fmaf(a1.y, b.y, acc[5].y);
            acc[5].z = fmaf(a1.y, b.z, acc[5].z); acc[5].w = fmaf(a1.y, b.w, acc[5].w);
            acc[6].x = fmaf(a1.z, b.x, acc[6].x); acc[6].y = fmaf(a1.z, b.y, acc[6].y);
            acc[6].z = fmaf(a1.z, b.z, acc[6].z); acc[6].w = fmaf(a1.z, b.w, acc[6].w);
            acc[7].x = fmaf(a1.w, b.x, acc[7].x); acc[7].y = fmaf(a1.w, b.y, acc[7].y);
            acc[7].z = fmaf(a1.w, b.z, acc[7].z); acc[7].w = fmaf(a1.w, b.w, acc[7].w);
        }
        __syncthreads();
    }
    unsigned short* w2 = Wt3 + (size_t)(l * 3 + 2) * H * H;
    unsigned short* ft = foldT + (size_t)l * 128 * 1664;
    int r = m0 + ty * 8;
    #pragma unroll
    for (int c = 0; c < 4; c++) {
        int n = tx * 4 + c;
        unsigned short tmp[8] __attribute__((aligned(16)));
        #pragma unroll
        for (int rr = 0; rr < 8; rr++) tmp[rr] = f2bf(((const float*)&acc[rr])[c]);
        unsigned short* dstp = (r < 128) ? (w2 + (size_t)n * 128 + r)
                                         : (ft + (size_t)n * 1664 + r);
        *(uint4*)dstp = *(const uint4*)tmp;
    }
}

// bias' = pb @ linW + lb  (per layer)
__global__ void k_bfold(const float* __restrict__ pb, const float* __restrict__ lb,
                        const float* __restrict__ linW, float* __restrict__ cf) {
    int l = blockIdx.x, n = threadIdx.x;
    const float* B = linW + (size_t)l * H * H;
    float s = lb[l * H + n];
    for (int j = 0; j < H; j++) s = fmaf(pb[l * H + j], B[j * H + n], s);
    cf[l * H + n] = s;
}

// ---------------- bf16 MFMA GEMM ----------------
// grid = (nplanes, row_tiles): consecutive blocks share the A row-slice (L2/L3 reuse).
// Operands SWAPPED in the mfma (computes D^T fragment): each lane holds 4 consecutive
// COLUMNS -> epilogue packs 4 bf16 = 8B ds_write_b64 into an LDS tile, then fully
// coalesced uint4 global stores (fixes 1.9x partial-line write inflation).
__global__ __launch_bounds__(256, 4) void k_mgemm(
    const unsigned short* __restrict__ A, int lda, int K, int nch,
    const unsigned short* __restrict__ Bt, int ldb, int bstride_y,
    const float* __restrict__ bias, unsigned short* __restrict__ outB)
{
    __shared__ unsigned short SH[2][128][72];   // staging; reused as 128x136 C-tile
    const unsigned short* Btp = Bt + (size_t)blockIdx.x * bstride_y;
    int m0 = blockIdx.y * 128;
    int tid = threadIdx.x;
    int wave = tid >> 6, lane = tid & 63;
    int wr = wave >> 1, wc = wave & 1;
    int ln = lane & 15, q = lane >> 4;

    f32x4 acc[4][4];
    #pragma unroll
    for (int a = 0; a < 4; a++)
        #pragma unroll
        for (int b = 0; b < 4; b++) acc[a][b] = (f32x4){0.f, 0.f, 0.f, 0.f};

    for (int c = 0; c < nch; c++) {
        int col = c * 64;
        #pragma unroll
        for (int i0 = 0; i0 < 4; i0++) {
            int i = tid + i0 * 256;
            int row = i >> 3, seg = i & 7;
            uint4 bv = *(const uint4*)(Btp + (size_t)row * ldb + col + seg * 8);
            *(uint4*)(&SH[1][row][seg * 8]) = bv;
            int rowg = m0 + row;
            uint4 av = make_uint4(0, 0, 0, 0);
            if (rowg < NN) av = *(const uint4*)(A + (size_t)rowg * lda + col + seg * 8);
            *(uint4*)(&SH[0][row][seg * 8]) = av;
        }
        __syncthreads();
        #pragma unroll
        for (int kq = 0; kq < 2; kq++) {
            bf16x8 af[4], bfr[4];
            #pragma unroll
            for (int f = 0; f < 4; f++) {
                af[f]  = *(const bf16x8*)(&SH[0][wr * 64 + f * 16 + ln][kq * 32 + q * 8]);
                bfr[f] = *(const bf16x8*)(&SH[1][wc * 64 + f * 16 + ln][kq * 32 + q * 8]);
            }
            #pragma unroll
            for (int fr = 0; fr < 4; fr++)
                #pragma unroll
                for (int fc = 0; fc < 4; fc++)
                    acc[fr][fc] = __builtin_amdgcn_mfma_f32_16x16x32_bf16(
                        bfr[fc], af[fr], acc[fr][fc], 0, 0, 0);   // swapped: D^T
        }
        __syncthreads();
    }

    // epilogue: lane holds rows wr*64+fr*16+ln, cols wc*64+fc*16+q*4 .. +3
    unsigned short* CT = &SH[0][0][0];   // 128 x (stride 136)
    #pragma unroll
    for (int fr = 0; fr < 4; fr++) {
        int rloc = wr * 64 + fr * 16 + ln;
        #pragma unroll
        for (int fc = 0; fc < 4; fc++) {
            int colb = wc * 64 + fc * 16 + q * 4;
            float4 bv = bias ? *(const float4*)(bias + colb) : make_float4(0, 0, 0, 0);
            unsigned short tmp[4] __attribute__((aligned(8)));
            tmp[0] = f2bf(acc[fr][fc][0] + bv.x);
            tmp[1] = f2bf(acc[fr][fc][1] + bv.y);
            tmp[2] = f2bf(acc[fr][fc][2] + bv.z);
            tmp[3] = f2bf(acc[fr][fc][3] + bv.w);
            *(uint2*)(&CT[rloc * 136 + colb]) = *(const uint2*)tmp;
        }
    }
    __syncthreads();
    unsigned short* outBp = outB + (size_t)blockIdx.x * NN * H;
    #pragma unroll
    for (int i0 = 0; i0 < 8; i0++) {
        int idx = tid + i0 * 256;
        int row = idx >> 4, seg = idx & 15;
        int rowg = m0 + row;
        if (rowg < NN)
            *(uint4*)(outBp + (size_t)rowg * H + seg * 8) = *(const uint4*)(&CT[row * 136 + seg * 8]);
    }
}

// ---------------- fused aggregation: one wave per node ----------------
__global__ __launch_bounds__(256) void k_agg2(
    const unsigned short* __restrict__ pd, const unsigned short* __restrict__ ps,
    const uint4* __restrict__ eattrP,     // [E][2] uint4 (16 bf16, slot-ordered)
    const int* __restrict__ csr_src, const int* __restrict__ row_ptr,
    const float* __restrict__ Kl, const float* __restrict__ cl,
    unsigned short* __restrict__ agg)
{
    int wv = threadIdx.x >> 6, lane = threadIdx.x & 63;
    int i = blockIdx.x * 4 + wv;
    int d0 = lane * 2;
    float2 kr[16];
    #pragma unroll
    for (int k = 0; k < 16; k++) kr[k] = *(const float2*)(Kl + k * H + d0);
    float2 c2 = *(const float2*)(cl + d0);
    unsigned hd = *(const unsigned*)(pd + (size_t)i * H + d0);
    float bx = c2.x + bflo(hd);
    float by = c2.y + bfhi(hd);
    int rs = __builtin_amdgcn_readfirstlane(row_ptr[i]);
    int re = __builtin_amdgcn_readfirstlane(row_ptr[i + 1]);
    float sx = 0.f, sy = 0.f, qx = 0.f, qy = 0.f;
    float mnx = 3.0e38f, mny = 3.0e38f, mxx = -3.0e38f, mxy = -3.0e38f;

    int src = (rs < re) ? csr_src[rs] : 0;
    uint4 e0 = (rs < re) ? eattrP[(size_t)rs * 2]     : make_uint4(0, 0, 0, 0);
    uint4 e1 = (rs < re) ? eattrP[(size_t)rs * 2 + 1] : make_uint4(0, 0, 0, 0);

    for (int slot = rs; slot < re; slot++) {
        unsigned hs = *(const unsigned*)(ps + (size_t)src * H + d0);
        int nx = slot + 1;
        int src_n = (nx < re) ? csr_src[nx] : 0;
        uint4 e0n = (nx < re) ? eattrP[(size_t)nx * 2]     : make_uint4(0, 0, 0, 0);
        uint4 e1n = (nx < re) ? eattrP[(size_t)nx * 2 + 1] : make_uint4(0, 0, 0, 0);
        unsigned eu[8] = {e0.x, e0.y, e0.z, e0.w, e1.x, e1.y, e1.z, e1.w};
        float ex = 0.f, ey = 0.f;
        #pragma unroll
        for (int j = 0; j < 8; j++) {
            float elo = __uint_as_float(eu[j] << 16);
            float ehi = __uint_as_float(eu[j] & 0xffff0000u);
            ex = fmaf(elo, kr[2 * j].x, ex);     ey = fmaf(elo, kr[2 * j].y, ey);
            ex = fmaf(ehi, kr[2 * j + 1].x, ex); ey = fmaf(ehi, kr[2 * j + 1].y, ey);
        }
        float ax = bx + bflo(hs) + ex;
        float ay = by + bfhi(hs) + ey;
        sx += ax; sy += ay;
        qx = fmaf(ax, ax, qx); qy = fmaf(ay, ay, qy);
        mnx = fminf(mnx, ax); mny = fminf(mny, ay);
        mxx = fmaxf(mxx, ax); mxy = fmaxf(mxy, ay);
        src = src_n; e0 = e0n; e1 = e1n;
    }

    int dg = re - rs;
    float dinv = 1.0f / fmaxf((float)dg, 1.0f);
    float mex = sx * dinv, mey = sy * dinv;
    float sdx = sqrtf(fmaxf(qx * dinv - mex * mex, 0.f) + EPSV);
    float sdy = sqrtf(fmaxf(qy * dinv - mey * mey, 0.f) + EPSV);
    if (dg == 0) { mnx = 0.f; mny = 0.f; mxx = 0.f; mxy = 0.f; }
    unsigned short* ap = agg + (size_t)i * 512 + d0;
    *(unsigned*)(ap)       = (unsigned)f2bf(mex) | ((unsigned)f2bf(mey) << 16);
    *(unsigned*)(ap + 128) = (unsigned)f2bf(mnx) | ((unsigned)f2bf(mny) << 16);
    *(unsigned*)(ap + 256) = (unsigned)f2bf(mxx) | ((unsigned)f2bf(mxy) << 16);
    *(unsigned*)(ap + 384) = (unsigned)f2bf(sdx) | ((unsigned)f2bf(sdy) << 16);
}

// ---------------- combine: h = relu(hA' + p0 + amp*p1 + att*p2 + bias') ----------------
__global__ __launch_bounds__(256) void k_comb(const unsigned* __restrict__ ha,
                                              const unsigned* __restrict__ part,
                                              const float* __restrict__ amp,
                                              const float* __restrict__ att,
                                              const float* __restrict__ biasf,
                                              unsigned* __restrict__ hbo,
                                              float* __restrict__ hfo) {
    int dv = blockIdx.x * 256 + threadIdx.x;
    int i = dv >> 6;
    int cp = dv & 63;
    float a = amp[i], t = att[i];
    unsigned uh = ha[dv];
    unsigned p0 = part[dv];
    unsigned p1 = part[dv + NP64];
    unsigned p2 = part[dv + 2 * NP64];
    float lo = bflo(uh) + bflo(p0) + a * bflo(p1) + t * bflo(p2) + biasf[cp * 2];
    float hi = bfhi(uh) + bfhi(p0) + a * bfhi(p1) + t * bfhi(p2) + biasf[cp * 2 + 1];
    lo = fmaxf(lo, 0.f); hi = fmaxf(hi, 0.f);
    hbo[dv] = (unsigned)f2bf(lo) | ((unsigned)f2bf(hi) << 16);
    if (hfo) { hfo[dv * 2] = lo; hfo[dv * 2 + 1] = hi; }
}

// ---------------- pooling + head ----------------
__device__ __forceinline__ int lbound(const int* a, int n, int v) {
    int lo = 0, hi = n;
    while (lo < hi) { int m = (lo + hi) >> 1; if (a[m] < v) lo = m + 1; else hi = m; }
    return lo;
}

__global__ __launch_bounds__(256) void k_pool(const float* __restrict__ h,
                                              const int* __restrict__ batch,
                                              const float* __restrict__ headW,
                                              const float* __restrict__ headb,
                                              float* __restrict__ out) {
    __shared__ float sm[256];
    int g = blockIdx.x;
    int t = threadIdx.x;
    int col = t & 127;
    int half = t >> 7;
    int lo = lbound(batch, NN, g);
    int hi = lbound(batch, NN, g + 1);
    int mid = lo + ((hi - lo) >> 1);
    int b0 = half ? mid : lo;
    int b1 = half ? hi : mid;
    float acc = 0.f;
    for (int i = b0; i < b1; i++) acc += h[(size_t)i * H + col];
    sm[t] = acc;
    __syncthreads();
    if (t < 128) sm[t] += sm[t + 128];
    __syncthreads();
    if (t < NOUT) {
        float r = headb[t];
        for (int j = 0; j < H; j++) r = fmaf(sm[j], headW[j * NOUT + t], r);
        out[g * NOUT + t] = r;
    }
}

// ---------------- launch ----------------
extern "C" void kernel_launch(void* const* d_in, const int* in_sizes, int n_in,
                              void* d_out, int out_size, void* d_ws, size_t ws_size,
                              hipStream_t stream) {
    const float* x          = (const float*)d_in[0];
    const float* edge_attr  = (const float*)d_in[1];
    const int*   src        = (const int*)d_in[2];
    const int*   dst        = (const int*)d_in[3];
    const int*   batch      = (const int*)d_in[4];
    const float* node_emb_W = (const float*)d_in[5];
    const float* node_emb_b = (const float*)d_in[6];
    const float* edge_emb_W = (const float*)d_in[7];
    const float* edge_emb_b = (const float*)d_in[8];
    const float* edge_enc_W = (const float*)d_in[9];
    const float* edge_enc_b = (const float*)d_in[10];
    const float* pre_W      = (const float*)d_in[11];
    const float* pre_b      = (const float*)d_in[12];
    const float* post_W     = (const float*)d_in[13];
    const float* post_b     = (const float*)d_in[14];
    const float* lin_W      = (const float*)d_in[15];
    const float* lin_b      = (const float*)d_in[16];
    const float* head_W     = (const float*)d_in[17];
    const float* head_b     = (const float*)d_in[18];
    float* out = (float*)d_out;

    char* wp = (char*)d_ws;
    auto carve = [&](size_t bytes) -> char* {
        char* r = wp;
        wp += (bytes + 255) & ~(size_t)255;
        return r;
    };
    int*   deg     = (int*)carve((size_t)NN * 4);
    int*   cursor  = (int*)carve((size_t)NN * 4);
    float* sumlog  = (float*)carve(4);
    int*   partial = (int*)carve(256 * 4);
    int*   row_ptr = (int*)carve((size_t)(NN + 1) * 4);
    int*   csr_src = (int*)carve((size_t)NE * 4);
    int*   csr_eid = (int*)carve((size_t)NE * 4);
    float* amp     = (float*)carve((size_t)NN * 4);
    float* att     = (float*)carve((size_t)NN * 4);
    float* Kc      = (float*)carve((size_t)NL * 16 * H * 4);
    float* cc      = (float*)carve((size_t)NL * H * 4);
    float* cfold   = (float*)carve((size_t)NL * H * 4);
    unsigned short* eattrP = (unsigned short*)carve((size_t)NE * EIN * 2);
    unsigned short* embWt  = (unsigned short*)carve((size_t)H * FIN * 2);
    unsigned short* Wt3    = (unsigned short*)carve((size_t)NL * 3 * H * H * 2);
    unsigned short* foldT  = (unsigned short*)carve((size_t)NL * 128 * 1664 * 2);
    unsigned short* xb     = (unsigned short*)carve((size_t)NN * FIN * 2);
    unsigned short* hb     = (unsigned short*)carve((size_t)NN * H * 2);
    unsigned short* planesB= (unsigned short*)carve((size_t)3 * NN * H * 2);
    unsigned short* aggb   = (unsigned short*)carve((size_t)NN * 4 * H * 2);
    unsigned short* partsB = (unsigned short*)carve((size_t)3 * NN * H * 2);
    float* hf      = (float*)carve((size_t)NN * H * 4);

    const size_t NP = (size_t)NN * H;

    hipMemsetAsync(deg, 0, (size_t)NN * 4, stream);
    hipMemsetAsync(cursor, 0, (size_t)NN * 4, stream);
    hipMemsetAsync(sumlog, 0, 4, stream);

    k_hist<<<(NE + 255) / 256, 256, 0, stream>>>(dst, deg);
    k_scan1<<<NBLK, 256, 0, stream>>>(deg, partial);
    k_scan2<<<1, 256, 0, stream>>>(partial, row_ptr, NBLK);
    k_scan3<<<NBLK, 256, 0, stream>>>(deg, partial, row_ptr);
    k_fill<<<(NE + 255) / 256, 256, 0, stream>>>(src, dst, row_ptr, cursor, csr_src, csr_eid);
    k_eperm<<<(NE * EIN + 255) / 256, 256, 0, stream>>>(edge_attr, csr_eid, eattrP);
    k_sumlog<<<NBLK, 256, 0, stream>>>(deg, sumlog);
    k_scalers<<<NBLK, 256, 0, stream>>>(deg, sumlog, amp, att);
    k_wprep<<<NL, 256, 0, stream>>>(edge_emb_W, edge_emb_b, edge_enc_W, edge_enc_b,
                                    pre_W, pre_b, Kc, cc);
    k_wfold<<<dim3(26, NL), 256, 0, stream>>>(post_W, lin_W, Wt3, foldT);
    k_bfold<<<NL, H, 0, stream>>>(post_b, lin_b, lin_W, cfold);

    TDs tds;
    int nd = 0;
    tds.t[nd++] = TD{node_emb_W, embWt, FIN};
    for (int l = 0; l < NL; l++) {
        tds.t[nd++] = TD{pre_W + (size_t)l * 3 * H * H,         Wt3 + (size_t)(l * 3 + 0) * H * H, H};
        tds.t[nd++] = TD{pre_W + (size_t)l * 3 * H * H + H * H, Wt3 + (size_t)(l * 3 + 1) * H * H, H};
    }
    k_prepw<<<dim3(64, 9), 256, 0, stream>>>(tds);
    k_cast<<<(NN * FIN + 255) / 256, 256, 0, stream>>>(x, xb, NN * FIN);

    // h = x @ node_emb_W + b  (bf16 out)
    k_mgemm<<<dim3(1, GB2), 256, 0, stream>>>(xb, FIN, FIN, 1, embWt, FIN, 0,
                                              node_emb_b, hb);

    for (int l = 0; l < NL; l++) {
        int last = (l == NL - 1);
        // planesB bf16: [hW_dst | hW_src | hA'(=h@Wh@linW)]
        k_mgemm<<<dim3(3, GB2), 256, 0, stream>>>(hb, H, H, 2,
                                                  Wt3 + (size_t)l * 3 * H * H, H, H * H,
                                                  nullptr, planesB);
        // fused aggregation
        k_agg2<<<NN / 4, 256, 0, stream>>>(planesB, planesB + NP,
                                           (const uint4*)eattrP, csr_src, row_ptr,
                                           Kc + (size_t)l * 16 * H, cc + (size_t)l * H,
                                           aggb);
        // partials: p_g = agg @ (B_g@linW), g=0..2  (split-K by scale group)
        k_mgemm<<<dim3(3, GB2), 256, 0, stream>>>(aggb, 4 * H, 4 * H, 8,
                                                  foldT + (size_t)l * 128 * 1664 + 128,
                                                  1664, 512,
                                                  nullptr, partsB);
        // combine: h = relu(hA' + p0 + amp*p1 + att*p2 + bias')
        k_comb<<<NP64 / 256, 256, 0, stream>>>((const unsigned*)(planesB + 2 * NP),
                                               (const unsigned*)partsB, amp, att,
                                               cfold + (size_t)l * H,
                                               (unsigned*)hb, last ? hf : nullptr);
    }

    k_pool<<<NG, 256, 0, stream>>>(hf, batch, head_W, head_b, out);
}

// Round 8
// 817.429 us; speedup vs baseline: 2.9537x; 1.0573x over previous
//
#include <hip/hip_runtime.h>

#define NN 50000
#define NE 400000
#define FIN 64
#define EIN 16
#define H 128
#define NL 4
#define NG 256
#define NOUT 12
#define EPSV 1e-5f

#define SB 256
#define NBLK ((NN + SB - 1) / SB)    // 196
#define GB2 ((NN + 127) / 128)       // 391 (128-row MFMA tiles)
#define NP64 (NN * 64)               // dwords per [NN,H] bf16 plane

typedef short bf16x8 __attribute__((ext_vector_type(8)));
typedef float f32x4 __attribute__((ext_vector_type(4)));

__device__ __forceinline__ unsigned short f2bf(float f) {
    unsigned u = __float_as_uint(f);
    u += 0x7fffu + ((u >> 16) & 1u);
    return (unsigned short)(u >> 16);
}

__device__ __forceinline__ float bflo(unsigned u) { return __uint_as_float(u << 16); }
__device__ __forceinline__ float bfhi(unsigned u) { return __uint_as_float(u & 0xffff0000u); }

// ---------------- setup kernels ----------------
__global__ void k_hist(const int* __restrict__ dst, int* __restrict__ deg) {
    int e = blockIdx.x * 256 + threadIdx.x;
    if (e < NE) atomicAdd(&deg[dst[e]], 1);
}

__global__ void k_scan1(const int* __restrict__ deg, int* __restrict__ partial) {
    __shared__ int sm[256];
    int i = blockIdx.x * 256 + threadIdx.x;
    sm[threadIdx.x] = (i < NN) ? deg[i] : 0;
    __syncthreads();
    for (int s = 128; s > 0; s >>= 1) {
        if (threadIdx.x < s) sm[threadIdx.x] += sm[threadIdx.x + s];
        __syncthreads();
    }
    if (threadIdx.x == 0) partial[blockIdx.x] = sm[0];
}

__global__ void k_scan2(int* __restrict__ partial, int* __restrict__ row_ptr, int nblk) {
    __shared__ int sm[256];
    int t = threadIdx.x;
    sm[t] = (t < nblk) ? partial[t] : 0;
    __syncthreads();
    for (int off = 1; off < 256; off <<= 1) {
        int v = (t >= off) ? sm[t - off] : 0;
        __syncthreads();
        sm[t] += v;
        __syncthreads();
    }
    int excl = (t == 0) ? 0 : sm[t - 1];
    if (t < nblk) partial[t] = excl;
    if (t == 0) row_ptr[0] = 0;
}

__global__ void k_scan3(const int* __restrict__ deg, const int* __restrict__ partial,
                        int* __restrict__ row_ptr) {
    __shared__ int sm[256];
    int t = threadIdx.x;
    int i = blockIdx.x * 256 + t;
    sm[t] = (i < NN) ? deg[i] : 0;
    __syncthreads();
    for (int off = 1; off < 256; off <<= 1) {
        int v = (t >= off) ? sm[t - off] : 0;
        __syncthreads();
        sm[t] += v;
        __syncthreads();
    }
    if (i < NN) row_ptr[i + 1] = partial[blockIdx.x] + sm[t];
}

__global__ void k_fill(const int* __restrict__ src, const int* __restrict__ dst,
                       const int* __restrict__ row_ptr, int* __restrict__ cursor,
                       int* __restrict__ csr_src, int* __restrict__ csr_eid) {
    int e = blockIdx.x * 256 + threadIdx.x;
    if (e >= NE) return;
    int d = dst[e];
    int pos = atomicAdd(&cursor[d], 1);
    int slot = row_ptr[d] + pos;
    csr_src[slot] = src[e];
    csr_eid[slot] = e;
}

// eattr permuted into CSR slot order, fp32 (one-time; uniform rows -> s_loads in k_agg2)
__global__ void k_eperm(const float* __restrict__ eattr, const int* __restrict__ csr_eid,
                        float* __restrict__ eattrF) {
    int idx = blockIdx.x * 256 + threadIdx.x;
    if (idx >= NE * EIN) return;
    int slot = idx >> 4, j = idx & 15;
    eattrF[idx] = eattr[(size_t)csr_eid[slot] * EIN + j];
}

__global__ void k_sumlog(const int* __restrict__ deg, float* __restrict__ sum) {
    int i = blockIdx.x * 256 + threadIdx.x;
    float v = (i < NN) ? log1pf((float)deg[i]) : 0.f;
    #pragma unroll
    for (int off = 32; off > 0; off >>= 1) v += __shfl_down(v, off, 64);
    if ((threadIdx.x & 63) == 0) atomicAdd(sum, v);
}

__global__ void k_scalers(const int* __restrict__ deg, const float* __restrict__ sumlog,
                          float* __restrict__ amp, float* __restrict__ att) {
    int i = blockIdx.x * 256 + threadIdx.x;
    if (i >= NN) return;
    float avg = sumlog[0] / (float)NN;
    float degc = fmaxf((float)deg[i], 1.0f);
    float la = logf(degc + 1.0f);
    amp[i] = la / avg;
    att[i] = avg / la;
}

// Per-layer fold: K_l = embW @ encW_l @ preW_l[2H:]  (16x128)
__global__ void k_wprep(const float* __restrict__ embW, const float* __restrict__ emb_b,
                        const float* __restrict__ encW, const float* __restrict__ enc_b,
                        const float* __restrict__ preW, const float* __restrict__ pre_b,
                        float* __restrict__ Kc, float* __restrict__ cc) {
    int l = blockIdx.x;
    const float* encWl = encW + (size_t)l * H * H;
    const float* preW2 = preW + (size_t)l * 3 * H * H + 2 * H * H;
    __shared__ float T1[16 * H];
    __shared__ float b1[H];
    int t = threadIdx.x;
    for (int idx = t; idx < 16 * H; idx += 256) {
        int r = idx / H, j = idx % H;
        float s = 0.f;
        for (int k = 0; k < H; k++) s = fmaf(embW[r * H + k], encWl[k * H + j], s);
        T1[idx] = s;
    }
    if (t < H) {
        float s = enc_b[l * H + t];
        for (int k = 0; k < H; k++) s = fmaf(emb_b[k], encWl[k * H + t], s);
        b1[t] = s;
    }
    __syncthreads();
    for (int idx = t; idx < 16 * H; idx += 256) {
        int r = idx / H, j = idx % H;
        float s = 0.f;
        for (int k = 0; k < H; k++) s = fmaf(T1[r * H + k], preW2[k * H + j], s);
        Kc[l * 16 * H + idx] = s;
    }
    if (t < H) {
        float s = pre_b[l * H + t];
        for (int k = 0; k < H; k++) s = fmaf(b1[k], preW2[k * H + t], s);
        cc[l * H + t] = s;
    }
}

// ---------------- weight transpose+cast: D[n][k] = bf16(S[k][n]), S has 128 cols ----------------
struct TD { const float* S; unsigned short* D; int K; };
struct TDs { TD t[9]; };

__global__ void k_prepw(TDs p) {
    TD d = p.t[blockIdx.y];
    int idx = blockIdx.x * 256 + threadIdx.x;
    int total = d.K << 7;
    if (idx < total) {
        int k = idx >> 7, n = idx & 127;
        d.D[(size_t)n * d.K + k] = f2bf(d.S[(size_t)k * 128 + n]);
    }
}

__global__ void k_cast(const float* __restrict__ S, unsigned short* __restrict__ D, int n) {
    int i = blockIdx.x * 256 + threadIdx.x;
    if (i < n) D[i] = f2bf(S[i]);
}

// ---------------- weight fold: fold_l = postW_l @ linW_l  (fp32 acc, bf16-T out) --------------
__global__ __launch_bounds__(256) void k_wfold(const float* __restrict__ postW,
                                               const float* __restrict__ linW,
                                               unsigned short* __restrict__ Wt3,
                                               unsigned short* __restrict__ foldT) {
    __shared__ float As[32][68];
    __shared__ float Bs[32][128];
    int l = blockIdx.y;
    const float* A = postW + (size_t)l * 13 * H * H;   // [1664][128]
    const float* Bp = linW + (size_t)l * H * H;        // [128][128]
    int m0 = blockIdx.x * 64;
    int tid = threadIdx.x;
    int tx = tid & 31, ty = tid >> 5;
    float4 acc[8];
    #pragma unroll
    for (int r = 0; r < 8; r++) acc[r] = make_float4(0, 0, 0, 0);
    int f = tid & 7, r0 = tid >> 3;
    int cf = tid & 31, kr0 = tid >> 5;
    for (int k0 = 0; k0 < H; k0 += 32) {
        #pragma unroll
        for (int hh = 0; hh < 2; hh++) {
            int r = r0 + hh * 32;
            float4 v = *(const float4*)(A + (size_t)(m0 + r) * H + k0 + f * 4);
            As[f * 4 + 0][r] = v.x; As[f * 4 + 1][r] = v.y;
            As[f * 4 + 2][r] = v.z; As[f * 4 + 3][r] = v.w;
        }
        #pragma unroll
        for (int hh = 0; hh < 4; hh++) {
            int kr = kr0 + hh * 8;
            *(float4*)&Bs[kr][cf * 4] = *(const float4*)(Bp + (size_t)(k0 + kr) * H + cf * 4);
        }
        __syncthreads();
        #pragma unroll
        for (int kk = 0; kk < 32; kk++) {
            float4 b = *(float4*)&Bs[kk][tx * 4];
            float4 a0 = *(float4*)&As[kk][ty * 8];
            float4 a1 = *(float4*)&As[kk][ty * 8 + 4];
            acc[0].x = fmaf(a0.x, b.x, acc[0].x); acc[0].y = fmaf(a0.x, b.y, acc[0].y);
            acc[0].z = fmaf(a0.x, b.z, acc[0].z); acc[0].w = fmaf(a0.x, b.w, acc[0].w);
            acc[1].x = fmaf(a0.y, b.x, acc[1].x); acc[1].y = fmaf(a0.y, b.y, acc[1].y);
            acc[1].z = fmaf(a0.y, b.z, acc[1].z); acc[1].w = fmaf(a0.y, b.w, acc[1].w);
            acc[2].x = fmaf(a0.z, b.x, acc[2].x); acc[2].y = fmaf(a0.z, b.y, acc[2].y);
            acc[2].z = fmaf(a0.z, b.z, acc[2].z); acc[2].w = fmaf(a0.z, b.w, acc[2].w);
            acc[3].x = fmaf(a0.w, b.x, acc[3].x); acc[3].y = fmaf(a0.w, b.y, acc[3].y);
            acc[3].z = fmaf(a0.w, b.z, acc[3].z); acc[3].w = fmaf(a0.w, b.w, acc[3].w);
            acc[4].x = fmaf(a1.x, b.x, acc[4].x); acc[4].y = fmaf(a1.x, b.y, acc[4].y);
            acc[4].z = fmaf(a1.x, b.z, acc[4].z); acc[4].w = fmaf(a1.x, b.w, acc[4].w);
            acc[5].x = fmaf(a1.y, b.x, acc[5].x); acc[5].y = fmaf(a1.y, b.y, acc[5].y);
            acc[5].z = fmaf(a1.y, b.z, acc[5].z); acc[5].w = fmaf(a1.y, b.w, acc[5].w);
            acc[6].x = fmaf(a1.z, b.x, acc[6].x); acc[6].y = fmaf(a1.z, b.y, acc[6].y);
            acc[6].z = fmaf(a1.z, b.z, acc[6].z); acc[6].w = fmaf(a1.z, b.w, acc[6].w);
            acc[7].x = fmaf(a1.w, b.x, acc[7].x); acc[7].y = fmaf(a1.w, b.y, acc[7].y);
            acc[7].z = fmaf(a1.w, b.z, acc[7].z); acc[7].w = fmaf(a1.w, b.w, acc[7].w);
        }
        __syncthreads();
    }
    unsigned short* w2 = Wt3 + (size_t)(l * 3 + 2) * H * H;
    unsigned short* ft = foldT + (size_t)l * 128 * 1664;
    int r = m0 + ty * 8;
    #pragma unroll
    for (int c = 0; c < 4; c++) {
        int n = tx * 4 + c;
        unsigned short tmp[8] __attribute__((aligned(16)));
        #pragma unroll
        for (int rr = 0; rr < 8; rr++) tmp[rr] = f2bf(((const float*)&acc[rr])[c]);
        unsigned short* dstp = (r < 128) ? (w2 + (size_t)n * 128 + r)
                                         : (ft + (size_t)n * 1664 + r);
        *(uint4*)dstp = *(const uint4*)tmp;
    }
}

// bias' = pb @ linW + lb  (per layer)
__global__ void k_bfold(const float* __restrict__ pb, const float* __restrict__ lb,
                        const float* __restrict__ linW, float* __restrict__ cf) {
    int l = blockIdx.x, n = threadIdx.x;
    const float* B = linW + (size_t)l * H * H;
    float s = lb[l * H + n];
    for (int j = 0; j < H; j++) s = fmaf(pb[l * H + j], B[j * H + n], s);
    cf[l * H + n] = s;
}

// ---------------- bf16 MFMA GEMM (swapped-operand D^T epilogue, LDS-staged C) ----------------
__global__ __launch_bounds__(256, 4) void k_mgemm(
    const unsigned short* __restrict__ A, int lda, int K, int nch,
    const unsigned short* __restrict__ Bt, int ldb, int bstride_y,
    const float* __restrict__ bias, unsigned short* __restrict__ outB)
{
    __shared__ unsigned short SH[2][128][72];   // staging; reused as 128x136 C-tile
    const unsigned short* Btp = Bt + (size_t)blockIdx.x * bstride_y;
    int m0 = blockIdx.y * 128;
    int tid = threadIdx.x;
    int wave = tid >> 6, lane = tid & 63;
    int wr = wave >> 1, wc = wave & 1;
    int ln = lane & 15, q = lane >> 4;

    f32x4 acc[4][4];
    #pragma unroll
    for (int a = 0; a < 4; a++)
        #pragma unroll
        for (int b = 0; b < 4; b++) acc[a][b] = (f32x4){0.f, 0.f, 0.f, 0.f};

    for (int c = 0; c < nch; c++) {
        int col = c * 64;
        #pragma unroll
        for (int i0 = 0; i0 < 4; i0++) {
            int i = tid + i0 * 256;
            int row = i >> 3, seg = i & 7;
            uint4 bv = *(const uint4*)(Btp + (size_t)row * ldb + col + seg * 8);
            *(uint4*)(&SH[1][row][seg * 8]) = bv;
            int rowg = m0 + row;
            uint4 av = make_uint4(0, 0, 0, 0);
            if (rowg < NN) av = *(const uint4*)(A + (size_t)rowg * lda + col + seg * 8);
            *(uint4*)(&SH[0][row][seg * 8]) = av;
        }
        __syncthreads();
        #pragma unroll
        for (int kq = 0; kq < 2; kq++) {
            bf16x8 af[4], bfr[4];
            #pragma unroll
            for (int f = 0; f < 4; f++) {
                af[f]  = *(const bf16x8*)(&SH[0][wr * 64 + f * 16 + ln][kq * 32 + q * 8]);
                bfr[f] = *(const bf16x8*)(&SH[1][wc * 64 + f * 16 + ln][kq * 32 + q * 8]);
            }
            #pragma unroll
            for (int fr = 0; fr < 4; fr++)
                #pragma unroll
                for (int fc = 0; fc < 4; fc++)
                    acc[fr][fc] = __builtin_amdgcn_mfma_f32_16x16x32_bf16(
                        bfr[fc], af[fr], acc[fr][fc], 0, 0, 0);   // swapped: D^T
        }
        __syncthreads();
    }

    unsigned short* CT = &SH[0][0][0];   // 128 x (stride 136)
    #pragma unroll
    for (int fr = 0; fr < 4; fr++) {
        int rloc = wr * 64 + fr * 16 + ln;
        #pragma unroll
        for (int fc = 0; fc < 4; fc++) {
            int colb = wc * 64 + fc * 16 + q * 4;
            float4 bv = bias ? *(const float4*)(bias + colb) : make_float4(0, 0, 0, 0);
            unsigned short tmp[4] __attribute__((aligned(8)));
            tmp[0] = f2bf(acc[fr][fc][0] + bv.x);
            tmp[1] = f2bf(acc[fr][fc][1] + bv.y);
            tmp[2] = f2bf(acc[fr][fc][2] + bv.z);
            tmp[3] = f2bf(acc[fr][fc][3] + bv.w);
            *(uint2*)(&CT[rloc * 136 + colb]) = *(const uint2*)tmp;
        }
    }
    __syncthreads();
    unsigned short* outBp = outB + (size_t)blockIdx.x * NN * H;
    #pragma unroll
    for (int i0 = 0; i0 < 8; i0++) {
        int idx = tid + i0 * 256;
        int row = idx >> 4, seg = idx & 15;
        int rowg = m0 + row;
        if (rowg < NN)
            *(uint4*)(outBp + (size_t)rowg * H + seg * 8) = *(const uint4*)(&CT[row * 136 + seg * 8]);
    }
}

// ---------------- fused aggregation: one wave per node ----------------
// eattrF rows are wave-uniform fp32 -> s_load_dwordx* into SGPRs, feeding v_fma as
// the scalar operand (no unpack VALU). hs gathers pipelined depth-2; 2 slots/iter.
__global__ __launch_bounds__(256) void k_agg2(
    const unsigned short* __restrict__ pd, const unsigned short* __restrict__ ps,
    const float* __restrict__ eF,         // [E][16] fp32, slot-ordered
    const int* __restrict__ csr_src, const int* __restrict__ row_ptr,
    const float* __restrict__ Kl, const float* __restrict__ cl,
    unsigned short* __restrict__ agg)
{
    int wv = threadIdx.x >> 6, lane = threadIdx.x & 63;
    int i = blockIdx.x * 4 + wv;
    int d0 = lane * 2;
    float2 kr[16];
    #pragma unroll
    for (int k = 0; k < 16; k++) kr[k] = *(const float2*)(Kl + k * H + d0);
    float2 c2 = *(const float2*)(cl + d0);
    unsigned hd = *(const unsigned*)(pd + (size_t)i * H + d0);
    float bx = c2.x + bflo(hd);
    float by = c2.y + bfhi(hd);
    int rs = __builtin_amdgcn_readfirstlane(row_ptr[i]);
    int re = __builtin_amdgcn_readfirstlane(row_ptr[i + 1]);
    float sx = 0.f, sy = 0.f, qx = 0.f, qy = 0.f;
    float mnx = 3.0e38f, mny = 3.0e38f, mxx = -3.0e38f, mxy = -3.0e38f;

    // hs pipeline: loads for slots rs, rs+1 in flight
    int n0 = (rs < re)     ? __builtin_amdgcn_readfirstlane(csr_src[rs])     : 0;
    int n1 = (rs + 1 < re) ? __builtin_amdgcn_readfirstlane(csr_src[rs + 1]) : 0;
    unsigned hsA = *(const unsigned*)(ps + (size_t)n0 * H + d0);
    unsigned hsB = *(const unsigned*)(ps + (size_t)n1 * H + d0);

    int slot = rs;
    for (; slot + 1 < re; slot += 2) {
        // prefetch slots +2, +3
        int p0 = (slot + 2 < re) ? __builtin_amdgcn_readfirstlane(csr_src[slot + 2]) : 0;
        int p1 = (slot + 3 < re) ? __builtin_amdgcn_readfirstlane(csr_src[slot + 3]) : 0;
        unsigned hsC = *(const unsigned*)(ps + (size_t)p0 * H + d0);
        unsigned hsD = *(const unsigned*)(ps + (size_t)p1 * H + d0);
        const float* ea = eF + (size_t)slot * EIN;   // uniform -> s_load
        const float* eb = ea + EIN;
        float ax = bx + bflo(hsA), ay = by + bfhi(hsA);
        float cx = bx + bflo(hsB), cy = by + bfhi(hsB);
        #pragma unroll
        for (int j = 0; j < 16; j++) {
            float e1 = ea[j], e2 = eb[j];
            ax = fmaf(e1, kr[j].x, ax); ay = fmaf(e1, kr[j].y, ay);
            cx = fmaf(e2, kr[j].x, cx); cy = fmaf(e2, kr[j].y, cy);
        }
        sx += ax + cx; sy += ay + cy;
        qx = fmaf(ax, ax, fmaf(cx, cx, qx));
        qy = fmaf(ay, ay, fmaf(cy, cy, qy));
        mnx = fminf(mnx, fminf(ax, cx)); mny = fminf(mny, fminf(ay, cy));
        mxx = fmaxf(mxx, fmaxf(ax, cx)); mxy = fmaxf(mxy, fmaxf(ay, cy));
        hsA = hsC; hsB = hsD;
    }
    if (slot < re) {   // odd tail
        const float* ea = eF + (size_t)slot * EIN;
        float ax = bx + bflo(hsA), ay = by + bfhi(hsA);
        #pragma unroll
        for (int j = 0; j < 16; j++) {
            float e1 = ea[j];
            ax = fmaf(e1, kr[j].x, ax); ay = fmaf(e1, kr[j].y, ay);
        }
        sx += ax; sy += ay;
        qx = fmaf(ax, ax, qx); qy = fmaf(ay, ay, qy);
        mnx = fminf(mnx, ax); mny = fminf(mny, ay);
        mxx = fmaxf(mxx, ax); mxy = fmaxf(mxy, ay);
    }

    int dg = re - rs;
    float dinv = 1.0f / fmaxf((float)dg, 1.0f);
    float mex = sx * dinv, mey = sy * dinv;
    float sdx = sqrtf(fmaxf(qx * dinv - mex * mex, 0.f) + EPSV);
    float sdy = sqrtf(fmaxf(qy * dinv - mey * mey, 0.f) + EPSV);
    if (dg == 0) { mnx = 0.f; mny = 0.f; mxx = 0.f; mxy = 0.f; }
    unsigned short* ap = agg + (size_t)i * 512 + d0;
    *(unsigned*)(ap)       = (unsigned)f2bf(mex) | ((unsigned)f2bf(mey) << 16);
    *(unsigned*)(ap + 128) = (unsigned)f2bf(mnx) | ((unsigned)f2bf(mny) << 16);
    *(unsigned*)(ap + 256) = (unsigned)f2bf(mxx) | ((unsigned)f2bf(mxy) << 16);
    *(unsigned*)(ap + 384) = (unsigned)f2bf(sdx) | ((unsigned)f2bf(sdy) << 16);
}

// ---------------- combine: h = relu(hA' + p0 + amp*p1 + att*p2 + bias') ----------------
__global__ __launch_bounds__(256) void k_comb(const unsigned* __restrict__ ha,
                                              const unsigned* __restrict__ part,
                                              const float* __restrict__ amp,
                                              const float* __restrict__ att,
                                              const float* __restrict__ biasf,
                                              unsigned* __restrict__ hbo,
                                              float* __restrict__ hfo) {
    int dv = blockIdx.x * 256 + threadIdx.x;
    int i = dv >> 6;
    int cp = dv & 63;
    float a = amp[i], t = att[i];
    unsigned uh = ha[dv];
    unsigned p0 = part[dv];
    unsigned p1 = part[dv + NP64];
    unsigned p2 = part[dv + 2 * NP64];
    float lo = bflo(uh) + bflo(p0) + a * bflo(p1) + t * bflo(p2) + biasf[cp * 2];
    float hi = bfhi(uh) + bfhi(p0) + a * bfhi(p1) + t * bfhi(p2) + biasf[cp * 2 + 1];
    lo = fmaxf(lo, 0.f); hi = fmaxf(hi, 0.f);
    hbo[dv] = (unsigned)f2bf(lo) | ((unsigned)f2bf(hi) << 16);
    if (hfo) { hfo[dv * 2] = lo; hfo[dv * 2 + 1] = hi; }
}

// ---------------- pooling + head ----------------
__device__ __forceinline__ int lbound(const int* a, int n, int v) {
    int lo = 0, hi = n;
    while (lo < hi) { int m = (lo + hi) >> 1; if (a[m] < v) lo = m + 1; else hi = m; }
    return lo;
}

__global__ __launch_bounds__(256) void k_pool(const float* __restrict__ h,
                                              const int* __restrict__ batch,
                                              const float* __restrict__ headW,
                                              const float* __restrict__ headb,
                                              float* __restrict__ out) {
    __shared__ float sm[256];
    int g = blockIdx.x;
    int t = threadIdx.x;
    int col = t & 127;
    int half = t >> 7;
    int lo = lbound(batch, NN, g);
    int hi = lbound(batch, NN, g + 1);
    int mid = lo + ((hi - lo) >> 1);
    int b0 = half ? mid : lo;
    int b1 = half ? hi : mid;
    float acc = 0.f;
    for (int i = b0; i < b1; i++) acc += h[(size_t)i * H + col];
    sm[t] = acc;
    __syncthreads();
    if (t < 128) sm[t] += sm[t + 128];
    __syncthreads();
    if (t < NOUT) {
        float r = headb[t];
        for (int j = 0; j < H; j++) r = fmaf(sm[j], headW[j * NOUT + t], r);
        out[g * NOUT + t] = r;
    }
}

// ---------------- launch ----------------
extern "C" void kernel_launch(void* const* d_in, const int* in_sizes, int n_in,
                              void* d_out, int out_size, void* d_ws, size_t ws_size,
                              hipStream_t stream) {
    const float* x          = (const float*)d_in[0];
    const float* edge_attr  = (const float*)d_in[1];
    const int*   src        = (const int*)d_in[2];
    const int*   dst        = (const int*)d_in[3];
    const int*   batch      = (const int*)d_in[4];
    const float* node_emb_W = (const float*)d_in[5];
    const float* node_emb_b = (const float*)d_in[6];
    const float* edge_emb_W = (const float*)d_in[7];
    const float* edge_emb_b = (const float*)d_in[8];
    const float* edge_enc_W = (const float*)d_in[9];
    const float* edge_enc_b = (const float*)d_in[10];
    const float* pre_W      = (const float*)d_in[11];
    const float* pre_b      = (const float*)d_in[12];
    const float* post_W     = (const float*)d_in[13];
    const float* post_b     = (const float*)d_in[14];
    const float* lin_W      = (const float*)d_in[15];
    const float* lin_b      = (const float*)d_in[16];
    const float* head_W     = (const float*)d_in[17];
    const float* head_b     = (const float*)d_in[18];
    float* out = (float*)d_out;

    char* wp = (char*)d_ws;
    auto carve = [&](size_t bytes) -> char* {
        char* r = wp;
        wp += (bytes + 255) & ~(size_t)255;
        return r;
    };
    int*   deg     = (int*)carve((size_t)NN * 4);
    int*   cursor  = (int*)carve((size_t)NN * 4);
    float* sumlog  = (float*)carve(4);
    int*   partial = (int*)carve(256 * 4);
    int*   row_ptr = (int*)carve((size_t)(NN + 1) * 4);
    int*   csr_src = (int*)carve((size_t)NE * 4);
    int*   csr_eid = (int*)carve((size_t)NE * 4);
    float* amp     = (float*)carve((size_t)NN * 4);
    float* att     = (float*)carve((size_t)NN * 4);
    float* Kc      = (float*)carve((size_t)NL * 16 * H * 4);
    float* cc      = (float*)carve((size_t)NL * H * 4);
    float* cfold   = (float*)carve((size_t)NL * H * 4);
    float* eattrF  = (float*)carve((size_t)NE * EIN * 4);
    unsigned short* embWt  = (unsigned short*)carve((size_t)H * FIN * 2);
    unsigned short* Wt3    = (unsigned short*)carve((size_t)NL * 3 * H * H * 2);
    unsigned short* foldT  = (unsigned short*)carve((size_t)NL * 128 * 1664 * 2);
    unsigned short* xb     = (unsigned short*)carve((size_t)NN * FIN * 2);
    unsigned short* hb     = (unsigned short*)carve((size_t)NN * H * 2);
    unsigned short* planesB= (unsigned short*)carve((size_t)3 * NN * H * 2);
    unsigned short* aggb   = (unsigned short*)carve((size_t)NN * 4 * H * 2);
    unsigned short* partsB = (unsigned short*)carve((size_t)3 * NN * H * 2);
    float* hf      = (float*)carve((size_t)NN * H * 4);

    const size_t NP = (size_t)NN * H;

    hipMemsetAsync(deg, 0, (size_t)NN * 4, stream);
    hipMemsetAsync(cursor, 0, (size_t)NN * 4, stream);
    hipMemsetAsync(sumlog, 0, 4, stream);

    k_hist<<<(NE + 255) / 256, 256, 0, stream>>>(dst, deg);
    k_scan1<<<NBLK, 256, 0, stream>>>(deg, partial);
    k_scan2<<<1, 256, 0, stream>>>(partial, row_ptr, NBLK);
    k_scan3<<<NBLK, 256, 0, stream>>>(deg, partial, row_ptr);
    k_fill<<<(NE + 255) / 256, 256, 0, stream>>>(src, dst, row_ptr, cursor, csr_src, csr_eid);
    k_eperm<<<(NE * EIN + 255) / 256, 256, 0, stream>>>(edge_attr, csr_eid, eattrF);
    k_sumlog<<<NBLK, 256, 0, stream>>>(deg, sumlog);
    k_scalers<<<NBLK, 256, 0, stream>>>(deg, sumlog, amp, att);
    k_wprep<<<NL, 256, 0, stream>>>(edge_emb_W, edge_emb_b, edge_enc_W, edge_enc_b,
                                    pre_W, pre_b, Kc, cc);
    k_wfold<<<dim3(26, NL), 256, 0, stream>>>(post_W, lin_W, Wt3, foldT);
    k_bfold<<<NL, H, 0, stream>>>(post_b, lin_b, lin_W, cfold);

    TDs tds;
    int nd = 0;
    tds.t[nd++] = TD{node_emb_W, embWt, FIN};
    for (int l = 0; l < NL; l++) {
        tds.t[nd++] = TD{pre_W + (size_t)l * 3 * H * H,         Wt3 + (size_t)(l * 3 + 0) * H * H, H};
        tds.t[nd++] = TD{pre_W + (size_t)l * 3 * H * H + H * H, Wt3 + (size_t)(l * 3 + 1) * H * H, H};
    }
    k_prepw<<<dim3(64, 9), 256, 0, stream>>>(tds);
    k_cast<<<(NN * FIN + 255) / 256, 256, 0, stream>>>(x, xb, NN * FIN);

    // h = x @ node_emb_W + b  (bf16 out)
    k_mgemm<<<dim3(1, GB2), 256, 0, stream>>>(xb, FIN, FIN, 1, embWt, FIN, 0,
                                              node_emb_b, hb);

    for (int l = 0; l < NL; l++) {
        int last = (l == NL - 1);
        // planesB bf16: [hW_dst | hW_src | hA'(=h@Wh@linW)]
        k_mgemm<<<dim3(3, GB2), 256, 0, stream>>>(hb, H, H, 2,
                                                  Wt3 + (size_t)l * 3 * H * H, H, H * H,
                                                  nullptr, planesB);
        // fused aggregation
        k_agg2<<<NN / 4, 256, 0, stream>>>(planesB, planesB + NP,
                                           eattrF, csr_src, row_ptr,
                                           Kc + (size_t)l * 16 * H, cc + (size_t)l * H,
                                           aggb);
        // partials: p_g = agg @ (B_g@linW), g=0..2  (split-K by scale group)
        k_mgemm<<<dim3(3, GB2), 256, 0, stream>>>(aggb, 4 * H, 4 * H, 8,
                                                  foldT + (size_t)l * 128 * 1664 + 128,
                                                  1664, 512,
                                                  nullptr, partsB);
        // combine: h = relu(hA' + p0 + amp*p1 + att*p2 + bias')
        k_comb<<<NP64 / 256, 256, 0, stream>>>((const unsigned*)(planesB + 2 * NP),
                                               (const unsigned*)partsB, amp, att,
                                               cfold + (size_t)l * H,
                                               (unsigned*)hb, last ? hf : nullptr);
    }

    k_pool<<<NG, 256, 0, stream>>>(hf, batch, head_W, head_b, out);
}

// Round 9
// 785.766 us; speedup vs baseline: 3.0727x; 1.0403x over previous
//
#include <hip/hip_runtime.h>

#define NN 50000
#define NE 400000
#define FIN 64
#define EIN 16
#define H 128
#define NL 4
#define NG 256
#define NOUT 12
#define EPSV 1e-5f

#define SB 256
#define NBLK ((NN + SB - 1) / SB)    // 196
#define GB2 ((NN + 127) / 128)       // 391 (128-row MFMA tiles)
#define NP64 (NN * 64)               // dwords per [NN,H] bf16 plane

typedef short bf16x8 __attribute__((ext_vector_type(8)));
typedef float f32x4 __attribute__((ext_vector_type(4)));

__device__ __forceinline__ unsigned short f2bf(float f) {
    unsigned u = __float_as_uint(f);
    u += 0x7fffu + ((u >> 16) & 1u);
    return (unsigned short)(u >> 16);
}

__device__ __forceinline__ float bflo(unsigned u) { return __uint_as_float(u << 16); }
__device__ __forceinline__ float bfhi(unsigned u) { return __uint_as_float(u & 0xffff0000u); }

// ---------------- setup kernels ----------------
__global__ void k_hist(const int* __restrict__ dst, int* __restrict__ deg) {
    int e = blockIdx.x * 256 + threadIdx.x;
    if (e < NE) atomicAdd(&deg[dst[e]], 1);
}

__global__ void k_scan1(const int* __restrict__ deg, int* __restrict__ partial) {
    __shared__ int sm[256];
    int i = blockIdx.x * 256 + threadIdx.x;
    sm[threadIdx.x] = (i < NN) ? deg[i] : 0;
    __syncthreads();
    for (int s = 128; s > 0; s >>= 1) {
        if (threadIdx.x < s) sm[threadIdx.x] += sm[threadIdx.x + s];
        __syncthreads();
    }
    if (threadIdx.x == 0) partial[blockIdx.x] = sm[0];
}

__global__ void k_scan2(int* __restrict__ partial, int* __restrict__ row_ptr, int nblk) {
    __shared__ int sm[256];
    int t = threadIdx.x;
    sm[t] = (t < nblk) ? partial[t] : 0;
    __syncthreads();
    for (int off = 1; off < 256; off <<= 1) {
        int v = (t >= off) ? sm[t - off] : 0;
        __syncthreads();
        sm[t] += v;
        __syncthreads();
    }
    int excl = (t == 0) ? 0 : sm[t - 1];
    if (t < nblk) partial[t] = excl;
    if (t == 0) row_ptr[0] = 0;
}

__global__ void k_scan3(const int* __restrict__ deg, const int* __restrict__ partial,
                        int* __restrict__ row_ptr) {
    __shared__ int sm[256];
    int t = threadIdx.x;
    int i = blockIdx.x * 256 + t;
    sm[t] = (i < NN) ? deg[i] : 0;
    __syncthreads();
    for (int off = 1; off < 256; off <<= 1) {
        int v = (t >= off) ? sm[t - off] : 0;
        __syncthreads();
        sm[t] += v;
        __syncthreads();
    }
    if (i < NN) row_ptr[i + 1] = partial[blockIdx.x] + sm[t];
}

__global__ void k_fill(const int* __restrict__ src, const int* __restrict__ dst,
                       const int* __restrict__ row_ptr, int* __restrict__ cursor,
                       int* __restrict__ csr_src, int* __restrict__ csr_eid) {
    int e = blockIdx.x * 256 + threadIdx.x;
    if (e >= NE) return;
    int d = dst[e];
    int pos = atomicAdd(&cursor[d], 1);
    int slot = row_ptr[d] + pos;
    csr_src[slot] = src[e];
    csr_eid[slot] = e;
}

// eattr permuted into CSR slot order, fp32 (one-time; uniform rows -> s_loads in k_agg2)
__global__ void k_eperm(const float* __restrict__ eattr, const int* __restrict__ csr_eid,
                        float* __restrict__ eattrF) {
    int idx = blockIdx.x * 256 + threadIdx.x;
    if (idx >= NE * EIN) return;
    int slot = idx >> 4, j = idx & 15;
    eattrF[idx] = eattr[(size_t)csr_eid[slot] * EIN + j];
}

__global__ void k_sumlog(const int* __restrict__ deg, float* __restrict__ sum) {
    int i = blockIdx.x * 256 + threadIdx.x;
    float v = (i < NN) ? log1pf((float)deg[i]) : 0.f;
    #pragma unroll
    for (int off = 32; off > 0; off >>= 1) v += __shfl_down(v, off, 64);
    if ((threadIdx.x & 63) == 0) atomicAdd(sum, v);
}

__global__ void k_scalers(const int* __restrict__ deg, const float* __restrict__ sumlog,
                          float* __restrict__ amp, float* __restrict__ att) {
    int i = blockIdx.x * 256 + threadIdx.x;
    if (i >= NN) return;
    float avg = sumlog[0] / (float)NN;
    float degc = fmaxf((float)deg[i], 1.0f);
    float la = logf(degc + 1.0f);
    amp[i] = la / avg;
    att[i] = avg / la;
}

// ---------------- M_l = encW_l @ preW2_l  (128x128 fp32, tiled; replaces serial k_wprep) ----
__global__ __launch_bounds__(256) void k_encfold(const float* __restrict__ encW,
                                                 const float* __restrict__ preW,
                                                 float* __restrict__ M) {
    __shared__ float As[32][68];
    __shared__ float Bs[32][128];
    int l = blockIdx.y;
    const float* A = encW + (size_t)l * H * H;
    const float* Bp = preW + (size_t)l * 3 * H * H + 2 * H * H;
    float* Ml = M + (size_t)l * H * H;
    int m0 = blockIdx.x * 64;
    int tid = threadIdx.x;
    int tx = tid & 31, ty = tid >> 5;
    float4 acc[8];
    #pragma unroll
    for (int r = 0; r < 8; r++) acc[r] = make_float4(0, 0, 0, 0);
    int f = tid & 7, r0 = tid >> 3;
    int cf = tid & 31, kr0 = tid >> 5;
    for (int k0 = 0; k0 < H; k0 += 32) {
        #pragma unroll
        for (int hh = 0; hh < 2; hh++) {
            int r = r0 + hh * 32;
            float4 v = *(const float4*)(A + (size_t)(m0 + r) * H + k0 + f * 4);
            As[f * 4 + 0][r] = v.x; As[f * 4 + 1][r] = v.y;
            As[f * 4 + 2][r] = v.z; As[f * 4 + 3][r] = v.w;
        }
        #pragma unroll
        for (int hh = 0; hh < 4; hh++) {
            int kr = kr0 + hh * 8;
            *(float4*)&Bs[kr][cf * 4] = *(const float4*)(Bp + (size_t)(k0 + kr) * H + cf * 4);
        }
        __syncthreads();
        #pragma unroll
        for (int kk = 0; kk < 32; kk++) {
            float4 b = *(float4*)&Bs[kk][tx * 4];
            float4 a0 = *(float4*)&As[kk][ty * 8];
            float4 a1 = *(float4*)&As[kk][ty * 8 + 4];
            acc[0].x = fmaf(a0.x, b.x, acc[0].x); acc[0].y = fmaf(a0.x, b.y, acc[0].y);
            acc[0].z = fmaf(a0.x, b.z, acc[0].z); acc[0].w = fmaf(a0.x, b.w, acc[0].w);
            acc[1].x = fmaf(a0.y, b.x, acc[1].x); acc[1].y = fmaf(a0.y, b.y, acc[1].y);
            acc[1].z = fmaf(a0.y, b.z, acc[1].z); acc[1].w = fmaf(a0.y, b.w, acc[1].w);
            acc[2].x = fmaf(a0.z, b.x, acc[2].x); acc[2].y = fmaf(a0.z, b.y, acc[2].y);
            acc[2].z = fmaf(a0.z, b.z, acc[2].z); acc[2].w = fmaf(a0.z, b.w, acc[2].w);
            acc[3].x = fmaf(a0.w, b.x, acc[3].x); acc[3].y = fmaf(a0.w, b.y, acc[3].y);
            acc[3].z = fmaf(a0.w, b.z, acc[3].z); acc[3].w = fmaf(a0.w, b.w, acc[3].w);
            acc[4].x = fmaf(a1.x, b.x, acc[4].x); acc[4].y = fmaf(a1.x, b.y, acc[4].y);
            acc[4].z = fmaf(a1.x, b.z, acc[4].z); acc[4].w = fmaf(a1.x, b.w, acc[4].w);
            acc[5].x = fmaf(a1.y, b.x, acc[5].x); acc[5].y = fmaf(a1.y, b.y, acc[5].y);
            acc[5].z = fmaf(a1.y, b.z, acc[5].z); acc[5].w = fmaf(a1.y, b.w, acc[5].w);
            acc[6].x = fmaf(a1.z, b.x, acc[6].x); acc[6].y = fmaf(a1.z, b.y, acc[6].y);
            acc[6].z = fmaf(a1.z, b.z, acc[6].z); acc[6].w = fmaf(a1.z, b.w, acc[6].w);
            acc[7].x = fmaf(a1.w, b.x, acc[7].x); acc[7].y = fmaf(a1.w, b.y, acc[7].y);
            acc[7].z = fmaf(a1.w, b.z, acc[7].z); acc[7].w = fmaf(a1.w, b.w, acc[7].w);
        }
        __syncthreads();
    }
    #pragma unroll
    for (int rr = 0; rr < 8; rr++) {
        int row = m0 + ty * 8 + rr;
        *(float4*)(Ml + (size_t)row * H + tx * 4) = acc[rr];
    }
}

// Kc_l = embW @ M_l  (16x128 per layer; one elem/thread, coalesced)
__global__ void k_kprep(const float* __restrict__ embW, const float* __restrict__ M,
                        float* __restrict__ Kc) {
    int l = blockIdx.y;
    int idx = blockIdx.x * 256 + threadIdx.x;   // 2048 elems
    int r = idx >> 7, j = idx & 127;
    const float* Ml = M + (size_t)l * H * H;
    float s = 0.f;
    for (int k = 0; k < H; k++) s = fmaf(embW[r * H + k], Ml[k * H + j], s);
    Kc[l * 16 * H + idx] = s;
}

// cc_l = (emb_b @ encW_l + enc_b_l) @ preW2_l + pre_b_l
__global__ void k_cprep(const float* __restrict__ emb_b, const float* __restrict__ encW,
                        const float* __restrict__ enc_b, const float* __restrict__ preW,
                        const float* __restrict__ pre_b, float* __restrict__ cc) {
    __shared__ float b1[H];
    int l = blockIdx.x, t = threadIdx.x;
    const float* encWl = encW + (size_t)l * H * H;
    const float* preW2 = preW + (size_t)l * 3 * H * H + 2 * H * H;
    float s = enc_b[l * H + t];
    for (int k = 0; k < H; k++) s = fmaf(emb_b[k], encWl[k * H + t], s);
    b1[t] = s;
    __syncthreads();
    float c = pre_b[l * H + t];
    for (int k = 0; k < H; k++) c = fmaf(b1[k], preW2[k * H + t], c);
    cc[l * H + t] = c;
}

// ---------------- weight transpose+cast: D[n][k] = bf16(S[k][n]), S has 128 cols ----------------
struct TD { const float* S; unsigned short* D; int K; };
struct TDs { TD t[9]; };

__global__ void k_prepw(TDs p) {
    TD d = p.t[blockIdx.y];
    int idx = blockIdx.x * 256 + threadIdx.x;
    int total = d.K << 7;
    if (idx < total) {
        int k = idx >> 7, n = idx & 127;
        d.D[(size_t)n * d.K + k] = f2bf(d.S[(size_t)k * 128 + n]);
    }
}

__global__ void k_cast(const float* __restrict__ S, unsigned short* __restrict__ D, int n) {
    int i = blockIdx.x * 256 + threadIdx.x;
    if (i < n) D[i] = f2bf(S[i]);
}

// ---------------- weight fold: fold_l = postW_l @ linW_l  (fp32 acc, bf16-T out) --------------
__global__ __launch_bounds__(256) void k_wfold(const float* __restrict__ postW,
                                               const float* __restrict__ linW,
                                               unsigned short* __restrict__ Wt3,
                                               unsigned short* __restrict__ foldT) {
    __shared__ float As[32][68];
    __shared__ float Bs[32][128];
    int l = blockIdx.y;
    const float* A = postW + (size_t)l * 13 * H * H;   // [1664][128]
    const float* Bp = linW + (size_t)l * H * H;        // [128][128]
    int m0 = blockIdx.x * 64;
    int tid = threadIdx.x;
    int tx = tid & 31, ty = tid >> 5;
    float4 acc[8];
    #pragma unroll
    for (int r = 0; r < 8; r++) acc[r] = make_float4(0, 0, 0, 0);
    int f = tid & 7, r0 = tid >> 3;
    int cf = tid & 31, kr0 = tid >> 5;
    for (int k0 = 0; k0 < H; k0 += 32) {
        #pragma unroll
        for (int hh = 0; hh < 2; hh++) {
            int r = r0 + hh * 32;
            float4 v = *(const float4*)(A + (size_t)(m0 + r) * H + k0 + f * 4);
            As[f * 4 + 0][r] = v.x; As[f * 4 + 1][r] = v.y;
            As[f * 4 + 2][r] = v.z; As[f * 4 + 3][r] = v.w;
        }
        #pragma unroll
        for (int hh = 0; hh < 4; hh++) {
            int kr = kr0 + hh * 8;
            *(float4*)&Bs[kr][cf * 4] = *(const float4*)(Bp + (size_t)(k0 + kr) * H + cf * 4);
        }
        __syncthreads();
        #pragma unroll
        for (int kk = 0; kk < 32; kk++) {
            float4 b = *(float4*)&Bs[kk][tx * 4];
            float4 a0 = *(float4*)&As[kk][ty * 8];
            float4 a1 = *(float4*)&As[kk][ty * 8 + 4];
            acc[0].x = fmaf(a0.x, b.x, acc[0].x); acc[0].y = fmaf(a0.x, b.y, acc[0].y);
            acc[0].z = fmaf(a0.x, b.z, acc[0].z); acc[0].w = fmaf(a0.x, b.w, acc[0].w);
            acc[1].x = fmaf(a0.y, b.x, acc[1].x); acc[1].y = fmaf(a0.y, b.y, acc[1].y);
            acc[1].z = fmaf(a0.y, b.z, acc[1].z); acc[1].w = fmaf(a0.y, b.w, acc[1].w);
            acc[2].x = fmaf(a0.z, b.x, acc[2].x); acc[2].y = fmaf(a0.z, b.y, acc[2].y);
            acc[2].z = fmaf(a0.z, b.z, acc[2].z); acc[2].w = fmaf(a0.z, b.w, acc[2].w);
            acc[3].x = fmaf(a0.w, b.x, acc[3].x); acc[3].y = fmaf(a0.w, b.y, acc[3].y);
            acc[3].z = fmaf(a0.w, b.z, acc[3].z); acc[3].w = fmaf(a0.w, b.w, acc[3].w);
            acc[4].x = fmaf(a1.x, b.x, acc[4].x); acc[4].y = fmaf(a1.x, b.y, acc[4].y);
            acc[4].z = fmaf(a1.x, b.z, acc[4].z); acc[4].w = fmaf(a1.x, b.w, acc[4].w);
            acc[5].x = fmaf(a1.y, b.x, acc[5].x); acc[5].y = fmaf(a1.y, b.y, acc[5].y);
            acc[5].z = fmaf(a1.y, b.z, acc[5].z); acc[5].w = fmaf(a1.y, b.w, acc[5].w);
            acc[6].x = fmaf(a1.z, b.x, acc[6].x); acc[6].y = fmaf(a1.z, b.y, acc[6].y);
            acc[6].z = fmaf(a1.z, b.z, acc[6].z); acc[6].w = fmaf(a1.z, b.w, acc[6].w);
            acc[7].x = fmaf(a1.w, b.x, acc[7].x); acc[7].y = fmaf(a1.w, b.y, acc[7].y);
            acc[7].z = fmaf(a1.w, b.z, acc[7].z); acc[7].w = fmaf(a1.w, b.w, acc[7].w);
        }
        __syncthreads();
    }
    unsigned short* w2 = Wt3 + (size_t)(l * 3 + 2) * H * H;
    unsigned short* ft = foldT + (size_t)l * 128 * 1664;
    int r = m0 + ty * 8;
    #pragma unroll
    for (int c = 0; c < 4; c++) {
        int n = tx * 4 + c;
        unsigned short tmp[8] __attribute__((aligned(16)));
        #pragma unroll
        for (int rr = 0; rr < 8; rr++) tmp[rr] = f2bf(((const float*)&acc[rr])[c]);
        unsigned short* dstp = (r < 128) ? (w2 + (size_t)n * 128 + r)
                                         : (ft + (size_t)n * 1664 + r);
        *(uint4*)dstp = *(const uint4*)tmp;
    }
}

// bias' = pb @ linW + lb  (per layer)
__global__ void k_bfold(const float* __restrict__ pb, const float* __restrict__ lb,
                        const float* __restrict__ linW, float* __restrict__ cf) {
    int l = blockIdx.x, n = threadIdx.x;
    const float* B = linW + (size_t)l * H * H;
    float s = lb[l * H + n];
    for (int j = 0; j < H; j++) s = fmaf(pb[l * H + j], B[j * H + n], s);
    cf[l * H + n] = s;
}

// ---------------- bf16 MFMA GEMM (swapped-operand D^T epilogue, LDS-staged C) ----------------
__global__ __launch_bounds__(256, 4) void k_mgemm(
    const unsigned short* __restrict__ A, int lda, int K, int nch,
    const unsigned short* __restrict__ Bt, int ldb, int bstride_y,
    const float* __restrict__ bias, unsigned short* __restrict__ outB)
{
    __shared__ unsigned short SH[2][128][72];   // staging; reused as 128x136 C-tile
    const unsigned short* Btp = Bt + (size_t)blockIdx.x * bstride_y;
    int m0 = blockIdx.y * 128;
    int tid = threadIdx.x;
    int wave = tid >> 6, lane = tid & 63;
    int wr = wave >> 1, wc = wave & 1;
    int ln = lane & 15, q = lane >> 4;

    f32x4 acc[4][4];
    #pragma unroll
    for (int a = 0; a < 4; a++)
        #pragma unroll
        for (int b = 0; b < 4; b++) acc[a][b] = (f32x4){0.f, 0.f, 0.f, 0.f};

    for (int c = 0; c < nch; c++) {
        int col = c * 64;
        #pragma unroll
        for (int i0 = 0; i0 < 4; i0++) {
            int i = tid + i0 * 256;
            int row = i >> 3, seg = i & 7;
            uint4 bv = *(const uint4*)(Btp + (size_t)row * ldb + col + seg * 8);
            *(uint4*)(&SH[1][row][seg * 8]) = bv;
            int rowg = m0 + row;
            uint4 av = make_uint4(0, 0, 0, 0);
            if (rowg < NN) av = *(const uint4*)(A + (size_t)rowg * lda + col + seg * 8);
            *(uint4*)(&SH[0][row][seg * 8]) = av;
        }
        __syncthreads();
        #pragma unroll
        for (int kq = 0; kq < 2; kq++) {
            bf16x8 af[4], bfr[4];
            #pragma unroll
            for (int f = 0; f < 4; f++) {
                af[f]  = *(const bf16x8*)(&SH[0][wr * 64 + f * 16 + ln][kq * 32 + q * 8]);
                bfr[f] = *(const bf16x8*)(&SH[1][wc * 64 + f * 16 + ln][kq * 32 + q * 8]);
            }
            #pragma unroll
            for (int fr = 0; fr < 4; fr++)
                #pragma unroll
                for (int fc = 0; fc < 4; fc++)
                    acc[fr][fc] = __builtin_amdgcn_mfma_f32_16x16x32_bf16(
                        bfr[fc], af[fr], acc[fr][fc], 0, 0, 0);   // swapped: D^T
        }
        __syncthreads();
    }

    unsigned short* CT = &SH[0][0][0];   // 128 x (stride 136)
    #pragma unroll
    for (int fr = 0; fr < 4; fr++) {
        int rloc = wr * 64 + fr * 16 + ln;
        #pragma unroll
        for (int fc = 0; fc < 4; fc++) {
            int colb = wc * 64 + fc * 16 + q * 4;
            float4 bv = bias ? *(const float4*)(bias + colb) : make_float4(0, 0, 0, 0);
            unsigned short tmp[4] __attribute__((aligned(8)));
            tmp[0] = f2bf(acc[fr][fc][0] + bv.x);
            tmp[1] = f2bf(acc[fr][fc][1] + bv.y);
            tmp[2] = f2bf(acc[fr][fc][2] + bv.z);
            tmp[3] = f2bf(acc[fr][fc][3] + bv.w);
            *(uint2*)(&CT[rloc * 136 + colb]) = *(const uint2*)tmp;
        }
    }
    __syncthreads();
    unsigned short* outBp = outB + (size_t)blockIdx.x * NN * H;
    #pragma unroll
    for (int i0 = 0; i0 < 8; i0++) {
        int idx = tid + i0 * 256;
        int row = idx >> 4, seg = idx & 15;
        int rowg = m0 + row;
        if (rowg < NN)
            *(uint4*)(outBp + (size_t)rowg * H + seg * 8) = *(const uint4*)(&CT[row * 136 + seg * 8]);
    }
}

// ---------------- fused aggregation: one wave per node ----------------
__global__ __launch_bounds__(256) void k_agg2(
    const unsigned short* __restrict__ pd, const unsigned short* __restrict__ ps,
    const float* __restrict__ eF,         // [E][16] fp32, slot-ordered
    const int* __restrict__ csr_src, const int* __restrict__ row_ptr,
    const float* __restrict__ Kl, const float* __restrict__ cl,
    unsigned short* __restrict__ agg)
{
    int wv = threadIdx.x >> 6, lane = threadIdx.x & 63;
    int i = blockIdx.x * 4 + wv;
    int d0 = lane * 2;
    float2 kr[16];
    #pragma unroll
    for (int k = 0; k < 16; k++) kr[k] = *(const float2*)(Kl + k * H + d0);
    float2 c2 = *(const float2*)(cl + d0);
    unsigned hd = *(const unsigned*)(pd + (size_t)i * H + d0);
    float bx = c2.x + bflo(hd);
    float by = c2.y + bfhi(hd);
    int rs = __builtin_amdgcn_readfirstlane(row_ptr[i]);
    int re = __builtin_amdgcn_readfirstlane(row_ptr[i + 1]);
    float sx = 0.f, sy = 0.f, qx = 0.f, qy = 0.f;
    float mnx = 3.0e38f, mny = 3.0e38f, mxx = -3.0e38f, mxy = -3.0e38f;

    int n0 = (rs < re)     ? __builtin_amdgcn_readfirstlane(csr_src[rs])     : 0;
    int n1 = (rs + 1 < re) ? __builtin_amdgcn_readfirstlane(csr_src[rs + 1]) : 0;
    unsigned hsA = *(const unsigned*)(ps + (size_t)n0 * H + d0);
    unsigned hsB = *(const unsigned*)(ps + (size_t)n1 * H + d0);

    int slot = rs;
    for (; slot + 1 < re; slot += 2) {
        int p0 = (slot + 2 < re) ? __builtin_amdgcn_readfirstlane(csr_src[slot + 2]) : 0;
        int p1 = (slot + 3 < re) ? __builtin_amdgcn_readfirstlane(csr_src[slot + 3]) : 0;
        unsigned hsC = *(const unsigned*)(ps + (size_t)p0 * H + d0);
        unsigned hsD = *(const unsigned*)(ps + (size_t)p1 * H + d0);
        const float* ea = eF + (size_t)slot * EIN;   // uniform -> s_load
        const float* eb = ea + EIN;
        float ax = bx + bflo(hsA), ay = by + bfhi(hsA);
        float cx = bx + bflo(hsB), cy = by + bfhi(hsB);
        #pragma unroll
        for (int j = 0; j < 16; j++) {
            float e1 = ea[j], e2 = eb[j];
            ax = fmaf(e1, kr[j].x, ax); ay = fmaf(e1, kr[j].y, ay);
            cx = fmaf(e2, kr[j].x, cx); cy = fmaf(e2, kr[j].y, cy);
        }
        sx += ax + cx; sy += ay + cy;
        qx = fmaf(ax, ax, fmaf(cx, cx, qx));
        qy = fmaf(ay, ay, fmaf(cy, cy, qy));
        mnx = fminf(mnx, fminf(ax, cx)); mny = fminf(mny, fminf(ay, cy));
        mxx = fmaxf(mxx, fmaxf(ax, cx)); mxy = fmaxf(mxy, fmaxf(ay, cy));
        hsA = hsC; hsB = hsD;
    }
    if (slot < re) {   // odd tail
        const float* ea = eF + (size_t)slot * EIN;
        float ax = bx + bflo(hsA), ay = by + bfhi(hsA);
        #pragma unroll
        for (int j = 0; j < 16; j++) {
            float e1 = ea[j];
            ax = fmaf(e1, kr[j].x, ax); ay = fmaf(e1, kr[j].y, ay);
        }
        sx += ax; sy += ay;
        qx = fmaf(ax, ax, qx); qy = fmaf(ay, ay, qy);
        mnx = fminf(mnx, ax); mny = fminf(mny, ay);
        mxx = fmaxf(mxx, ax); mxy = fmaxf(mxy, ay);
    }

    int dg = re - rs;
    float dinv = 1.0f / fmaxf((float)dg, 1.0f);
    float mex = sx * dinv, mey = sy * dinv;
    float sdx = sqrtf(fmaxf(qx * dinv - mex * mex, 0.f) + EPSV);
    float sdy = sqrtf(fmaxf(qy * dinv - mey * mey, 0.f) + EPSV);
    if (dg == 0) { mnx = 0.f; mny = 0.f; mxx = 0.f; mxy = 0.f; }
    unsigned short* ap = agg + (size_t)i * 512 + d0;
    *(unsigned*)(ap)       = (unsigned)f2bf(mex) | ((unsigned)f2bf(mey) << 16);
    *(unsigned*)(ap + 128) = (unsigned)f2bf(mnx) | ((unsigned)f2bf(mny) << 16);
    *(unsigned*)(ap + 256) = (unsigned)f2bf(mxx) | ((unsigned)f2bf(mxy) << 16);
    *(unsigned*)(ap + 384) = (unsigned)f2bf(sdx) | ((unsigned)f2bf(sdy) << 16);
}

// ---------------- combine: h = relu(hA' + p0 + amp*p1 + att*p2 + bias') ----------------
__global__ __launch_bounds__(256) void k_comb(const unsigned* __restrict__ ha,
                                              const unsigned* __restrict__ part,
                                              const float* __restrict__ amp,
                                              const float* __restrict__ att,
                                              const float* __restrict__ biasf,
                                              unsigned* __restrict__ hbo,
                                              float* __restrict__ hfo) {
    int dv = blockIdx.x * 256 + threadIdx.x;
    int i = dv >> 6;
    int cp = dv & 63;
    float a = amp[i], t = att[i];
    unsigned uh = ha[dv];
    unsigned p0 = part[dv];
    unsigned p1 = part[dv + NP64];
    unsigned p2 = part[dv + 2 * NP64];
    float lo = bflo(uh) + bflo(p0) + a * bflo(p1) + t * bflo(p2) + biasf[cp * 2];
    float hi = bfhi(uh) + bfhi(p0) + a * bfhi(p1) + t * bfhi(p2) + biasf[cp * 2 + 1];
    lo = fmaxf(lo, 0.f); hi = fmaxf(hi, 0.f);
    hbo[dv] = (unsigned)f2bf(lo) | ((unsigned)f2bf(hi) << 16);
    if (hfo) { hfo[dv * 2] = lo; hfo[dv * 2 + 1] = hi; }
}

// ---------------- pooling + head ----------------
__device__ __forceinline__ int lbound(const int* a, int n, int v) {
    int lo = 0, hi = n;
    while (lo < hi) { int m = (lo + hi) >> 1; if (a[m] < v) lo = m + 1; else hi = m; }
    return lo;
}

__global__ __launch_bounds__(256) void k_pool(const float* __restrict__ h,
                                              const int* __restrict__ batch,
                                              const float* __restrict__ headW,
                                              const float* __restrict__ headb,
                                              float* __restrict__ out) {
    __shared__ float sm[256];
    int g = blockIdx.x;
    int t = threadIdx.x;
    int col = t & 127;
    int half = t >> 7;
    int lo = lbound(batch, NN, g);
    int hi = lbound(batch, NN, g + 1);
    int mid = lo + ((hi - lo) >> 1);
    int b0 = half ? mid : lo;
    int b1 = half ? hi : mid;
    float acc = 0.f;
    for (int i = b0; i < b1; i++) acc += h[(size_t)i * H + col];
    sm[t] = acc;
    __syncthreads();
    if (t < 128) sm[t] += sm[t + 128];
    __syncthreads();
    if (t < NOUT) {
        float r = headb[t];
        for (int j = 0; j < H; j++) r = fmaf(sm[j], headW[j * NOUT + t], r);
        out[g * NOUT + t] = r;
    }
}

// ---------------- launch ----------------
extern "C" void kernel_launch(void* const* d_in, const int* in_sizes, int n_in,
                              void* d_out, int out_size, void* d_ws, size_t ws_size,
                              hipStream_t stream) {
    const float* x          = (const float*)d_in[0];
    const float* edge_attr  = (const float*)d_in[1];
    const int*   src        = (const int*)d_in[2];
    const int*   dst        = (const int*)d_in[3];
    const int*   batch      = (const int*)d_in[4];
    const float* node_emb_W = (const float*)d_in[5];
    const float* node_emb_b = (const float*)d_in[6];
    const float* edge_emb_W = (const float*)d_in[7];
    const float* edge_emb_b = (const float*)d_in[8];
    const float* edge_enc_W = (const float*)d_in[9];
    const float* edge_enc_b = (const float*)d_in[10];
    const float* pre_W      = (const float*)d_in[11];
    const float* pre_b      = (const float*)d_in[12];
    const float* post_W     = (const float*)d_in[13];
    const float* post_b     = (const float*)d_in[14];
    const float* lin_W      = (const float*)d_in[15];
    const float* lin_b      = (const float*)d_in[16];
    const float* head_W     = (const float*)d_in[17];
    const float* head_b     = (const float*)d_in[18];
    float* out = (float*)d_out;

    char* wp = (char*)d_ws;
    auto carve = [&](size_t bytes) -> char* {
        char* r = wp;
        wp += (bytes + 255) & ~(size_t)255;
        return r;
    };
    int*   deg     = (int*)carve((size_t)NN * 4);      // |
    int*   cursor  = (int*)carve((size_t)NN * 4);      // | zeroed in ONE memset
    float* sumlog  = (float*)carve(4);                 // |
    int*   partial = (int*)carve(256 * 4);
    int*   row_ptr = (int*)carve((size_t)(NN + 1) * 4);
    int*   csr_src = (int*)carve((size_t)NE * 4);
    int*   csr_eid = (int*)carve((size_t)NE * 4);
    float* amp     = (float*)carve((size_t)NN * 4);
    float* att     = (float*)carve((size_t)NN * 4);
    float* Kc      = (float*)carve((size_t)NL * 16 * H * 4);
    float* cc      = (float*)carve((size_t)NL * H * 4);
    float* cfold   = (float*)carve((size_t)NL * H * 4);
    float* Mf      = (float*)carve((size_t)NL * H * H * 4);
    float* eattrF  = (float*)carve((size_t)NE * EIN * 4);
    unsigned short* embWt  = (unsigned short*)carve((size_t)H * FIN * 2);
    unsigned short* Wt3    = (unsigned short*)carve((size_t)NL * 3 * H * H * 2);
    unsigned short* foldT  = (unsigned short*)carve((size_t)NL * 128 * 1664 * 2);
    unsigned short* xb     = (unsigned short*)carve((size_t)NN * FIN * 2);
    unsigned short* hb     = (unsigned short*)carve((size_t)NN * H * 2);
    unsigned short* planesB= (unsigned short*)carve((size_t)3 * NN * H * 2);
    unsigned short* aggb   = (unsigned short*)carve((size_t)NN * 4 * H * 2);
    unsigned short* partsB = (unsigned short*)carve((size_t)3 * NN * H * 2);
    float* hf      = (float*)carve((size_t)NN * H * 4);

    const size_t NP = (size_t)NN * H;

    // deg, cursor, sumlog are contiguous carves (256-aligned): one memset
    hipMemsetAsync(deg, 0, ((size_t)NN * 4 + 255 & ~(size_t)255) * 2 + 256, stream);

    k_hist<<<(NE + 255) / 256, 256, 0, stream>>>(dst, deg);
    k_scan1<<<NBLK, 256, 0, stream>>>(deg, partial);
    k_scan2<<<1, 256, 0, stream>>>(partial, row_ptr, NBLK);
    k_scan3<<<NBLK, 256, 0, stream>>>(deg, partial, row_ptr);
    k_fill<<<(NE + 255) / 256, 256, 0, stream>>>(src, dst, row_ptr, cursor, csr_src, csr_eid);
    k_eperm<<<(NE * EIN + 255) / 256, 256, 0, stream>>>(edge_attr, csr_eid, eattrF);
    k_sumlog<<<NBLK, 256, 0, stream>>>(deg, sumlog);
    k_scalers<<<NBLK, 256, 0, stream>>>(deg, sumlog, amp, att);
    k_encfold<<<dim3(2, NL), 256, 0, stream>>>(edge_enc_W, pre_W, Mf);
    k_kprep<<<dim3(8, NL), 256, 0, stream>>>(edge_emb_W, Mf, Kc);
    k_cprep<<<NL, H, 0, stream>>>(edge_emb_b, edge_enc_W, edge_enc_b, pre_W, pre_b, cc);
    k_wfold<<<dim3(26, NL), 256, 0, stream>>>(post_W, lin_W, Wt3, foldT);
    k_bfold<<<NL, H, 0, stream>>>(post_b, lin_b, lin_W, cfold);

    TDs tds;
    int nd = 0;
    tds.t[nd++] = TD{node_emb_W, embWt, FIN};
    for (int l = 0; l < NL; l++) {
        tds.t[nd++] = TD{pre_W + (size_t)l * 3 * H * H,         Wt3 + (size_t)(l * 3 + 0) * H * H, H};
        tds.t[nd++] = TD{pre_W + (size_t)l * 3 * H * H + H * H, Wt3 + (size_t)(l * 3 + 1) * H * H, H};
    }
    k_prepw<<<dim3(64, 9), 256, 0, stream>>>(tds);
    k_cast<<<(NN * FIN + 255) / 256, 256, 0, stream>>>(x, xb, NN * FIN);

    // h = x @ node_emb_W + b  (bf16 out)
    k_mgemm<<<dim3(1, GB2), 256, 0, stream>>>(xb, FIN, FIN, 1, embWt, FIN, 0,
                                              node_emb_b, hb);

    for (int l = 0; l < NL; l++) {
        int last = (l == NL - 1);
        // planesB bf16: [hW_dst | hW_src | hA'(=h@Wh@linW)]
        k_mgemm<<<dim3(3, GB2), 256, 0, stream>>>(hb, H, H, 2,
                                                  Wt3 + (size_t)l * 3 * H * H, H, H * H,
                                                  nullptr, planesB);
        // fused aggregation
        k_agg2<<<NN / 4, 256, 0, stream>>>(planesB, planesB + NP,
                                           eattrF, csr_src, row_ptr,
                                           Kc + (size_t)l * 16 * H, cc + (size_t)l * H,
                                           aggb);
        // partials: p_g = agg @ (B_g@linW), g=0..2  (split-K by scale group)
        k_mgemm<<<dim3(3, GB2), 256, 0, stream>>>(aggb, 4 * H, 4 * H, 8,
                                                  foldT + (size_t)l * 128 * 1664 + 128,
                                                  1664, 512,
                                                  nullptr, partsB);
        // combine: h = relu(hA' + p0 + amp*p1 + att*p2 + bias')
        k_comb<<<NP64 / 256, 256, 0, stream>>>((const unsigned*)(planesB + 2 * NP),
                                               (const unsigned*)partsB, amp, att,
                                               cfold + (size_t)l * H,
                                               (unsigned*)hb, last ? hf : nullptr);
    }

    k_pool<<<NG, 256, 0, stream>>>(hf, batch, head_W, head_b, out);
}

// Round 10
// 778.488 us; speedup vs baseline: 3.1014x; 1.0093x over previous
//
#include <hip/hip_runtime.h>

#define NN 50000
#define NE 400000
#define FIN 64
#define EIN 16
#define H 128
#define NL 4
#define NG 256
#define NOUT 12
#define EPSV 1e-5f

#define SB 256
#define NBLK ((NN + SB - 1) / SB)    // 196
#define GB2 ((NN + 127) / 128)       // 391 (128-row MFMA tiles)
#define NP64 (NN * 64)               // dwords per [NN,H] bf16 plane

typedef short bf16x8 __attribute__((ext_vector_type(8)));
typedef float f32x4 __attribute__((ext_vector_type(4)));
typedef float v2f __attribute__((ext_vector_type(2)));

__device__ __forceinline__ unsigned short f2bf(float f) {
    unsigned u = __float_as_uint(f);
    u += 0x7fffu + ((u >> 16) & 1u);
    return (unsigned short)(u >> 16);
}

__device__ __forceinline__ float bflo(unsigned u) { return __uint_as_float(u << 16); }
__device__ __forceinline__ float bfhi(unsigned u) { return __uint_as_float(u & 0xffff0000u); }

// ---------------- setup kernels ----------------
__global__ void k_hist(const int* __restrict__ dst, int* __restrict__ deg) {
    int e = blockIdx.x * 256 + threadIdx.x;
    if (e < NE) atomicAdd(&deg[dst[e]], 1);
}

__global__ void k_scan1(const int* __restrict__ deg, int* __restrict__ partial) {
    __shared__ int sm[256];
    int i = blockIdx.x * 256 + threadIdx.x;
    sm[threadIdx.x] = (i < NN) ? deg[i] : 0;
    __syncthreads();
    for (int s = 128; s > 0; s >>= 1) {
        if (threadIdx.x < s) sm[threadIdx.x] += sm[threadIdx.x + s];
        __syncthreads();
    }
    if (threadIdx.x == 0) partial[blockIdx.x] = sm[0];
}

__global__ void k_scan2(int* __restrict__ partial, int* __restrict__ row_ptr, int nblk) {
    __shared__ int sm[256];
    int t = threadIdx.x;
    sm[t] = (t < nblk) ? partial[t] : 0;
    __syncthreads();
    for (int off = 1; off < 256; off <<= 1) {
        int v = (t >= off) ? sm[t - off] : 0;
        __syncthreads();
        sm[t] += v;
        __syncthreads();
    }
    int excl = (t == 0) ? 0 : sm[t - 1];
    if (t < nblk) partial[t] = excl;
    if (t == 0) row_ptr[0] = 0;
}

__global__ void k_scan3(const int* __restrict__ deg, const int* __restrict__ partial,
                        int* __restrict__ row_ptr) {
    __shared__ int sm[256];
    int t = threadIdx.x;
    int i = blockIdx.x * 256 + t;
    sm[t] = (i < NN) ? deg[i] : 0;
    __syncthreads();
    for (int off = 1; off < 256; off <<= 1) {
        int v = (t >= off) ? sm[t - off] : 0;
        __syncthreads();
        sm[t] += v;
        __syncthreads();
    }
    if (i < NN) row_ptr[i + 1] = partial[blockIdx.x] + sm[t];
}

__global__ void k_fill(const int* __restrict__ src, const int* __restrict__ dst,
                       const int* __restrict__ row_ptr, int* __restrict__ cursor,
                       int* __restrict__ csr_src, int* __restrict__ csr_eid) {
    int e = blockIdx.x * 256 + threadIdx.x;
    if (e >= NE) return;
    int d = dst[e];
    int pos = atomicAdd(&cursor[d], 1);
    int slot = row_ptr[d] + pos;
    csr_src[slot] = src[e];
    csr_eid[slot] = e;
}

// eattr permuted into CSR slot order, fp32 (one-time; uniform rows -> s_loads in k_agg2)
__global__ void k_eperm(const float* __restrict__ eattr, const int* __restrict__ csr_eid,
                        float* __restrict__ eattrF) {
    int idx = blockIdx.x * 256 + threadIdx.x;
    if (idx >= NE * EIN) return;
    int slot = idx >> 4, j = idx & 15;
    eattrF[idx] = eattr[(size_t)csr_eid[slot] * EIN + j];
}

__global__ void k_sumlog(const int* __restrict__ deg, float* __restrict__ sum) {
    int i = blockIdx.x * 256 + threadIdx.x;
    float v = (i < NN) ? log1pf((float)deg[i]) : 0.f;
    #pragma unroll
    for (int off = 32; off > 0; off >>= 1) v += __shfl_down(v, off, 64);
    if ((threadIdx.x & 63) == 0) atomicAdd(sum, v);
}

__global__ void k_scalers(const int* __restrict__ deg, const float* __restrict__ sumlog,
                          float* __restrict__ amp, float* __restrict__ att) {
    int i = blockIdx.x * 256 + threadIdx.x;
    if (i >= NN) return;
    float avg = sumlog[0] / (float)NN;
    float degc = fmaxf((float)deg[i], 1.0f);
    float la = logf(degc + 1.0f);
    amp[i] = la / avg;
    att[i] = avg / la;
}

// ---------------- M_l = encW_l @ preW2_l  (128x128 fp32, tiled) ----------------
__global__ __launch_bounds__(256) void k_encfold(const float* __restrict__ encW,
                                                 const float* __restrict__ preW,
                                                 float* __restrict__ M) {
    __shared__ float As[32][68];
    __shared__ float Bs[32][128];
    int l = blockIdx.y;
    const float* A = encW + (size_t)l * H * H;
    const float* Bp = preW + (size_t)l * 3 * H * H + 2 * H * H;
    float* Ml = M + (size_t)l * H * H;
    int m0 = blockIdx.x * 64;
    int tid = threadIdx.x;
    int tx = tid & 31, ty = tid >> 5;
    float4 acc[8];
    #pragma unroll
    for (int r = 0; r < 8; r++) acc[r] = make_float4(0, 0, 0, 0);
    int f = tid & 7, r0 = tid >> 3;
    int cf = tid & 31, kr0 = tid >> 5;
    for (int k0 = 0; k0 < H; k0 += 32) {
        #pragma unroll
        for (int hh = 0; hh < 2; hh++) {
            int r = r0 + hh * 32;
            float4 v = *(const float4*)(A + (size_t)(m0 + r) * H + k0 + f * 4);
            As[f * 4 + 0][r] = v.x; As[f * 4 + 1][r] = v.y;
            As[f * 4 + 2][r] = v.z; As[f * 4 + 3][r] = v.w;
        }
        #pragma unroll
        for (int hh = 0; hh < 4; hh++) {
            int kr = kr0 + hh * 8;
            *(float4*)&Bs[kr][cf * 4] = *(const float4*)(Bp + (size_t)(k0 + kr) * H + cf * 4);
        }
        __syncthreads();
        #pragma unroll
        for (int kk = 0; kk < 32; kk++) {
            float4 b = *(float4*)&Bs[kk][tx * 4];
            float4 a0 = *(float4*)&As[kk][ty * 8];
            float4 a1 = *(float4*)&As[kk][ty * 8 + 4];
            acc[0].x = fmaf(a0.x, b.x, acc[0].x); acc[0].y = fmaf(a0.x, b.y, acc[0].y);
            acc[0].z = fmaf(a0.x, b.z, acc[0].z); acc[0].w = fmaf(a0.x, b.w, acc[0].w);
            acc[1].x = fmaf(a0.y, b.x, acc[1].x); acc[1].y = fmaf(a0.y, b.y, acc[1].y);
            acc[1].z = fmaf(a0.y, b.z, acc[1].z); acc[1].w = fmaf(a0.y, b.w, acc[1].w);
            acc[2].x = fmaf(a0.z, b.x, acc[2].x); acc[2].y = fmaf(a0.z, b.y, acc[2].y);
            acc[2].z = fmaf(a0.z, b.z, acc[2].z); acc[2].w = fmaf(a0.z, b.w, acc[2].w);
            acc[3].x = fmaf(a0.w, b.x, acc[3].x); acc[3].y = fmaf(a0.w, b.y, acc[3].y);
            acc[3].z = fmaf(a0.w, b.z, acc[3].z); acc[3].w = fmaf(a0.w, b.w, acc[3].w);
            acc[4].x = fmaf(a1.x, b.x, acc[4].x); acc[4].y = fmaf(a1.x, b.y, acc[4].y);
            acc[4].z = fmaf(a1.x, b.z, acc[4].z); acc[4].w = fmaf(a1.x, b.w, acc[4].w);
            acc[5].x = fmaf(a1.y, b.x, acc[5].x); acc[5].y = fmaf(a1.y, b.y, acc[5].y);
            acc[5].z = fmaf(a1.y, b.z, acc[5].z); acc[5].w = fmaf(a1.y, b.w, acc[5].w);
            acc[6].x = fmaf(a1.z, b.x, acc[6].x); acc[6].y = fmaf(a1.z, b.y, acc[6].y);
            acc[6].z = fmaf(a1.z, b.z, acc[6].z); acc[6].w = fmaf(a1.z, b.w, acc[6].w);
            acc[7].x = fmaf(a1.w, b.x, acc[7].x); acc[7].y = fmaf(a1.w, b.y, acc[7].y);
            acc[7].z = fmaf(a1.w, b.z, acc[7].z); acc[7].w = fmaf(a1.w, b.w, acc[7].w);
        }
        __syncthreads();
    }
    #pragma unroll
    for (int rr = 0; rr < 8; rr++) {
        int row = m0 + ty * 8 + rr;
        *(float4*)(Ml + (size_t)row * H + tx * 4) = acc[rr];
    }
}

// Kc_l = embW @ M_l  (16x128 per layer)
__global__ void k_kprep(const float* __restrict__ embW, const float* __restrict__ M,
                        float* __restrict__ Kc) {
    int l = blockIdx.y;
    int idx = blockIdx.x * 256 + threadIdx.x;   // 2048 elems
    int r = idx >> 7, j = idx & 127;
    const float* Ml = M + (size_t)l * H * H;
    float s = 0.f;
    for (int k = 0; k < H; k++) s = fmaf(embW[r * H + k], Ml[k * H + j], s);
    Kc[l * 16 * H + idx] = s;
}

// cc_l = (emb_b @ encW_l + enc_b_l) @ preW2_l + pre_b_l
__global__ void k_cprep(const float* __restrict__ emb_b, const float* __restrict__ encW,
                        const float* __restrict__ enc_b, const float* __restrict__ preW,
                        const float* __restrict__ pre_b, float* __restrict__ cc) {
    __shared__ float b1[H];
    int l = blockIdx.x, t = threadIdx.x;
    const float* encWl = encW + (size_t)l * H * H;
    const float* preW2 = preW + (size_t)l * 3 * H * H + 2 * H * H;
    float s = enc_b[l * H + t];
    for (int k = 0; k < H; k++) s = fmaf(emb_b[k], encWl[k * H + t], s);
    b1[t] = s;
    __syncthreads();
    float c = pre_b[l * H + t];
    for (int k = 0; k < H; k++) c = fmaf(b1[k], preW2[k * H + t], c);
    cc[l * H + t] = c;
}

// ---------------- weight transpose+cast: D[n][k] = bf16(S[k][n]), S has 128 cols ----------------
struct TD { const float* S; unsigned short* D; int K; };
struct TDs { TD t[9]; };

__global__ void k_prepw(TDs p) {
    TD d = p.t[blockIdx.y];
    int idx = blockIdx.x * 256 + threadIdx.x;
    int total = d.K << 7;
    if (idx < total) {
        int k = idx >> 7, n = idx & 127;
        d.D[(size_t)n * d.K + k] = f2bf(d.S[(size_t)k * 128 + n]);
    }
}

__global__ void k_cast(const float* __restrict__ S, unsigned short* __restrict__ D, int n) {
    int i = blockIdx.x * 256 + threadIdx.x;
    if (i < n) D[i] = f2bf(S[i]);
}

// ---------------- weight fold: fold_l = postW_l @ linW_l  (fp32 acc, bf16-T out) --------------
__global__ __launch_bounds__(256) void k_wfold(const float* __restrict__ postW,
                                               const float* __restrict__ linW,
                                               unsigned short* __restrict__ Wt3,
                                               unsigned short* __restrict__ foldT) {
    __shared__ float As[32][68];
    __shared__ float Bs[32][128];
    int l = blockIdx.y;
    const float* A = postW + (size_t)l * 13 * H * H;   // [1664][128]
    const float* Bp = linW + (size_t)l * H * H;        // [128][128]
    int m0 = blockIdx.x * 64;
    int tid = threadIdx.x;
    int tx = tid & 31, ty = tid >> 5;
    float4 acc[8];
    #pragma unroll
    for (int r = 0; r < 8; r++) acc[r] = make_float4(0, 0, 0, 0);
    int f = tid & 7, r0 = tid >> 3;
    int cf = tid & 31, kr0 = tid >> 5;
    for (int k0 = 0; k0 < H; k0 += 32) {
        #pragma unroll
        for (int hh = 0; hh < 2; hh++) {
            int r = r0 + hh * 32;
            float4 v = *(const float4*)(A + (size_t)(m0 + r) * H + k0 + f * 4);
            As[f * 4 + 0][r] = v.x; As[f * 4 + 1][r] = v.y;
            As[f * 4 + 2][r] = v.z; As[f * 4 + 3][r] = v.w;
        }
        #pragma unroll
        for (int hh = 0; hh < 4; hh++) {
            int kr = kr0 + hh * 8;
            *(float4*)&Bs[kr][cf * 4] = *(const float4*)(Bp + (size_t)(k0 + kr) * H + cf * 4);
        }
        __syncthreads();
        #pragma unroll
        for (int kk = 0; kk < 32; kk++) {
            float4 b = *(float4*)&Bs[kk][tx * 4];
            float4 a0 = *(float4*)&As[kk][ty * 8];
            float4 a1 = *(float4*)&As[kk][ty * 8 + 4];
            acc[0].x = fmaf(a0.x, b.x, acc[0].x); acc[0].y = fmaf(a0.x, b.y, acc[0].y);
            acc[0].z = fmaf(a0.x, b.z, acc[0].z); acc[0].w = fmaf(a0.x, b.w, acc[0].w);
            acc[1].x = fmaf(a0.y, b.x, acc[1].x); acc[1].y = fmaf(a0.y, b.y, acc[1].y);
            acc[1].z = fmaf(a0.y, b.z, acc[1].z); acc[1].w = fmaf(a0.y, b.w, acc[1].w);
            acc[2].x = fmaf(a0.z, b.x, acc[2].x); acc[2].y = fmaf(a0.z, b.y, acc[2].y);
            acc[2].z = fmaf(a0.z, b.z, acc[2].z); acc[2].w = fmaf(a0.z, b.w, acc[2].w);
            acc[3].x = fmaf(a0.w, b.x, acc[3].x); acc[3].y = fmaf(a0.w, b.y, acc[3].y);
            acc[3].z = fmaf(a0.w, b.z, acc[3].z); acc[3].w = fmaf(a0.w, b.w, acc[3].w);
            acc[4].x = fmaf(a1.x, b.x, acc[4].x); acc[4].y = fmaf(a1.x, b.y, acc[4].y);
            acc[4].z = fmaf(a1.x, b.z, acc[4].z); acc[4].w = fmaf(a1.x, b.w, acc[4].w);
            acc[5].x = fmaf(a1.y, b.x, acc[5].x); acc[5].y = fmaf(a1.y, b.y, acc[5].y);
            acc[5].z = fmaf(a1.y, b.z, acc[5].z); acc[5].w = fmaf(a1.y, b.w, acc[5].w);
            acc[6].x = fmaf(a1.z, b.x, acc[6].x); acc[6].y = fmaf(a1.z, b.y, acc[6].y);
            acc[6].z = fmaf(a1.z, b.z, acc[6].z); acc[6].w = fmaf(a1.z, b.w, acc[6].w);
            acc[7].x = fmaf(a1.w, b.x, acc[7].x); acc[7].y = fmaf(a1.w, b.y, acc[7].y);
            acc[7].z = fmaf(a1.w, b.z, acc[7].z); acc[7].w = fmaf(a1.w, b.w, acc[7].w);
        }
        __syncthreads();
    }
    unsigned short* w2 = Wt3 + (size_t)(l * 3 + 2) * H * H;
    unsigned short* ft = foldT + (size_t)l * 128 * 1664;
    int r = m0 + ty * 8;
    #pragma unroll
    for (int c = 0; c < 4; c++) {
        int n = tx * 4 + c;
        unsigned short tmp[8] __attribute__((aligned(16)));
        #pragma unroll
        for (int rr = 0; rr < 8; rr++) tmp[rr] = f2bf(((const float*)&acc[rr])[c]);
        unsigned short* dstp = (r < 128) ? (w2 + (size_t)n * 128 + r)
                                         : (ft + (size_t)n * 1664 + r);
        *(uint4*)dstp = *(const uint4*)tmp;
    }
}

// bias' = pb @ linW + lb  (per layer)
__global__ void k_bfold(const float* __restrict__ pb, const float* __restrict__ lb,
                        const float* __restrict__ linW, float* __restrict__ cf) {
    int l = blockIdx.x, n = threadIdx.x;
    const float* B = linW + (size_t)l * H * H;
    float s = lb[l * H + n];
    for (int j = 0; j < H; j++) s = fmaf(pb[l * H + j], B[j * H + n], s);
    cf[l * H + n] = s;
}

// ---------------- bf16 MFMA GEMM (swapped-operand D^T epilogue, LDS-staged C) ----------------
__global__ __launch_bounds__(256, 4) void k_mgemm(
    const unsigned short* __restrict__ A, int lda, int K, int nch,
    const unsigned short* __restrict__ Bt, int ldb, int bstride_y,
    const float* __restrict__ bias, unsigned short* __restrict__ outB)
{
    __shared__ unsigned short SH[2][128][72];   // staging; reused as 128x136 C-tile
    const unsigned short* Btp = Bt + (size_t)blockIdx.x * bstride_y;
    int m0 = blockIdx.y * 128;
    int tid = threadIdx.x;
    int wave = tid >> 6, lane = tid & 63;
    int wr = wave >> 1, wc = wave & 1;
    int ln = lane & 15, q = lane >> 4;

    f32x4 acc[4][4];
    #pragma unroll
    for (int a = 0; a < 4; a++)
        #pragma unroll
        for (int b = 0; b < 4; b++) acc[a][b] = (f32x4){0.f, 0.f, 0.f, 0.f};

    for (int c = 0; c < nch; c++) {
        int col = c * 64;
        #pragma unroll
        for (int i0 = 0; i0 < 4; i0++) {
            int i = tid + i0 * 256;
            int row = i >> 3, seg = i & 7;
            uint4 bv = *(const uint4*)(Btp + (size_t)row * ldb + col + seg * 8);
            *(uint4*)(&SH[1][row][seg * 8]) = bv;
            int rowg = m0 + row;
            uint4 av = make_uint4(0, 0, 0, 0);
            if (rowg < NN) av = *(const uint4*)(A + (size_t)rowg * lda + col + seg * 8);
            *(uint4*)(&SH[0][row][seg * 8]) = av;
        }
        __syncthreads();
        #pragma unroll
        for (int kq = 0; kq < 2; kq++) {
            bf16x8 af[4], bfr[4];
            #pragma unroll
            for (int f = 0; f < 4; f++) {
                af[f]  = *(const bf16x8*)(&SH[0][wr * 64 + f * 16 + ln][kq * 32 + q * 8]);
                bfr[f] = *(const bf16x8*)(&SH[1][wc * 64 + f * 16 + ln][kq * 32 + q * 8]);
            }
            #pragma unroll
            for (int fr = 0; fr < 4; fr++)
                #pragma unroll
                for (int fc = 0; fc < 4; fc++)
                    acc[fr][fc] = __builtin_amdgcn_mfma_f32_16x16x32_bf16(
                        bfr[fc], af[fr], acc[fr][fc], 0, 0, 0);   // swapped: D^T
        }
        __syncthreads();
    }

    unsigned short* CT = &SH[0][0][0];   // 128 x (stride 136)
    #pragma unroll
    for (int fr = 0; fr < 4; fr++) {
        int rloc = wr * 64 + fr * 16 + ln;
        #pragma unroll
        for (int fc = 0; fc < 4; fc++) {
            int colb = wc * 64 + fc * 16 + q * 4;
            float4 bv = bias ? *(const float4*)(bias + colb) : make_float4(0, 0, 0, 0);
            unsigned short tmp[4] __attribute__((aligned(8)));
            tmp[0] = f2bf(acc[fr][fc][0] + bv.x);
            tmp[1] = f2bf(acc[fr][fc][1] + bv.y);
            tmp[2] = f2bf(acc[fr][fc][2] + bv.z);
            tmp[3] = f2bf(acc[fr][fc][3] + bv.w);
            *(uint2*)(&CT[rloc * 136 + colb]) = *(const uint2*)tmp;
        }
    }
    __syncthreads();
    unsigned short* outBp = outB + (size_t)blockIdx.x * NN * H;
    #pragma unroll
    for (int i0 = 0; i0 < 8; i0++) {
        int idx = tid + i0 * 256;
        int row = idx >> 4, seg = idx & 15;
        int rowg = m0 + row;
        if (rowg < NN)
            *(uint4*)(outBp + (size_t)rowg * H + seg * 8) = *(const uint4*)(&CT[row * 136 + seg * 8]);
    }
}

// ---------------- fused aggregation: one wave per node ----------------
// Packed fp32 (v_pk_fma_f32) on the (x,y) column pair; depth-4 hs gather pipeline.
__global__ __launch_bounds__(256) void k_agg2(
    const unsigned short* __restrict__ pd, const unsigned short* __restrict__ ps,
    const float* __restrict__ eF,         // [E][16] fp32, slot-ordered
    const int* __restrict__ csr_src, const int* __restrict__ row_ptr,
    const float* __restrict__ Kl, const float* __restrict__ cl,
    unsigned short* __restrict__ agg)
{
    int wv = threadIdx.x >> 6, lane = threadIdx.x & 63;
    int i = blockIdx.x * 4 + wv;
    int d0 = lane * 2;
    v2f kr[16];
    #pragma unroll
    for (int k = 0; k < 16; k++) kr[k] = *(const v2f*)(Kl + k * H + d0);
    v2f c2 = *(const v2f*)(cl + d0);
    unsigned hd = *(const unsigned*)(pd + (size_t)i * H + d0);
    v2f base = c2 + (v2f){bflo(hd), bfhi(hd)};
    int rs = __builtin_amdgcn_readfirstlane(row_ptr[i]);
    int re = __builtin_amdgcn_readfirstlane(row_ptr[i + 1]);
    v2f s = (v2f){0.f, 0.f}, qv = (v2f){0.f, 0.f};
    v2f mn = (v2f){3.0e38f, 3.0e38f}, mx = (v2f){-3.0e38f, -3.0e38f};

    // depth-4 pipeline: hs loads for slots rs..rs+3 in flight
    unsigned hs0, hs1, hs2, hs3;
    {
        int a0 = (rs < re)     ? __builtin_amdgcn_readfirstlane(csr_src[rs])     : 0;
        int a1 = (rs + 1 < re) ? __builtin_amdgcn_readfirstlane(csr_src[rs + 1]) : 0;
        int a2 = (rs + 2 < re) ? __builtin_amdgcn_readfirstlane(csr_src[rs + 2]) : 0;
        int a3 = (rs + 3 < re) ? __builtin_amdgcn_readfirstlane(csr_src[rs + 3]) : 0;
        hs0 = *(const unsigned*)(ps + (size_t)a0 * H + d0);
        hs1 = *(const unsigned*)(ps + (size_t)a1 * H + d0);
        hs2 = *(const unsigned*)(ps + (size_t)a2 * H + d0);
        hs3 = *(const unsigned*)(ps + (size_t)a3 * H + d0);
    }

    int slot = rs;
    for (; slot + 1 < re; slot += 2) {
        // prefetch slots +4, +5 (consumed 2 iterations later)
        int p0 = (slot + 4 < re) ? __builtin_amdgcn_readfirstlane(csr_src[slot + 4]) : 0;
        int p1 = (slot + 5 < re) ? __builtin_amdgcn_readfirstlane(csr_src[slot + 5]) : 0;
        unsigned hsN0 = *(const unsigned*)(ps + (size_t)p0 * H + d0);
        unsigned hsN1 = *(const unsigned*)(ps + (size_t)p1 * H + d0);
        const float* ea = eF + (size_t)slot * EIN;   // uniform -> s_load
        const float* eb = ea + EIN;
        v2f a = base + (v2f){bflo(hs0), bfhi(hs0)};
        v2f c = base + (v2f){bflo(hs1), bfhi(hs1)};
        #pragma unroll
        for (int j = 0; j < 16; j++) {
            float e1 = ea[j], e2 = eb[j];
            a = (v2f){e1, e1} * kr[j] + a;   // v_pk_fma_f32
            c = (v2f){e2, e2} * kr[j] + c;
        }
        s = s + a + c;
        qv = a * a + (c * c + qv);
        mn.x = fminf(mn.x, fminf(a.x, c.x)); mn.y = fminf(mn.y, fminf(a.y, c.y));
        mx.x = fmaxf(mx.x, fmaxf(a.x, c.x)); mx.y = fmaxf(mx.y, fmaxf(a.y, c.y));
        hs0 = hs2; hs1 = hs3; hs2 = hsN0; hs3 = hsN1;
    }
    if (slot < re) {   // odd tail
        const float* ea = eF + (size_t)slot * EIN;
        v2f a = base + (v2f){bflo(hs0), bfhi(hs0)};
        #pragma unroll
        for (int j = 0; j < 16; j++) {
            float e1 = ea[j];
            a = (v2f){e1, e1} * kr[j] + a;
        }
        s = s + a;
        qv = a * a + qv;
        mn.x = fminf(mn.x, a.x); mn.y = fminf(mn.y, a.y);
        mx.x = fmaxf(mx.x, a.x); mx.y = fmaxf(mx.y, a.y);
    }

    int dg = re - rs;
    float dinv = 1.0f / fmaxf((float)dg, 1.0f);
    v2f me = s * (v2f){dinv, dinv};
    float sdx = sqrtf(fmaxf(qv.x * dinv - me.x * me.x, 0.f) + EPSV);
    float sdy = sqrtf(fmaxf(qv.y * dinv - me.y * me.y, 0.f) + EPSV);
    if (dg == 0) { mn = (v2f){0.f, 0.f}; mx = (v2f){0.f, 0.f}; }
    unsigned short* ap = agg + (size_t)i * 512 + d0;
    *(unsigned*)(ap)       = (unsigned)f2bf(me.x) | ((unsigned)f2bf(me.y) << 16);
    *(unsigned*)(ap + 128) = (unsigned)f2bf(mn.x) | ((unsigned)f2bf(mn.y) << 16);
    *(unsigned*)(ap + 256) = (unsigned)f2bf(mx.x) | ((unsigned)f2bf(mx.y) << 16);
    *(unsigned*)(ap + 384) = (unsigned)f2bf(sdx)  | ((unsigned)f2bf(sdy)  << 16);
}

// ---------------- combine: h = relu(hA' + p0 + amp*p1 + att*p2 + bias') ----------------
__global__ __launch_bounds__(256) void k_comb(const unsigned* __restrict__ ha,
                                              const unsigned* __restrict__ part,
                                              const float* __restrict__ amp,
                                              const float* __restrict__ att,
                                              const float* __restrict__ biasf,
                                              unsigned* __restrict__ hbo,
                                              float* __restrict__ hfo) {
    int dv = blockIdx.x * 256 + threadIdx.x;
    int i = dv >> 6;
    int cp = dv & 63;
    float a = amp[i], t = att[i];
    unsigned uh = ha[dv];
    unsigned p0 = part[dv];
    unsigned p1 = part[dv + NP64];
    unsigned p2 = part[dv + 2 * NP64];
    float lo = bflo(uh) + bflo(p0) + a * bflo(p1) + t * bflo(p2) + biasf[cp * 2];
    float hi = bfhi(uh) + bfhi(p0) + a * bfhi(p1) + t * bfhi(p2) + biasf[cp * 2 + 1];
    lo = fmaxf(lo, 0.f); hi = fmaxf(hi, 0.f);
    hbo[dv] = (unsigned)f2bf(lo) | ((unsigned)f2bf(hi) << 16);
    if (hfo) { hfo[dv * 2] = lo; hfo[dv * 2 + 1] = hi; }
}

// ---------------- pooling + head ----------------
__device__ __forceinline__ int lbound(const int* a, int n, int v) {
    int lo = 0, hi = n;
    while (lo < hi) { int m = (lo + hi) >> 1; if (a[m] < v) lo = m + 1; else hi = m; }
    return lo;
}

__global__ __launch_bounds__(256) void k_pool(const float* __restrict__ h,
                                              const int* __restrict__ batch,
                                              const float* __restrict__ headW,
                                              const float* __restrict__ headb,
                                              float* __restrict__ out) {
    __shared__ float sm[256];
    int g = blockIdx.x;
    int t = threadIdx.x;
    int col = t & 127;
    int half = t >> 7;
    int lo = lbound(batch, NN, g);
    int hi = lbound(batch, NN, g + 1);
    int mid = lo + ((hi - lo) >> 1);
    int b0 = half ? mid : lo;
    int b1 = half ? hi : mid;
    float acc = 0.f;
    for (int i = b0; i < b1; i++) acc += h[(size_t)i * H + col];
    sm[t] = acc;
    __syncthreads();
    if (t < 128) sm[t] += sm[t + 128];
    __syncthreads();
    if (t < NOUT) {
        float r = headb[t];
        for (int j = 0; j < H; j++) r = fmaf(sm[j], headW[j * NOUT + t], r);
        out[g * NOUT + t] = r;
    }
}

// ---------------- launch ----------------
extern "C" void kernel_launch(void* const* d_in, const int* in_sizes, int n_in,
                              void* d_out, int out_size, void* d_ws, size_t ws_size,
                              hipStream_t stream) {
    const float* x          = (const float*)d_in[0];
    const float* edge_attr  = (const float*)d_in[1];
    const int*   src        = (const int*)d_in[2];
    const int*   dst        = (const int*)d_in[3];
    const int*   batch      = (const int*)d_in[4];
    const float* node_emb_W = (const float*)d_in[5];
    const float* node_emb_b = (const float*)d_in[6];
    const float* edge_emb_W = (const float*)d_in[7];
    const float* edge_emb_b = (const float*)d_in[8];
    const float* edge_enc_W = (const float*)d_in[9];
    const float* edge_enc_b = (const float*)d_in[10];
    const float* pre_W      = (const float*)d_in[11];
    const float* pre_b      = (const float*)d_in[12];
    const float* post_W     = (const float*)d_in[13];
    const float* post_b     = (const float*)d_in[14];
    const float* lin_W      = (const float*)d_in[15];
    const float* lin_b      = (const float*)d_in[16];
    const float* head_W     = (const float*)d_in[17];
    const float* head_b     = (const float*)d_in[18];
    float* out = (float*)d_out;

    char* wp = (char*)d_ws;
    auto carve = [&](size_t bytes) -> char* {
        char* r = wp;
        wp += (bytes + 255) & ~(size_t)255;
        return r;
    };
    int*   deg     = (int*)carve((size_t)NN * 4);      // |
    int*   cursor  = (int*)carve((size_t)NN * 4);      // | zeroed in ONE memset
    float* sumlog  = (float*)carve(4);                 // |
    int*   partial = (int*)carve(256 * 4);
    int*   row_ptr = (int*)carve((size_t)(NN + 1) * 4);
    int*   csr_src = (int*)carve((size_t)NE * 4);
    int*   csr_eid = (int*)carve((size_t)NE * 4);
    float* amp     = (float*)carve((size_t)NN * 4);
    float* att     = (float*)carve((size_t)NN * 4);
    float* Kc      = (float*)carve((size_t)NL * 16 * H * 4);
    float* cc      = (float*)carve((size_t)NL * H * 4);
    float* cfold   = (float*)carve((size_t)NL * H * 4);
    float* Mf      = (float*)carve((size_t)NL * H * H * 4);
    float* eattrF  = (float*)carve((size_t)NE * EIN * 4);
    unsigned short* embWt  = (unsigned short*)carve((size_t)H * FIN * 2);
    unsigned short* Wt3    = (unsigned short*)carve((size_t)NL * 3 * H * H * 2);
    unsigned short* foldT  = (unsigned short*)carve((size_t)NL * 128 * 1664 * 2);
    unsigned short* xb     = (unsigned short*)carve((size_t)NN * FIN * 2);
    unsigned short* hb     = (unsigned short*)carve((size_t)NN * H * 2);
    unsigned short* planesB= (unsigned short*)carve((size_t)3 * NN * H * 2);
    unsigned short* aggb   = (unsigned short*)carve((size_t)NN * 4 * H * 2);
    unsigned short* partsB = (unsigned short*)carve((size_t)3 * NN * H * 2);
    float* hf      = (float*)carve((size_t)NN * H * 4);

    const size_t NP = (size_t)NN * H;

    // deg, cursor, sumlog are contiguous carves (256-aligned): one memset
    hipMemsetAsync(deg, 0, ((size_t)NN * 4 + 255 & ~(size_t)255) * 2 + 256, stream);

    k_hist<<<(NE + 255) / 256, 256, 0, stream>>>(dst, deg);
    k_scan1<<<NBLK, 256, 0, stream>>>(deg, partial);
    k_scan2<<<1, 256, 0, stream>>>(partial, row_ptr, NBLK);
    k_scan3<<<NBLK, 256, 0, stream>>>(deg, partial, row_ptr);
    k_fill<<<(NE + 255) / 256, 256, 0, stream>>>(src, dst, row_ptr, cursor, csr_src, csr_eid);
    k_eperm<<<(NE * EIN + 255) / 256, 256, 0, stream>>>(edge_attr, csr_eid, eattrF);
    k_sumlog<<<NBLK, 256, 0, stream>>>(deg, sumlog);
    k_scalers<<<NBLK, 256, 0, stream>>>(deg, sumlog, amp, att);
    k_encfold<<<dim3(2, NL), 256, 0, stream>>>(edge_enc_W, pre_W, Mf);
    k_kprep<<<dim3(8, NL), 256, 0, stream>>>(edge_emb_W, Mf, Kc);
    k_cprep<<<NL, H, 0, stream>>>(edge_emb_b, edge_enc_W, edge_enc_b, pre_W, pre_b, cc);
    k_wfold<<<dim3(26, NL), 256, 0, stream>>>(post_W, lin_W, Wt3, foldT);
    k_bfold<<<NL, H, 0, stream>>>(post_b, lin_b, lin_W, cfold);

    TDs tds;
    int nd = 0;
    tds.t[nd++] = TD{node_emb_W, embWt, FIN};
    for (int l = 0; l < NL; l++) {
        tds.t[nd++] = TD{pre_W + (size_t)l * 3 * H * H,         Wt3 + (size_t)(l * 3 + 0) * H * H, H};
        tds.t[nd++] = TD{pre_W + (size_t)l * 3 * H * H + H * H, Wt3 + (size_t)(l * 3 + 1) * H * H, H};
    }
    k_prepw<<<dim3(64, 9), 256, 0, stream>>>(tds);
    k_cast<<<(NN * FIN + 255) / 256, 256, 0, stream>>>(x, xb, NN * FIN);

    // h = x @ node_emb_W + b  (bf16 out)
    k_mgemm<<<dim3(1, GB2), 256, 0, stream>>>(xb, FIN, FIN, 1, embWt, FIN, 0,
                                              node_emb_b, hb);

    for (int l = 0; l < NL; l++) {
        int last = (l == NL - 1);
        // planesB bf16: [hW_dst | hW_src | hA'(=h@Wh@linW)]
        k_mgemm<<<dim3(3, GB2), 256, 0, stream>>>(hb, H, H, 2,
                                                  Wt3 + (size_t)l * 3 * H * H, H, H * H,
                                                  nullptr, planesB);
        // fused aggregation
        k_agg2<<<NN / 4, 256, 0, stream>>>(planesB, planesB + NP,
                                           eattrF, csr_src, row_ptr,
                                           Kc + (size_t)l * 16 * H, cc + (size_t)l * H,
                                           aggb);
        // partials: p_g = agg @ (B_g@linW), g=0..2  (split-K by scale group)
        k_mgemm<<<dim3(3, GB2), 256, 0, stream>>>(aggb, 4 * H, 4 * H, 8,
                                                  foldT + (size_t)l * 128 * 1664 + 128,
                                                  1664, 512,
                                                  nullptr, partsB);
        // combine: h = relu(hA' + p0 + amp*p1 + att*p2 + bias')
        k_comb<<<NP64 / 256, 256, 0, stream>>>((const unsigned*)(planesB + 2 * NP),
                                               (const unsigned*)partsB, amp, att,
                                               cfold + (size_t)l * H,
                                               (unsigned*)hb, last ? hf : nullptr);
    }

    k_pool<<<NG, 256, 0, stream>>>(hf, batch, head_W, head_b, out);
}